// Round 1
// baseline (24681.615 us; speedup 1.0000x reference)
//
#include <hip/hip_runtime.h>
#include <cfloat>

// ---------------------------------------------------------------------------
// SearchTransfer (TTSR): 3-level patch correlation + argmax + gather/fold.
// Levels (LEV): 0 = lv3 (C=256,H=64,k=3,s=1,p=1,D=2304)
//              1 = lv2 (C=128,H=128,k=6,s=2,p=2,D=4608)
//              2 = lv1 (C=64,H=256,k=12,s=4,p=4,D=9216)
// L = M = 4096 patch positions per batch, B = 2.
//
// score(l,m) = sum_d (u_rs[d,l]*rinv[d] - mval) * (u_lr[d,m]*ninv[m] - mval)
//            = ninv[m]*G[l,m] - mval*P[l] - mval*ninv[m]*csum[m] + D*mval^2
// S = max_l score * scale ; arg = argmax_l (first occurrence on ties).
// ---------------------------------------------------------------------------

template<int LEV> struct LT;
template<> struct LT<0> { static constexpr int C=256, H=64,  K=3,  S=1, P=1; };
template<> struct LT<1> { static constexpr int C=128, H=128, K=6,  S=2, P=2; };
template<> struct LT<2> { static constexpr int C=64,  H=256, K=12, S=4, P=4; };

__host__ __device__ constexpr int lev_D(int lev){ return lev==0?2304:(lev==1?4608:9216); }
// ws float-index offsets
__host__ __device__ constexpr int rho_off(int lev){ return 32 + (lev>0?2*2304:0) + (lev>1?2*4608:0); } // end 32288
__host__ __device__ constexpr int p_off(int lev)   { return 32288  + lev*8192;  } // end 56864
__host__ __device__ constexpr int ninv_off(int lev){ return 56864  + lev*8192;  } // end 81440
__host__ __device__ constexpr int csum_off(int lev){ return 81440  + lev*8192;  } // end 106016
__host__ __device__ constexpr int pmax_off(int lev){ return 106016 + lev*65536; } // end 302624
__host__ __device__ constexpr int parg_off(int lev){ return 302624 + lev*65536; } // end 499232 (int)
__host__ __device__ constexpr int arg_off(){ return 499232; }                     // int, 8192

// --- per-(b,d) row norm of refsr unfold (normalize axis=2) + scalar accums ---
template<int LEV>
__global__ void k_rownorm(const float* __restrict__ refsr, float* __restrict__ ws){
    constexpr int C=LT<LEV>::C, H=LT<LEV>::H, K=LT<LEV>::K, S=LT<LEV>::S, PD=LT<LEV>::P;
    constexpr int D = C*K*K, KK=K*K;
    int tid = threadIdx.x, lane = tid & 63;
    int wid = (blockIdx.x*blockDim.x + tid) >> 6;
    if (wid >= 2*D) return;
    int b = wid / D, d = wid % D;
    int c = d/KK, rem = d%KK, ki = rem/K, kj = rem%K;
    const float* img = refsr + (size_t)(b*C + c)*H*H;
    float sum=0.f, ssq=0.f;
    for (int idx=lane; idx<4096; idx+=64){
        int ho=idx>>6, wo=idx&63;
        int row = ho*S+ki-PD, col = wo*S+kj-PD;
        if (row>=0 && row<H && col>=0 && col<H){
            float v = img[row*H+col]; sum += v; ssq += v*v;
        }
    }
    #pragma unroll
    for (int off=32; off; off>>=1){ sum += __shfl_xor(sum,off); ssq += __shfl_xor(ssq,off); }
    if (lane==0){
        float rinv = 1.0f / fmaxf(sqrtf(ssq), 1e-12f);
        ws[rho_off(LEV) + b*D + d] = rinv;
        atomicAdd(&ws[LEV*4+0], sum*rinv);        // sum(rs)
        atomicAdd(&ws[LEV*4+1], ssq*rinv*rinv);   // sum(rs^2)
    }
}

// --- per-(b,m) column norm of lrsr unfold (normalize axis=1) + scalar accums ---
template<int LEV>
__global__ void k_colnorm(const float* __restrict__ lrsr, float* __restrict__ ws){
    constexpr int C=LT<LEV>::C, H=LT<LEV>::H, K=LT<LEV>::K, S=LT<LEV>::S, PD=LT<LEV>::P;
    constexpr int D = C*K*K, KK=K*K;
    int tid = threadIdx.x, lane = tid & 63;
    int wid = (blockIdx.x*blockDim.x + tid) >> 6;
    if (wid >= 8192) return;
    int b = wid >> 12, m = wid & 4095;
    int my = m>>6, mx = m&63;
    float sum=0.f, ssq=0.f;
    for (int d=lane; d<D; d+=64){
        int c = d/KK, rem = d%KK, ki = rem/K, kj = rem%K;
        int row = my*S+ki-PD, col = mx*S+kj-PD;
        if (row>=0 && row<H && col>=0 && col<H){
            float v = lrsr[((size_t)(b*C+c)*H + row)*H + col]; sum += v; ssq += v*v;
        }
    }
    #pragma unroll
    for (int off=32; off; off>>=1){ sum += __shfl_xor(sum,off); ssq += __shfl_xor(ssq,off); }
    if (lane==0){
        float ninv = 1.0f / fmaxf(sqrtf(ssq), 1e-12f);
        ws[ninv_off(LEV) + wid] = ninv;
        ws[csum_off(LEV) + wid] = sum;
        atomicAdd(&ws[LEV*4+2], sum*ninv);        // sum(lr)
        atomicAdd(&ws[LEV*4+3], ssq*ninv*ninv);   // sum(lr^2)
    }
}

// --- P[b,l] = sum_d u_rs[d,l] * rinv[d] ---
template<int LEV>
__global__ void k_pvec(const float* __restrict__ refsr, float* __restrict__ ws){
    constexpr int C=LT<LEV>::C, H=LT<LEV>::H, K=LT<LEV>::K, S=LT<LEV>::S, PD=LT<LEV>::P;
    constexpr int D = C*K*K, KK=K*K;
    int tid = threadIdx.x, lane = tid & 63;
    int wid = (blockIdx.x*blockDim.x + tid) >> 6;
    if (wid >= 8192) return;
    int b = wid >> 12, l = wid & 4095;
    int ly = l>>6, lx = l&63;
    const float* rinv = ws + rho_off(LEV) + b*D;
    float sum=0.f;
    for (int d=lane; d<D; d+=64){
        int c = d/KK, rem = d%KK, ki = rem/K, kj = rem%K;
        int row = ly*S+ki-PD, col = lx*S+kj-PD;
        if (row>=0 && row<H && col>=0 && col<H)
            sum += refsr[((size_t)(b*C+c)*H + row)*H + col] * rinv[d];
    }
    #pragma unroll
    for (int off=32; off; off>>=1) sum += __shfl_xor(sum,off);
    if (lane==0) ws[p_off(LEV) + wid] = sum;
}

// --- scalars: mval per level, scales (incl. reference's ym3 bug in R2) ---
__global__ void k_finalize(float* __restrict__ ws){
    if (threadIdx.x || blockIdx.x) return;
    float gx2[3], gy2[3];
    for (int lev=0; lev<3; lev++){
        float BDL = 2.0f * (float)lev_D(lev) * 4096.0f;
        float m = ws[lev*4+0] / BDL;
        ws[12+lev] = m;
        gx2[lev] = ws[lev*4+1] - 2.f*m*ws[lev*4+0] + BDL*m*m;
        gy2[lev] = ws[lev*4+3] - 2.f*m*ws[lev*4+2] + BDL*m*m;
    }
    ws[16+0] = 1.0f/(sqrtf(gx2[0])*sqrtf(gy2[0]));
    ws[16+1] = 1.0f/(sqrtf(gx2[1])*sqrtf(gy2[0]));   // reference bug: uses ym3
    ws[16+2] = 1.0f/(sqrtf(gx2[2])*sqrtf(gy2[2]));
}

// --- fused GEMM + running max/argmax over l-chunk ---
// grid: (my=64, lchunk=8, b=2), block 256. Each block: 64 m x 512 l x D.
template<int LEV>
__launch_bounds__(256)
__global__ void k_corr(const float* __restrict__ refsr, const float* __restrict__ lrsr,
                       float* __restrict__ ws){
    constexpr int C=LT<LEV>::C, H=LT<LEV>::H, K=LT<LEV>::K, S=LT<LEV>::S, PD=LT<LEV>::P;
    constexpr int D = C*K*K, KK=K*K;
    __shared__ float As[32][64];
    __shared__ float Bs[32][64];
    int tid = threadIdx.x, tr = tid & 15, tc = tid >> 4;
    int my = blockIdx.x, lchunk = blockIdx.y, b = blockIdx.z;
    const float* rimg = refsr + (size_t)b*C*H*H;
    const float* limg = lrsr  + (size_t)b*C*H*H;
    const float* rinv = ws + rho_off(LEV) + b*D;

    float mval = ws[12+LEV];
    float Dm2 = (float)D * mval * mval;
    float niv[4], cm[4];
    #pragma unroll
    for (int j=0;j<4;j++){
        int m = my*64 + tc*4 + j;
        float nv = ws[ninv_off(LEV) + b*4096 + m];
        niv[j] = nv;
        cm[j] = -mval*nv*ws[csum_off(LEV) + b*4096 + m] + Dm2;
    }
    float rmax[4] = {-FLT_MAX,-FLT_MAX,-FLT_MAX,-FLT_MAX};
    int   rarg[4] = {0x7fffffff,0x7fffffff,0x7fffffff,0x7fffffff};

    for (int lt=0; lt<8; lt++){
        int ly = lchunk*8 + lt;
        float acc[4][4];
        #pragma unroll
        for (int i=0;i<4;i++)
            #pragma unroll
            for (int j=0;j<4;j++) acc[i][j]=0.f;

        for (int d0=0; d0<D; d0+=32){
            #pragma unroll
            for (int it=0; it<8; it++){
                int e = tid + it*256;
                int t = e>>6, xx = e&63;
                int d = d0+t;
                int c = d/KK, rem = d%KK, ki = rem/K, kj = rem%K;
                int arow = ly*S+ki-PD, acol = xx*S+kj-PD;
                float av = (arow>=0 && arow<H && acol>=0 && acol<H)
                           ? rimg[(size_t)(c*H+arow)*H + acol] : 0.f;
                As[t][xx] = av * rinv[d];
                int brow = my*S+ki-PD, bcol = xx*S+kj-PD;
                Bs[t][xx] = (brow>=0 && brow<H && bcol>=0 && bcol<H)
                           ? limg[(size_t)(c*H+brow)*H + bcol] : 0.f;
            }
            __syncthreads();
            #pragma unroll 8
            for (int t=0;t<32;t++){
                float av[4], bv[4];
                *(float4*)av = *(const float4*)&As[t][tr*4];
                *(float4*)bv = *(const float4*)&Bs[t][tc*4];
                #pragma unroll
                for (int i=0;i<4;i++)
                    #pragma unroll
                    for (int j=0;j<4;j++)
                        acc[i][j] = fmaf(av[i], bv[j], acc[i][j]);
            }
            __syncthreads();
        }

        float Pl[4];
        #pragma unroll
        for (int i=0;i<4;i++) Pl[i] = ws[p_off(LEV) + b*4096 + ly*64 + tr*4 + i];
        #pragma unroll
        for (int j=0;j<4;j++){
            float v = -FLT_MAX; int vi = 0x7fffffff;
            #pragma unroll
            for (int i=0;i<4;i++){
                float sc = niv[j]*acc[i][j] - mval*Pl[i] + cm[j];
                if (sc > v){ v = sc; vi = ly*64 + tr*4 + i; }
            }
            #pragma unroll
            for (int off=1; off<16; off<<=1){
                float ov = __shfl_xor(v, off, 16);
                int   oi = __shfl_xor(vi, off, 16);
                if (ov > v || (ov == v && oi < vi)){ v = ov; vi = oi; }
            }
            if (v > rmax[j] || (v == rmax[j] && vi < rarg[j])){ rmax[j]=v; rarg[j]=vi; }
        }
    }
    if (tr==0){
        #pragma unroll
        for (int j=0;j<4;j++){
            int m = my*64 + tc*4 + j;
            int o = (b*8 + lchunk)*4096 + m;
            ws[pmax_off(LEV) + o] = rmax[j];
            ((int*)ws)[parg_off(LEV) + o] = rarg[j];
        }
    }
}

// --- reduce 8 l-chunks -> S3,S2,S1,arg outputs ---
__global__ void k_smax(float* __restrict__ ws, float* __restrict__ out){
    int gid = blockIdx.x*256 + threadIdx.x;
    if (gid >= 8192) return;
    int b = gid >> 12, m = gid & 4095;
    for (int lev=0; lev<3; lev++){
        float mv = -FLT_MAX; int ma = 0x7fffffff;
        for (int ch=0; ch<8; ch++){
            int o = ((b*8+ch)<<12) + m;
            float v = ws[pmax_off(lev) + o];
            int   a = ((const int*)ws)[parg_off(lev) + o];
            if (v > mv || (v == mv && a < ma)){ mv=v; ma=a; }
        }
        out[lev*8192 + gid] = mv * ws[16+lev];
        if (lev==0){
            out[3*8192 + gid] = (float)ma;
            ((int*)ws)[arg_off() + gid] = ma;
        }
    }
}

// --- T = fold(gather(unfold(ref), arg)) / 9 ---
template<int LEV>
__global__ void k_transfer(const float* __restrict__ ref, const float* __restrict__ wsf,
                           float* __restrict__ outT){
    constexpr int C=LT<LEV>::C, H=LT<LEV>::H, K=LT<LEV>::K, S=LT<LEV>::S, PD=LT<LEV>::P;
    const int* arg = (const int*)wsf + arg_off();
    size_t gid = (size_t)blockIdx.x*256 + threadIdx.x;
    size_t total = (size_t)2*C*H*H;
    if (gid >= total) return;
    int x = (int)(gid % H);
    int y = (int)((gid / H) % H);
    int c = (int)((gid / ((size_t)H*H)) % C);
    int b = (int)(gid / ((size_t)C*H*H));
    const float* rimg = ref + (size_t)(b*C+c)*H*H;
    int byo = (y+PD)/S, ryo = (y+PD)%S;
    int bxo = (x+PD)/S, rxo = (x+PD)%S;
    float acc = 0.f;
    #pragma unroll
    for (int jy=0; jy<3; jy++){
        int ho = byo - jy;
        if (ho < 0 || ho >= 64) continue;
        int ki = ryo + jy*S;
        #pragma unroll
        for (int jx=0; jx<3; jx++){
            int wo = bxo - jx;
            if (wo < 0 || wo >= 64) continue;
            int kj = rxo + jx*S;
            int l = arg[b*4096 + ho*64 + wo];
            int ly = l>>6, lx = l&63;
            int srow = ly*S + ki - PD, scol = lx*S + kj - PD;
            if (srow>=0 && srow<H && scol>=0 && scol<H)
                acc += rimg[srow*H + scol];
        }
    }
    outT[gid] = acc * (1.0f/9.0f);
}

extern "C" void kernel_launch(void* const* d_in, const int* in_sizes, int n_in,
                              void* d_out, int out_size, void* d_ws, size_t ws_size,
                              hipStream_t stream){
    // setup_inputs order: lrsr_lv1, lrsr_lv2, lrsr_lv3, refsr_lv1, refsr_lv2, refsr_lv3,
    //                     ref_lv1, ref_lv2, ref_lv3
    const float* lrsr[3]  = { (const float*)d_in[2], (const float*)d_in[1], (const float*)d_in[0] };
    const float* refsr[3] = { (const float*)d_in[5], (const float*)d_in[4], (const float*)d_in[3] };
    const float* refp[3]  = { (const float*)d_in[8], (const float*)d_in[7], (const float*)d_in[6] };
    float* ws  = (float*)d_ws;
    float* out = (float*)d_out;

    hipMemsetAsync(d_ws, 0, 128, stream);  // zero scalar accumulators

    k_rownorm<0><<<2304/2, 256, 0, stream>>>(refsr[0], ws);
    k_rownorm<1><<<4608/2, 256, 0, stream>>>(refsr[1], ws);
    k_rownorm<2><<<9216/2, 256, 0, stream>>>(refsr[2], ws);
    k_colnorm<0><<<2048, 256, 0, stream>>>(lrsr[0], ws);
    k_colnorm<1><<<2048, 256, 0, stream>>>(lrsr[1], ws);
    k_colnorm<2><<<2048, 256, 0, stream>>>(lrsr[2], ws);
    k_pvec<0><<<2048, 256, 0, stream>>>(refsr[0], ws);
    k_pvec<1><<<2048, 256, 0, stream>>>(refsr[1], ws);
    k_pvec<2><<<2048, 256, 0, stream>>>(refsr[2], ws);
    k_finalize<<<1, 64, 0, stream>>>(ws);

    dim3 cgrid(64, 8, 2);
    k_corr<0><<<cgrid, 256, 0, stream>>>(refsr[0], lrsr[0], ws);
    k_corr<1><<<cgrid, 256, 0, stream>>>(refsr[1], lrsr[1], ws);
    k_corr<2><<<cgrid, 256, 0, stream>>>(refsr[2], lrsr[2], ws);

    k_smax<<<32, 256, 0, stream>>>(ws, out);

    k_transfer<0><<< (2*256*64*64)/256,  256, 0, stream>>>(refp[0], ws, out + 32768);
    k_transfer<1><<< (2*128*128*128)/256,256, 0, stream>>>(refp[1], ws, out + 2129920);
    k_transfer<2><<< (2*64*256*256)/256, 256, 0, stream>>>(refp[2], ws, out + 6324224);
}

// Round 2
// 19047.089 us; speedup vs baseline: 1.2958x; 1.2958x over previous
//
#include <hip/hip_runtime.h>
#include <cfloat>

// ---------------------------------------------------------------------------
// SearchTransfer (TTSR): 3-level patch correlation + argmax + gather/fold.
// Levels: 0 = lv3 (C=256,H=64,k=3,s=1,p=1,D=2304)
//         1 = lv2 (C=128,H=128,k=6,s=2,p=2,D=4608)
//         2 = lv1 (C=64,H=256,k=12,s=4,p=4,D=9216)
// L = M = 4096 patch positions per batch, B = 2.
//
// score(l,m) = ninv[m]*G[l,m] - mval*P[l] - mval*ninv[m]*csum[m] + D*mval^2
// G[l,m] = sum_d (u_rs[d,l]*rinv[d]) * u_lr[d,m]
//
// Fast path: G via bf16x3-split MFMA (6 products, fp32 accumulate) on
// materialized K-contiguous planes in ws. Fallback: fp32 VALU GEMM.
// ---------------------------------------------------------------------------

typedef short short8 __attribute__((ext_vector_type(8)));
typedef float f32x4  __attribute__((ext_vector_type(4)));

template<int LEV> struct LT;
template<> struct LT<0> { static constexpr int C=256, H=64,  K=3,  S=1, P=1; };
template<> struct LT<1> { static constexpr int C=128, H=128, K=6,  S=2, P=2; };
template<> struct LT<2> { static constexpr int C=64,  H=256, K=12, S=4, P=4; };

__host__ __device__ constexpr int lev_D(int lev){ return lev==0?2304:(lev==1?4608:9216); }
// ws float-index offsets
__host__ __device__ constexpr int rho_off(int lev){ return 32 + (lev>0?2*2304:0) + (lev>1?2*4608:0); } // end 32288
__host__ __device__ constexpr int p_off(int lev)   { return 32288  + lev*8192;   } // end 56864
__host__ __device__ constexpr int ninv_off(int lev){ return 56864  + lev*8192;   } // end 81440
__host__ __device__ constexpr int csum_off(int lev){ return 81440  + lev*8192;   } // end 106016
__host__ __device__ constexpr int pmax_off(int lev){ return 106016 + lev*262144; } // [b][32][4096], end 892448
__host__ __device__ constexpr int parg_off(int lev){ return 892448 + lev*262144; } // int, end 1678880
__host__ __device__ constexpr int arg_off(){ return 1678880; }                     // int, 8192
static constexpr size_t PLANE_BASE_BYTES = 8u << 20;  // planes live at ws+8MB

__device__ inline unsigned short f2bf(float f){
    unsigned int u = __float_as_uint(f);
    return (unsigned short)((u + 0x7fffu + ((u >> 16) & 1u)) >> 16);
}
__device__ inline float bf2f(unsigned short h){ return __uint_as_float(((unsigned)h) << 16); }

#define GLOAD16(g, l) __builtin_amdgcn_global_load_lds( \
    (const __attribute__((address_space(1))) unsigned int*)(g), \
    (__attribute__((address_space(3))) unsigned int*)(l), 16, 0, 0)

// --- per-(b,d) row norm of refsr unfold (normalize axis=2) + scalar accums ---
template<int LEV>
__global__ void k_rownorm(const float* __restrict__ refsr, float* __restrict__ ws){
    constexpr int C=LT<LEV>::C, H=LT<LEV>::H, K=LT<LEV>::K, S=LT<LEV>::S, PD=LT<LEV>::P;
    constexpr int D = C*K*K, KK=K*K;
    int tid = threadIdx.x, lane = tid & 63;
    int wid = (blockIdx.x*blockDim.x + tid) >> 6;
    if (wid >= 2*D) return;
    int b = wid / D, d = wid % D;
    int c = d/KK, rem = d%KK, ki = rem/K, kj = rem%K;
    const float* img = refsr + (size_t)(b*C + c)*H*H;
    float sum=0.f, ssq=0.f;
    for (int idx=lane; idx<4096; idx+=64){
        int ho=idx>>6, wo=idx&63;
        int row = ho*S+ki-PD, col = wo*S+kj-PD;
        if (row>=0 && row<H && col>=0 && col<H){
            float v = img[row*H+col]; sum += v; ssq += v*v;
        }
    }
    #pragma unroll
    for (int off=32; off; off>>=1){ sum += __shfl_xor(sum,off); ssq += __shfl_xor(ssq,off); }
    if (lane==0){
        float rinv = 1.0f / fmaxf(sqrtf(ssq), 1e-12f);
        ws[rho_off(LEV) + b*D + d] = rinv;
        atomicAdd(&ws[LEV*4+0], sum*rinv);
        atomicAdd(&ws[LEV*4+1], ssq*rinv*rinv);
    }
}

// --- per-(b,m) column norm of lrsr unfold (normalize axis=1) + scalar accums ---
template<int LEV>
__global__ void k_colnorm(const float* __restrict__ lrsr, float* __restrict__ ws){
    constexpr int C=LT<LEV>::C, H=LT<LEV>::H, K=LT<LEV>::K, S=LT<LEV>::S, PD=LT<LEV>::P;
    constexpr int D = C*K*K, KK=K*K;
    int tid = threadIdx.x, lane = tid & 63;
    int wid = (blockIdx.x*blockDim.x + tid) >> 6;
    if (wid >= 8192) return;
    int b = wid >> 12, m = wid & 4095;
    int my = m>>6, mx = m&63;
    float sum=0.f, ssq=0.f;
    for (int d=lane; d<D; d+=64){
        int c = d/KK, rem = d%KK, ki = rem/K, kj = rem%K;
        int row = my*S+ki-PD, col = mx*S+kj-PD;
        if (row>=0 && row<H && col>=0 && col<H){
            float v = lrsr[((size_t)(b*C+c)*H + row)*H + col]; sum += v; ssq += v*v;
        }
    }
    #pragma unroll
    for (int off=32; off; off>>=1){ sum += __shfl_xor(sum,off); ssq += __shfl_xor(ssq,off); }
    if (lane==0){
        float ninv = 1.0f / fmaxf(sqrtf(ssq), 1e-12f);
        ws[ninv_off(LEV) + wid] = ninv;
        ws[csum_off(LEV) + wid] = sum;
        atomicAdd(&ws[LEV*4+2], sum*ninv);
        atomicAdd(&ws[LEV*4+3], ssq*ninv*ninv);
    }
}

// --- P[b,l] = sum_d u_rs[d,l] * rinv[d] ---
template<int LEV>
__global__ void k_pvec(const float* __restrict__ refsr, float* __restrict__ ws){
    constexpr int C=LT<LEV>::C, H=LT<LEV>::H, K=LT<LEV>::K, S=LT<LEV>::S, PD=LT<LEV>::P;
    constexpr int D = C*K*K, KK=K*K;
    int tid = threadIdx.x, lane = tid & 63;
    int wid = (blockIdx.x*blockDim.x + tid) >> 6;
    if (wid >= 8192) return;
    int b = wid >> 12, l = wid & 4095;
    int ly = l>>6, lx = l&63;
    const float* rinv = ws + rho_off(LEV) + b*D;
    float sum=0.f;
    for (int d=lane; d<D; d+=64){
        int c = d/KK, rem = d%KK, ki = rem/K, kj = rem%K;
        int row = ly*S+ki-PD, col = lx*S+kj-PD;
        if (row>=0 && row<H && col>=0 && col<H)
            sum += refsr[((size_t)(b*C+c)*H + row)*H + col] * rinv[d];
    }
    #pragma unroll
    for (int off=32; off; off>>=1) sum += __shfl_xor(sum,off);
    if (lane==0) ws[p_off(LEV) + wid] = sum;
}

// --- scalars: mval per level, scales (incl. reference's ym3 bug in R2) ---
__global__ void k_finalize(float* __restrict__ ws){
    if (threadIdx.x || blockIdx.x) return;
    float gx2[3], gy2[3];
    for (int lev=0; lev<3; lev++){
        float BDL = 2.0f * (float)lev_D(lev) * 4096.0f;
        float m = ws[lev*4+0] / BDL;
        ws[12+lev] = m;
        gx2[lev] = ws[lev*4+1] - 2.f*m*ws[lev*4+0] + BDL*m*m;
        gy2[lev] = ws[lev*4+3] - 2.f*m*ws[lev*4+2] + BDL*m*m;
    }
    ws[16+0] = 1.0f/(sqrtf(gx2[0])*sqrtf(gy2[0]));
    ws[16+1] = 1.0f/(sqrtf(gx2[1])*sqrtf(gy2[0]));   // reference bug: uses ym3
    ws[16+2] = 1.0f/(sqrtf(gx2[2])*sqrtf(gy2[2]));
}

// --- bf16x3 split materialization: planes[q][row(l or m)][D], K-contiguous ---
// 16B slots within each 32-elem K-chunk pre-swizzled: slot ^= (row>>1)&3.
template<int LEV, bool ISA>
__global__ void k_split(const float* __restrict__ img4, const float* __restrict__ ws,
                        unsigned short* __restrict__ base, int b){
    constexpr int C=LT<LEV>::C, H=LT<LEV>::H, K=LT<LEV>::K, S=LT<LEV>::S, PD=LT<LEV>::P;
    constexpr int D = C*K*K, KK=K*K;
    const size_t PS = (size_t)4096 * D;
    int gid = blockIdx.x*256 + threadIdx.x;
    if (gid >= 4096*(D/8)) return;
    int kb = gid % (D/8), l = gid / (D/8);
    int k0 = kb*8;
    int ly = l>>6, lx = l&63;
    const float* img = img4 + (size_t)b*C*H*H;
    const float* rinv = ws + rho_off(LEV) + b*D;
    unsigned short h0[8], h1[8], h2[8];
    #pragma unroll
    for (int j=0;j<8;j++){
        int k = k0+j; int c=k/KK, rem=k%KK, ki=rem/K, kj=rem%K;
        int row=ly*S+ki-PD, col=lx*S+kj-PD;
        float x = (row>=0 && row<H && col>=0 && col<H)
                  ? img[(size_t)(c*H+row)*H+col] : 0.f;
        if (ISA) x *= rinv[k];
        unsigned short a = f2bf(x); float r  = x - bf2f(a);
        unsigned short m = f2bf(r); float r2 = r - bf2f(m);
        unsigned short c2 = f2bf(r2);
        h0[j]=a; h1[j]=m; h2[j]=c2;
    }
    int slot = (k0>>3)&3, sw = slot ^ ((l>>1)&3);
    size_t off = (size_t)l*D + (size_t)(k0 & ~31) + sw*8;
    uint4 u0, u1, u2;
    u0.x=h0[0]|((unsigned)h0[1]<<16); u0.y=h0[2]|((unsigned)h0[3]<<16);
    u0.z=h0[4]|((unsigned)h0[5]<<16); u0.w=h0[6]|((unsigned)h0[7]<<16);
    u1.x=h1[0]|((unsigned)h1[1]<<16); u1.y=h1[2]|((unsigned)h1[3]<<16);
    u1.z=h1[4]|((unsigned)h1[5]<<16); u1.w=h1[6]|((unsigned)h1[7]<<16);
    u2.x=h2[0]|((unsigned)h2[1]<<16); u2.y=h2[2]|((unsigned)h2[3]<<16);
    u2.z=h2[4]|((unsigned)h2[5]<<16); u2.w=h2[6]|((unsigned)h2[7]<<16);
    *(uint4*)(base + off)        = u0;
    *(uint4*)(base + PS + off)   = u1;
    *(uint4*)(base + 2*PS + off) = u2;
}

// --- MFMA GEMM (bf16x3, 6 products) + fused score/max/argmax epilogue ---
// grid (32 mblk, 32 lblk) per (lev,b); block 256 = 4 waves in 2x2 (l,m) layout.
template<int LEV>
__launch_bounds__(256, 2)
__global__ void k_gmfma(const unsigned short* __restrict__ planes,
                        float* __restrict__ ws, int b){
    constexpr int D = lev_D(LEV);
    const size_t PS = (size_t)4096 * D;
    __shared__ unsigned short lds[6*128*32];   // 6 tiles [128][32] bf16 = 48KB
    const int tid = threadIdx.x;
    const int w = tid >> 6, lane = tid & 63;
    const int mblk = blockIdx.x, lblk = blockIdx.y;
    const int lw = w >> 1, mw = w & 1;

    f32x4 acc[4][4];
    #pragma unroll
    for (int i=0;i<4;i++)
        #pragma unroll
        for (int j=0;j<4;j++) acc[i][j] = (f32x4){0.f,0.f,0.f,0.f};

    const int srow = lane >> 2, ssl = lane & 3;      // staging: 16 rows x 4 slots
    const int colrow = lane & 15, kk = lane >> 4;    // fragment addressing
    const int swz = (kk ^ ((lane >> 1) & 3)) * 8;    // inverse of split's slot swizzle
    const int aRow0 = lw*64 + colrow;
    const int bRow0 = mw*64 + colrow;

    for (int k0 = 0; k0 < D; k0 += 32){
        #pragma unroll
        for (int p = 0; p < 6; p++){
            const int rb = (p < 3 ? lblk : mblk)*128 + w*32 + srow;
            const unsigned short* gp0 = planes + (size_t)p*PS
                                        + (size_t)rb*D + (size_t)k0 + ssl*8;
            unsigned short* lp0 = &lds[p*4096 + w*1024];
            GLOAD16(gp0, lp0);
            GLOAD16(gp0 + (size_t)16*D, lp0 + 512);
        }
        __syncthreads();

        short8 aF[3][4];
        #pragma unroll
        for (int pa=0; pa<3; pa++)
            #pragma unroll
            for (int i=0;i<4;i++)
                aF[pa][i] = *(const short8*)&lds[pa*4096 + (aRow0 + i*16)*32 + swz];
        #pragma unroll
        for (int pb=0; pb<3; pb++){
            short8 bF[4];
            #pragma unroll
            for (int j=0;j<4;j++)
                bF[j] = *(const short8*)&lds[(3+pb)*4096 + (bRow0 + j*16)*32 + swz];
            const int npa = (pb==0) ? 3 : (pb==1 ? 2 : 1);
            for (int pa=0; pa<npa; pa++)
                #pragma unroll
                for (int i=0;i<4;i++)
                    #pragma unroll
                    for (int j=0;j<4;j++)
                        acc[i][j] = __builtin_amdgcn_mfma_f32_16x16x32_bf16(
                                        aF[pa][i], bF[j], acc[i][j], 0, 0, 0);
        }
        __syncthreads();
    }

    // ---- epilogue: score + per-m max/argmax over this block's 128 l ----
    const float mval = ws[12+LEV];
    const float Dm2 = (float)D * mval * mval;
    const float* Pv  = ws + p_off(LEV)    + b*4096;
    const float* NIv = ws + ninv_off(LEV) + b*4096;
    const float* CSv = ws + csum_off(LEV) + b*4096;
    const int lbase = lblk*128 + lw*64;
    const int mbase = mblk*128 + mw*64;
    const int rgrp = lane >> 4;
    float* smax = (float*)lds;          // [4][64]
    int*   sarg = (int*)&lds[512];      // [4][64]
    #pragma unroll
    for (int j=0;j<4;j++){
        int m = mbase + j*16 + colrow;
        float nv = NIv[m];
        float cmv = -mval*nv*CSv[m] + Dm2;
        float v = -FLT_MAX; int vi = 0x7fffffff;
        #pragma unroll
        for (int i=0;i<4;i++){
            #pragma unroll
            for (int rg=0; rg<4; rg++){
                int l = lbase + i*16 + rgrp*4 + rg;
                float sc = nv*acc[i][j][rg] - mval*Pv[l] + cmv;
                if (sc > v){ v = sc; vi = l; }
            }
        }
        #pragma unroll
        for (int off=16; off<64; off<<=1){
            float ov = __shfl_xor(v, off);
            int   oi = __shfl_xor(vi, off);
            if (ov > v || (ov == v && oi < vi)){ v = ov; vi = oi; }
        }
        if (rgrp == 0){
            smax[w*64 + j*16 + colrow] = v;
            sarg[w*64 + j*16 + colrow] = vi;
        }
    }
    __syncthreads();
    if (tid < 128){
        int mg = tid >> 6, idx = tid & 63;
        float v0 = smax[mg*64 + idx];     int a0 = sarg[mg*64 + idx];
        float v1 = smax[(mg+2)*64 + idx]; int a1 = sarg[(mg+2)*64 + idx];
        if (v1 > v0 || (v1 == v0 && a1 < a0)){ v0 = v1; a0 = a1; }
        int m = mblk*128 + mg*64 + idx;
        int o = (b*32 + lblk)*4096 + m;
        ws[pmax_off(LEV) + o] = v0;
        ((int*)ws)[parg_off(LEV) + o] = a0;
    }
}

// --- fp32 VALU fallback GEMM (used when ws too small for planes) ---
template<int LEV>
__launch_bounds__(256)
__global__ void k_corr(const float* __restrict__ refsr, const float* __restrict__ lrsr,
                       float* __restrict__ ws){
    constexpr int C=LT<LEV>::C, H=LT<LEV>::H, K=LT<LEV>::K, S=LT<LEV>::S, PD=LT<LEV>::P;
    constexpr int D = C*K*K, KK=K*K;
    __shared__ float As[32][64];
    __shared__ float Bs[32][64];
    int tid = threadIdx.x, tr = tid & 15, tc = tid >> 4;
    int my = blockIdx.x, lchunk = blockIdx.y, b = blockIdx.z;
    const float* rimg = refsr + (size_t)b*C*H*H;
    const float* limg = lrsr  + (size_t)b*C*H*H;
    const float* rinv = ws + rho_off(LEV) + b*D;

    float mval = ws[12+LEV];
    float Dm2 = (float)D * mval * mval;
    float niv[4], cm[4];
    #pragma unroll
    for (int j=0;j<4;j++){
        int m = my*64 + tc*4 + j;
        float nv = ws[ninv_off(LEV) + b*4096 + m];
        niv[j] = nv;
        cm[j] = -mval*nv*ws[csum_off(LEV) + b*4096 + m] + Dm2;
    }
    float rmax[4] = {-FLT_MAX,-FLT_MAX,-FLT_MAX,-FLT_MAX};
    int   rarg[4] = {0x7fffffff,0x7fffffff,0x7fffffff,0x7fffffff};

    for (int lt=0; lt<8; lt++){
        int ly = lchunk*8 + lt;
        float acc[4][4];
        #pragma unroll
        for (int i=0;i<4;i++)
            #pragma unroll
            for (int j=0;j<4;j++) acc[i][j]=0.f;

        for (int d0=0; d0<D; d0+=32){
            #pragma unroll
            for (int it=0; it<8; it++){
                int e = tid + it*256;
                int t = e>>6, xx = e&63;
                int d = d0+t;
                int c = d/KK, rem = d%KK, ki = rem/K, kj = rem%K;
                int arow = ly*S+ki-PD, acol = xx*S+kj-PD;
                float av = (arow>=0 && arow<H && acol>=0 && acol<H)
                           ? rimg[(size_t)(c*H+arow)*H + acol] : 0.f;
                As[t][xx] = av * rinv[d];
                int brow = my*S+ki-PD, bcol = xx*S+kj-PD;
                Bs[t][xx] = (brow>=0 && brow<H && bcol>=0 && bcol<H)
                           ? limg[(size_t)(c*H+brow)*H + bcol] : 0.f;
            }
            __syncthreads();
            #pragma unroll 8
            for (int t=0;t<32;t++){
                float av[4], bv[4];
                *(float4*)av = *(const float4*)&As[t][tr*4];
                *(float4*)bv = *(const float4*)&Bs[t][tc*4];
                #pragma unroll
                for (int i=0;i<4;i++)
                    #pragma unroll
                    for (int j=0;j<4;j++)
                        acc[i][j] = fmaf(av[i], bv[j], acc[i][j]);
            }
            __syncthreads();
        }

        float Pl[4];
        #pragma unroll
        for (int i=0;i<4;i++) Pl[i] = ws[p_off(LEV) + b*4096 + ly*64 + tr*4 + i];
        #pragma unroll
        for (int j=0;j<4;j++){
            float v = -FLT_MAX; int vi = 0x7fffffff;
            #pragma unroll
            for (int i=0;i<4;i++){
                float sc = niv[j]*acc[i][j] - mval*Pl[i] + cm[j];
                if (sc > v){ v = sc; vi = ly*64 + tr*4 + i; }
            }
            #pragma unroll
            for (int off=1; off<16; off<<=1){
                float ov = __shfl_xor(v, off, 16);
                int   oi = __shfl_xor(vi, off, 16);
                if (ov > v || (ov == v && oi < vi)){ v = ov; vi = oi; }
            }
            if (v > rmax[j] || (v == rmax[j] && vi < rarg[j])){ rmax[j]=v; rarg[j]=vi; }
        }
    }
    if (tr==0){
        #pragma unroll
        for (int j=0;j<4;j++){
            int m = my*64 + tc*4 + j;
            int o = (b*32 + lchunk)*4096 + m;
            ws[pmax_off(LEV) + o] = rmax[j];
            ((int*)ws)[parg_off(LEV) + o] = rarg[j];
        }
    }
}

// --- reduce l-chunks -> S3,S2,S1,arg outputs ---
__global__ void k_smax(float* __restrict__ ws, float* __restrict__ out,
                       int nch0, int nch1, int nch2){
    int gid = blockIdx.x*256 + threadIdx.x;
    if (gid >= 8192) return;
    int b = gid >> 12, m = gid & 4095;
    int nchs[3] = {nch0, nch1, nch2};
    for (int lev=0; lev<3; lev++){
        float mv = -FLT_MAX; int ma = 0x7fffffff;
        for (int ch=0; ch<nchs[lev]; ch++){
            int o = ((b*32+ch)<<12) + m;
            float v = ws[pmax_off(lev) + o];
            int   a = ((const int*)ws)[parg_off(lev) + o];
            if (v > mv || (v == mv && a < ma)){ mv=v; ma=a; }
        }
        out[lev*8192 + gid] = mv * ws[16+lev];
        if (lev==0){
            out[3*8192 + gid] = (float)ma;
            ((int*)ws)[arg_off() + gid] = ma;
        }
    }
}

// --- T = fold(gather(unfold(ref), arg)) / 9 ---
template<int LEV>
__global__ void k_transfer(const float* __restrict__ ref, const float* __restrict__ wsf,
                           float* __restrict__ outT){
    constexpr int C=LT<LEV>::C, H=LT<LEV>::H, K=LT<LEV>::K, S=LT<LEV>::S, PD=LT<LEV>::P;
    const int* arg = (const int*)wsf + arg_off();
    size_t gid = (size_t)blockIdx.x*256 + threadIdx.x;
    size_t total = (size_t)2*C*H*H;
    if (gid >= total) return;
    int x = (int)(gid % H);
    int y = (int)((gid / H) % H);
    int c = (int)((gid / ((size_t)H*H)) % C);
    int b = (int)(gid / ((size_t)C*H*H));
    const float* rimg = ref + (size_t)(b*C+c)*H*H;
    int byo = (y+PD)/S, ryo = (y+PD)%S;
    int bxo = (x+PD)/S, rxo = (x+PD)%S;
    float acc = 0.f;
    #pragma unroll
    for (int jy=0; jy<3; jy++){
        int ho = byo - jy;
        if (ho < 0 || ho >= 64) continue;
        int ki = ryo + jy*S;
        #pragma unroll
        for (int jx=0; jx<3; jx++){
            int wo = bxo - jx;
            if (wo < 0 || wo >= 64) continue;
            int kj = rxo + jx*S;
            int l = arg[b*4096 + ho*64 + wo];
            int ly = l>>6, lx = l&63;
            int srow = ly*S + ki - PD, scol = lx*S + kj - PD;
            if (srow>=0 && srow<H && scol>=0 && scol<H)
                acc += rimg[srow*H + scol];
        }
    }
    outT[gid] = acc * (1.0f/9.0f);
}

extern "C" void kernel_launch(void* const* d_in, const int* in_sizes, int n_in,
                              void* d_out, int out_size, void* d_ws, size_t ws_size,
                              hipStream_t stream){
    const float* lrsr[3]  = { (const float*)d_in[2], (const float*)d_in[1], (const float*)d_in[0] };
    const float* refsr[3] = { (const float*)d_in[5], (const float*)d_in[4], (const float*)d_in[3] };
    const float* refp[3]  = { (const float*)d_in[8], (const float*)d_in[7], (const float*)d_in[6] };
    float* ws  = (float*)d_ws;
    float* out = (float*)d_out;
    unsigned short* planes = (unsigned short*)((char*)d_ws + PLANE_BASE_BYTES);

    hipMemsetAsync(d_ws, 0, 128, stream);  // zero scalar accumulators

    k_rownorm<0><<<2304/2, 256, 0, stream>>>(refsr[0], ws);
    k_rownorm<1><<<4608/2, 256, 0, stream>>>(refsr[1], ws);
    k_rownorm<2><<<9216/2, 256, 0, stream>>>(refsr[2], ws);
    k_colnorm<0><<<2048, 256, 0, stream>>>(lrsr[0], ws);
    k_colnorm<1><<<2048, 256, 0, stream>>>(lrsr[1], ws);
    k_colnorm<2><<<2048, 256, 0, stream>>>(lrsr[2], ws);
    k_pvec<0><<<2048, 256, 0, stream>>>(refsr[0], ws);
    k_pvec<1><<<2048, 256, 0, stream>>>(refsr[1], ws);
    k_pvec<2><<<2048, 256, 0, stream>>>(refsr[2], ws);
    k_finalize<<<1, 64, 0, stream>>>(ws);

    const size_t need[3] = { PLANE_BASE_BYTES + (size_t)49152*2304,
                             PLANE_BASE_BYTES + (size_t)49152*4608,
                             PLANE_BASE_BYTES + (size_t)49152*9216 };
    int nch[3];
    dim3 cgrid(64, 8, 2);
    dim3 ggrid(32, 32);

    // level 0
    if (ws_size >= need[0]){
        nch[0] = 32;
        for (int b=0; b<2; b++){
            k_split<0,true ><<<4608, 256, 0, stream>>>(refsr[0], ws, planes, b);
            k_split<0,false><<<4608, 256, 0, stream>>>(lrsr[0],  ws, planes + 3*(size_t)4096*2304, b);
            k_gmfma<0><<<ggrid, 256, 0, stream>>>(planes, ws, b);
        }
    } else { nch[0] = 8; k_corr<0><<<cgrid, 256, 0, stream>>>(refsr[0], lrsr[0], ws); }
    // level 1
    if (ws_size >= need[1]){
        nch[1] = 32;
        for (int b=0; b<2; b++){
            k_split<1,true ><<<9216, 256, 0, stream>>>(refsr[1], ws, planes, b);
            k_split<1,false><<<9216, 256, 0, stream>>>(lrsr[1],  ws, planes + 3*(size_t)4096*4608, b);
            k_gmfma<1><<<ggrid, 256, 0, stream>>>(planes, ws, b);
        }
    } else { nch[1] = 8; k_corr<1><<<cgrid, 256, 0, stream>>>(refsr[1], lrsr[1], ws); }
    // level 2
    if (ws_size >= need[2]){
        nch[2] = 32;
        for (int b=0; b<2; b++){
            k_split<2,true ><<<18432, 256, 0, stream>>>(refsr[2], ws, planes, b);
            k_split<2,false><<<18432, 256, 0, stream>>>(lrsr[2],  ws, planes + 3*(size_t)4096*9216, b);
            k_gmfma<2><<<ggrid, 256, 0, stream>>>(planes, ws, b);
        }
    } else { nch[2] = 8; k_corr<2><<<cgrid, 256, 0, stream>>>(refsr[2], lrsr[2], ws); }

    k_smax<<<32, 256, 0, stream>>>(ws, out, nch[0], nch[1], nch[2]);

    k_transfer<0><<< (2*256*64*64)/256,   256, 0, stream>>>(refp[0], ws, out + 32768);
    k_transfer<1><<< (2*128*128*128)/256, 256, 0, stream>>>(refp[1], ws, out + 2129920);
    k_transfer<2><<< (2*64*256*256)/256,  256, 0, stream>>>(refp[2], ws, out + 6324224);
}

// Round 3
// 8529.616 us; speedup vs baseline: 2.8936x; 2.2331x over previous
//
#include <hip/hip_runtime.h>
#include <cfloat>

// ---------------------------------------------------------------------------
// SearchTransfer (TTSR): 3-level patch correlation + argmax + gather/fold.
// Levels: 0 = lv3 (C=256,H=64,k=3,s=1,p=1,D=2304)
//         1 = lv2 (C=128,H=128,k=6,s=2,p=2,D=4608)
//         2 = lv1 (C=64,H=256,k=12,s=4,p=4,D=9216)
// L = M = 4096 patch positions per batch, B = 2.
//
// score(l,m) = ninv[m]*G[l,m] - mval*P[l] - mval*ninv[m]*csum[m] + D*mval^2
// G[l,m] = sum_d (u_rs[d,l]*rinv[d]) * u_lr[d,m]
//
// G via bf16x3-split MFMA (6 products, fp32 accumulate).
// K-chunked (chunk<=2304 so planes stay L3-resident): planes per chunk ->
// MFMA GEMM accumulates into fp32 G[4096][4096] in ws -> k_score does
// score+max/argmax. lev0 uses the fused single-pass (no G) path.
// ---------------------------------------------------------------------------

typedef short short8 __attribute__((ext_vector_type(8)));
typedef float f32x4  __attribute__((ext_vector_type(4)));

template<int LEV> struct LT;
template<> struct LT<0> { static constexpr int C=256, H=64,  K=3,  S=1, P=1; };
template<> struct LT<1> { static constexpr int C=128, H=128, K=6,  S=2, P=2; };
template<> struct LT<2> { static constexpr int C=64,  H=256, K=12, S=4, P=4; };

__host__ __device__ constexpr int lev_D(int lev){ return lev==0?2304:(lev==1?4608:9216); }
// ws float-index offsets
__host__ __device__ constexpr int rho_off(int lev){ return 32 + (lev>0?2*2304:0) + (lev>1?2*4608:0); } // end 32288
__host__ __device__ constexpr int p_off(int lev)   { return 32288  + lev*8192;   } // end 56864
__host__ __device__ constexpr int ninv_off(int lev){ return 56864  + lev*8192;   } // end 81440
__host__ __device__ constexpr int csum_off(int lev){ return 81440  + lev*8192;   } // end 106016
__host__ __device__ constexpr int pmax_off(int lev){ return 106016 + lev*262144; } // [b][32][4096], end 892448
__host__ __device__ constexpr int parg_off(int lev){ return 892448 + lev*262144; } // int, end 1678880
__host__ __device__ constexpr int arg_off(){ return 1678880; }                     // int, 8192
// G fp32 buffer at ws+8MB (float idx 2097152), 64MB. Chunked planes at ws+72MB.
static constexpr size_t G_BASE_BYTES      = 8ull  << 20;
static constexpr size_t CHUNK_PLANE_BYTES = 72ull << 20;

__device__ inline unsigned short f2bf(float f){
    unsigned int u = __float_as_uint(f);
    return (unsigned short)((u + 0x7fffu + ((u >> 16) & 1u)) >> 16);
}
__device__ inline float bf2f(unsigned short h){ return __uint_as_float(((unsigned)h) << 16); }

#define GLOAD16(g, l) __builtin_amdgcn_global_load_lds( \
    (const __attribute__((address_space(1))) unsigned int*)(g), \
    (__attribute__((address_space(3))) unsigned int*)(l), 16, 0, 0)

// --- per-(b,d) row norm of refsr unfold (normalize axis=2) + scalar accums ---
template<int LEV>
__global__ void k_rownorm(const float* __restrict__ refsr, float* __restrict__ ws){
    constexpr int C=LT<LEV>::C, H=LT<LEV>::H, K=LT<LEV>::K, S=LT<LEV>::S, PD=LT<LEV>::P;
    constexpr int D = C*K*K, KK=K*K;
    int tid = threadIdx.x, lane = tid & 63;
    int wid = (blockIdx.x*blockDim.x + tid) >> 6;
    if (wid >= 2*D) return;
    int b = wid / D, d = wid % D;
    int c = d/KK, rem = d%KK, ki = rem/K, kj = rem%K;
    const float* img = refsr + (size_t)(b*C + c)*H*H;
    float sum=0.f, ssq=0.f;
    for (int idx=lane; idx<4096; idx+=64){
        int ho=idx>>6, wo=idx&63;
        int row = ho*S+ki-PD, col = wo*S+kj-PD;
        if (row>=0 && row<H && col>=0 && col<H){
            float v = img[row*H+col]; sum += v; ssq += v*v;
        }
    }
    #pragma unroll
    for (int off=32; off; off>>=1){ sum += __shfl_xor(sum,off); ssq += __shfl_xor(ssq,off); }
    if (lane==0){
        float rinv = 1.0f / fmaxf(sqrtf(ssq), 1e-12f);
        ws[rho_off(LEV) + b*D + d] = rinv;
        atomicAdd(&ws[LEV*4+0], sum*rinv);
        atomicAdd(&ws[LEV*4+1], ssq*rinv*rinv);
    }
}

// --- per-(b,m) column norm of lrsr unfold (normalize axis=1) + scalar accums ---
template<int LEV>
__global__ void k_colnorm(const float* __restrict__ lrsr, float* __restrict__ ws){
    constexpr int C=LT<LEV>::C, H=LT<LEV>::H, K=LT<LEV>::K, S=LT<LEV>::S, PD=LT<LEV>::P;
    constexpr int D = C*K*K, KK=K*K;
    int tid = threadIdx.x, lane = tid & 63;
    int wid = (blockIdx.x*blockDim.x + tid) >> 6;
    if (wid >= 8192) return;
    int b = wid >> 12, m = wid & 4095;
    int my = m>>6, mx = m&63;
    float sum=0.f, ssq=0.f;
    for (int d=lane; d<D; d+=64){
        int c = d/KK, rem = d%KK, ki = rem/K, kj = rem%K;
        int row = my*S+ki-PD, col = mx*S+kj-PD;
        if (row>=0 && row<H && col>=0 && col<H){
            float v = lrsr[((size_t)(b*C+c)*H + row)*H + col]; sum += v; ssq += v*v;
        }
    }
    #pragma unroll
    for (int off=32; off; off>>=1){ sum += __shfl_xor(sum,off); ssq += __shfl_xor(ssq,off); }
    if (lane==0){
        float ninv = 1.0f / fmaxf(sqrtf(ssq), 1e-12f);
        ws[ninv_off(LEV) + wid] = ninv;
        ws[csum_off(LEV) + wid] = sum;
        atomicAdd(&ws[LEV*4+2], sum*ninv);
        atomicAdd(&ws[LEV*4+3], ssq*ninv*ninv);
    }
}

// --- P[b,l] = sum_d u_rs[d,l] * rinv[d] ---
template<int LEV>
__global__ void k_pvec(const float* __restrict__ refsr, float* __restrict__ ws){
    constexpr int C=LT<LEV>::C, H=LT<LEV>::H, K=LT<LEV>::K, S=LT<LEV>::S, PD=LT<LEV>::P;
    constexpr int D = C*K*K, KK=K*K;
    int tid = threadIdx.x, lane = tid & 63;
    int wid = (blockIdx.x*blockDim.x + tid) >> 6;
    if (wid >= 8192) return;
    int b = wid >> 12, l = wid & 4095;
    int ly = l>>6, lx = l&63;
    const float* rinv = ws + rho_off(LEV) + b*D;
    float sum=0.f;
    for (int d=lane; d<D; d+=64){
        int c = d/KK, rem = d%KK, ki = rem/K, kj = rem%K;
        int row = ly*S+ki-PD, col = lx*S+kj-PD;
        if (row>=0 && row<H && col>=0 && col<H)
            sum += refsr[((size_t)(b*C+c)*H + row)*H + col] * rinv[d];
    }
    #pragma unroll
    for (int off=32; off; off>>=1) sum += __shfl_xor(sum,off);
    if (lane==0) ws[p_off(LEV) + wid] = sum;
}

// --- scalars: mval per level, scales (incl. reference's ym3 bug in R2) ---
__global__ void k_finalize(float* __restrict__ ws){
    if (threadIdx.x || blockIdx.x) return;
    float gx2[3], gy2[3];
    for (int lev=0; lev<3; lev++){
        float BDL = 2.0f * (float)lev_D(lev) * 4096.0f;
        float m = ws[lev*4+0] / BDL;
        ws[12+lev] = m;
        gx2[lev] = ws[lev*4+1] - 2.f*m*ws[lev*4+0] + BDL*m*m;
        gy2[lev] = ws[lev*4+3] - 2.f*m*ws[lev*4+2] + BDL*m*m;
    }
    ws[16+0] = 1.0f/(sqrtf(gx2[0])*sqrtf(gy2[0]));
    ws[16+1] = 1.0f/(sqrtf(gx2[1])*sqrtf(gy2[0]));   // reference bug: uses ym3
    ws[16+2] = 1.0f/(sqrtf(gx2[2])*sqrtf(gy2[2]));
}

// --- bf16x3 split materialization for K-range [kb0, kb0+kd):
//     planes[q][row][kd] local-K layout, 16B slots swizzled: slot ^= (row>>1)&3.
template<int LEV, bool ISA>
__global__ void k_split(const float* __restrict__ img4, const float* __restrict__ ws,
                        unsigned short* __restrict__ base, int b, int kb0, int kd){
    constexpr int C=LT<LEV>::C, H=LT<LEV>::H, K=LT<LEV>::K, S=LT<LEV>::S, PD=LT<LEV>::P;
    constexpr int KK=K*K;
    const size_t PS = (size_t)4096 * kd;
    int gid = blockIdx.x*256 + threadIdx.x;
    int kslots = kd >> 3;
    if (gid >= 4096*kslots) return;
    int kb = gid % kslots, l = gid / kslots;
    int kl0 = kb*8;
    int ly = l>>6, lx = l&63;
    const float* img = img4 + (size_t)b*C*H*H;
    const float* rinv = ws + rho_off(LEV) + b*lev_D(LEV);
    unsigned short h0[8], h1[8], h2[8];
    #pragma unroll
    for (int j=0;j<8;j++){
        int k = kb0 + kl0 + j; int c=k/KK, rem=k%KK, ki=rem/K, kj=rem%K;
        int row=ly*S+ki-PD, col=lx*S+kj-PD;
        float x = (row>=0 && row<H && col>=0 && col<H)
                  ? img[(size_t)(c*H+row)*H+col] : 0.f;
        if (ISA) x *= rinv[k];
        unsigned short a = f2bf(x); float r  = x - bf2f(a);
        unsigned short m = f2bf(r); float r2 = r - bf2f(m);
        unsigned short c2 = f2bf(r2);
        h0[j]=a; h1[j]=m; h2[j]=c2;
    }
    int slot = (kl0>>3)&3, sw = slot ^ ((l>>1)&3);
    size_t off = (size_t)l*kd + (size_t)(kl0 & ~31) + sw*8;
    uint4 u0, u1, u2;
    u0.x=h0[0]|((unsigned)h0[1]<<16); u0.y=h0[2]|((unsigned)h0[3]<<16);
    u0.z=h0[4]|((unsigned)h0[5]<<16); u0.w=h0[6]|((unsigned)h0[7]<<16);
    u1.x=h1[0]|((unsigned)h1[1]<<16); u1.y=h1[2]|((unsigned)h1[3]<<16);
    u1.z=h1[4]|((unsigned)h1[5]<<16); u1.w=h1[6]|((unsigned)h1[7]<<16);
    u2.x=h2[0]|((unsigned)h2[1]<<16); u2.y=h2[2]|((unsigned)h2[3]<<16);
    u2.z=h2[4]|((unsigned)h2[5]<<16); u2.w=h2[6]|((unsigned)h2[7]<<16);
    *(uint4*)(base + off)        = u0;
    *(uint4*)(base + PS + off)   = u1;
    *(uint4*)(base + 2*PS + off) = u2;
}

// --- MFMA GEMM (bf16x3, 6 products) over K-chunk of length kd.
// MODE 0: fused score/max/argmax epilogue (single chunk == full D).
// MODE 1: first chunk, write acc to G.  MODE 2: accumulate into G.
// grid (32 mblk, 32 lblk); block 256 = 4 waves in 2x2 (l,m) layout.
template<int LEV, int MODE>
__launch_bounds__(256, 2)
__global__ void k_gmfma(const unsigned short* __restrict__ planes,
                        float* __restrict__ ws, float* __restrict__ G,
                        int b, int kd){
    const size_t PS = (size_t)4096 * kd;
    __shared__ unsigned short lds[6*128*32];   // 6 tiles [128][32] bf16 = 48KB
    const int tid = threadIdx.x;
    const int w = tid >> 6, lane = tid & 63;
    const int mblk = blockIdx.x, lblk = blockIdx.y;
    const int lw = w >> 1, mw = w & 1;

    f32x4 acc[4][4];
    #pragma unroll
    for (int i=0;i<4;i++)
        #pragma unroll
        for (int j=0;j<4;j++) acc[i][j] = (f32x4){0.f,0.f,0.f,0.f};

    const int srow = lane >> 2, ssl = lane & 3;      // staging: 16 rows x 4 slots
    const int colrow = lane & 15, kk = lane >> 4;    // fragment addressing
    const int swz = (kk ^ ((lane >> 1) & 3)) * 8;    // inverse of split's slot swizzle
    const int aRow0 = lw*64 + colrow;
    const int bRow0 = mw*64 + colrow;

    for (int k0 = 0; k0 < kd; k0 += 32){
        #pragma unroll
        for (int p = 0; p < 6; p++){
            const int rb = (p < 3 ? lblk : mblk)*128 + w*32 + srow;
            const unsigned short* gp0 = planes + (size_t)p*PS
                                        + (size_t)rb*kd + (size_t)k0 + ssl*8;
            unsigned short* lp0 = &lds[p*4096 + w*1024];
            GLOAD16(gp0, lp0);
            GLOAD16(gp0 + (size_t)16*kd, lp0 + 512);
        }
        __syncthreads();

        short8 aF[3][4];
        #pragma unroll
        for (int pa=0; pa<3; pa++)
            #pragma unroll
            for (int i=0;i<4;i++)
                aF[pa][i] = *(const short8*)&lds[pa*4096 + (aRow0 + i*16)*32 + swz];
        #pragma unroll
        for (int pb=0; pb<3; pb++){
            short8 bF[4];
            #pragma unroll
            for (int j=0;j<4;j++)
                bF[j] = *(const short8*)&lds[(3+pb)*4096 + (bRow0 + j*16)*32 + swz];
            const int npa = (pb==0) ? 3 : (pb==1 ? 2 : 1);
            for (int pa=0; pa<npa; pa++)
                #pragma unroll
                for (int i=0;i<4;i++)
                    #pragma unroll
                    for (int j=0;j<4;j++)
                        acc[i][j] = __builtin_amdgcn_mfma_f32_16x16x32_bf16(
                                        aF[pa][i], bF[j], acc[i][j], 0, 0, 0);
        }
        __syncthreads();
    }

    const int lbase = lblk*128 + lw*64;
    const int mbase = mblk*128 + mw*64;
    const int rgrp = lane >> 4;

    if (MODE != 0){
        // accumulate into G[l][m]
        #pragma unroll
        for (int i=0;i<4;i++){
            #pragma unroll
            for (int rg=0; rg<4; rg++){
                float* gp = G + (size_t)(lbase + i*16 + rgrp*4 + rg)*4096
                              + mbase + colrow;
                #pragma unroll
                for (int j=0;j<4;j++){
                    float v = acc[i][j][rg];
                    if (MODE == 2) v += gp[j*16];
                    gp[j*16] = v;
                }
            }
        }
        return;
    }

    // ---- MODE 0 epilogue: score + per-m max/argmax over this block's 128 l ----
    constexpr int D = lev_D(LEV);
    const float mval = ws[12+LEV];
    const float Dm2 = (float)D * mval * mval;
    const float* Pv  = ws + p_off(LEV)    + b*4096;
    const float* NIv = ws + ninv_off(LEV) + b*4096;
    const float* CSv = ws + csum_off(LEV) + b*4096;
    float* smax = (float*)lds;          // [4][64]
    int*   sarg = (int*)&lds[512];      // [4][64]
    #pragma unroll
    for (int j=0;j<4;j++){
        int m = mbase + j*16 + colrow;
        float nv = NIv[m];
        float cmv = -mval*nv*CSv[m] + Dm2;
        float v = -FLT_MAX; int vi = 0x7fffffff;
        #pragma unroll
        for (int i=0;i<4;i++){
            #pragma unroll
            for (int rg=0; rg<4; rg++){
                int l = lbase + i*16 + rgrp*4 + rg;
                float sc = nv*acc[i][j][rg] - mval*Pv[l] + cmv;
                if (sc > v){ v = sc; vi = l; }
            }
        }
        #pragma unroll
        for (int off=16; off<64; off<<=1){
            float ov = __shfl_xor(v, off);
            int   oi = __shfl_xor(vi, off);
            if (ov > v || (ov == v && oi < vi)){ v = ov; vi = oi; }
        }
        if (rgrp == 0){
            smax[w*64 + j*16 + colrow] = v;
            sarg[w*64 + j*16 + colrow] = vi;
        }
    }
    __syncthreads();
    if (tid < 128){
        int mg = tid >> 6, idx = tid & 63;
        float v0 = smax[mg*64 + idx];     int a0 = sarg[mg*64 + idx];
        float v1 = smax[(mg+2)*64 + idx]; int a1 = sarg[(mg+2)*64 + idx];
        if (v1 > v0 || (v1 == v0 && a1 < a0)){ v0 = v1; a0 = a1; }
        int m = mblk*128 + mg*64 + idx;
        int o = (b*32 + lblk)*4096 + m;
        ws[pmax_off(LEV) + o] = v0;
        ((int*)ws)[parg_off(LEV) + o] = a0;
    }
}

// --- score + max/argmax from accumulated G; grid (64 mblk, 8 lsplit) ---
template<int LEV>
__global__ void k_score(const float* __restrict__ G, float* __restrict__ ws, int b){
    constexpr int D = lev_D(LEV);
    __shared__ float smax[4][64];
    __shared__ int   sarg[4][64];
    int tid = threadIdx.x, mloc = tid & 63, r = tid >> 6;
    int m = blockIdx.x*64 + mloc;
    int l0 = blockIdx.y*512;
    float mval = ws[12+LEV];
    float nv = ws[ninv_off(LEV) + b*4096 + m];
    float cmv = -mval*nv*ws[csum_off(LEV) + b*4096 + m] + (float)D*mval*mval;
    const float* Pv = ws + p_off(LEV) + b*4096;
    float best = -FLT_MAX; int bi = 0x7fffffff;
    for (int lt=0; lt<128; lt++){
        int l = l0 + lt*4 + r;
        float sc = nv*G[(size_t)l*4096 + m] - mval*Pv[l] + cmv;
        if (sc > best){ best = sc; bi = l; }
    }
    smax[r][mloc] = best; sarg[r][mloc] = bi;
    __syncthreads();
    if (tid < 64){
        float v = smax[0][tid]; int vi = sarg[0][tid];
        #pragma unroll
        for (int rr=1; rr<4; rr++){
            float ov = smax[rr][tid]; int oi = sarg[rr][tid];
            if (ov > v || (ov == v && oi < vi)){ v = ov; vi = oi; }
        }
        int o = (b*32 + blockIdx.y)*4096 + blockIdx.x*64 + tid;
        ws[pmax_off(LEV) + o] = v;
        ((int*)ws)[parg_off(LEV) + o] = vi;
    }
}

// --- fp32 VALU fallback GEMM (last-resort) ---
template<int LEV>
__launch_bounds__(256)
__global__ void k_corr(const float* __restrict__ refsr, const float* __restrict__ lrsr,
                       float* __restrict__ ws){
    constexpr int C=LT<LEV>::C, H=LT<LEV>::H, K=LT<LEV>::K, S=LT<LEV>::S, PD=LT<LEV>::P;
    constexpr int D = C*K*K, KK=K*K;
    __shared__ float As[32][64];
    __shared__ float Bs[32][64];
    int tid = threadIdx.x, tr = tid & 15, tc = tid >> 4;
    int my = blockIdx.x, lchunk = blockIdx.y, b = blockIdx.z;
    const float* rimg = refsr + (size_t)b*C*H*H;
    const float* limg = lrsr  + (size_t)b*C*H*H;
    const float* rinv = ws + rho_off(LEV) + b*D;

    float mval = ws[12+LEV];
    float Dm2 = (float)D * mval * mval;
    float niv[4], cm[4];
    #pragma unroll
    for (int j=0;j<4;j++){
        int m = my*64 + tc*4 + j;
        float nv = ws[ninv_off(LEV) + b*4096 + m];
        niv[j] = nv;
        cm[j] = -mval*nv*ws[csum_off(LEV) + b*4096 + m] + Dm2;
    }
    float rmax[4] = {-FLT_MAX,-FLT_MAX,-FLT_MAX,-FLT_MAX};
    int   rarg[4] = {0x7fffffff,0x7fffffff,0x7fffffff,0x7fffffff};

    for (int lt=0; lt<8; lt++){
        int ly = lchunk*8 + lt;
        float acc[4][4];
        #pragma unroll
        for (int i=0;i<4;i++)
            #pragma unroll
            for (int j=0;j<4;j++) acc[i][j]=0.f;

        for (int d0=0; d0<D; d0+=32){
            #pragma unroll
            for (int it=0; it<8; it++){
                int e = tid + it*256;
                int t = e>>6, xx = e&63;
                int d = d0+t;
                int c = d/KK, rem = d%KK, ki = rem/K, kj = rem%K;
                int arow = ly*S+ki-PD, acol = xx*S+kj-PD;
                float av = (arow>=0 && arow<H && acol>=0 && acol<H)
                           ? rimg[(size_t)(c*H+arow)*H + acol] : 0.f;
                As[t][xx] = av * rinv[d];
                int brow = my*S+ki-PD, bcol = xx*S+kj-PD;
                Bs[t][xx] = (brow>=0 && brow<H && bcol>=0 && bcol<H)
                           ? limg[(size_t)(c*H+brow)*H + bcol] : 0.f;
            }
            __syncthreads();
            #pragma unroll 8
            for (int t=0;t<32;t++){
                float av[4], bv[4];
                *(float4*)av = *(const float4*)&As[t][tr*4];
                *(float4*)bv = *(const float4*)&Bs[t][tc*4];
                #pragma unroll
                for (int i=0;i<4;i++)
                    #pragma unroll
                    for (int j=0;j<4;j++)
                        acc[i][j] = fmaf(av[i], bv[j], acc[i][j]);
            }
            __syncthreads();
        }

        float Pl[4];
        #pragma unroll
        for (int i=0;i<4;i++) Pl[i] = ws[p_off(LEV) + b*4096 + ly*64 + tr*4 + i];
        #pragma unroll
        for (int j=0;j<4;j++){
            float v = -FLT_MAX; int vi = 0x7fffffff;
            #pragma unroll
            for (int i=0;i<4;i++){
                float sc = niv[j]*acc[i][j] - mval*Pl[i] + cm[j];
                if (sc > v){ v = sc; vi = ly*64 + tr*4 + i; }
            }
            #pragma unroll
            for (int off=1; off<16; off<<=1){
                float ov = __shfl_xor(v, off, 16);
                int   oi = __shfl_xor(vi, off, 16);
                if (ov > v || (ov == v && oi < vi)){ v = ov; vi = oi; }
            }
            if (v > rmax[j] || (v == rmax[j] && vi < rarg[j])){ rmax[j]=v; rarg[j]=vi; }
        }
    }
    if (tr==0){
        #pragma unroll
        for (int j=0;j<4;j++){
            int m = my*64 + tc*4 + j;
            int o = (b*32 + lchunk)*4096 + m;
            ws[pmax_off(LEV) + o] = rmax[j];
            ((int*)ws)[parg_off(LEV) + o] = rarg[j];
        }
    }
}

// --- reduce l-chunks -> S3,S2,S1,arg outputs ---
__global__ void k_smax(float* __restrict__ ws, float* __restrict__ out,
                       int nch0, int nch1, int nch2){
    int gid = blockIdx.x*256 + threadIdx.x;
    if (gid >= 8192) return;
    int b = gid >> 12, m = gid & 4095;
    int nchs[3] = {nch0, nch1, nch2};
    for (int lev=0; lev<3; lev++){
        float mv = -FLT_MAX; int ma = 0x7fffffff;
        for (int ch=0; ch<nchs[lev]; ch++){
            int o = ((b*32+ch)<<12) + m;
            float v = ws[pmax_off(lev) + o];
            int   a = ((const int*)ws)[parg_off(lev) + o];
            if (v > mv || (v == mv && a < ma)){ mv=v; ma=a; }
        }
        out[lev*8192 + gid] = mv * ws[16+lev];
        if (lev==0){
            out[3*8192 + gid] = (float)ma;
            ((int*)ws)[arg_off() + gid] = ma;
        }
    }
}

// --- T = fold(gather(unfold(ref), arg)) / 9 ---
template<int LEV>
__global__ void k_transfer(const float* __restrict__ ref, const float* __restrict__ wsf,
                           float* __restrict__ outT){
    constexpr int C=LT<LEV>::C, H=LT<LEV>::H, K=LT<LEV>::K, S=LT<LEV>::S, PD=LT<LEV>::P;
    const int* arg = (const int*)wsf + arg_off();
    size_t gid = (size_t)blockIdx.x*256 + threadIdx.x;
    size_t total = (size_t)2*C*H*H;
    if (gid >= total) return;
    int x = (int)(gid % H);
    int y = (int)((gid / H) % H);
    int c = (int)((gid / ((size_t)H*H)) % C);
    int b = (int)(gid / ((size_t)C*H*H));
    const float* rimg = ref + (size_t)(b*C+c)*H*H;
    int byo = (y+PD)/S, ryo = (y+PD)%S;
    int bxo = (x+PD)/S, rxo = (x+PD)%S;
    float acc = 0.f;
    #pragma unroll
    for (int jy=0; jy<3; jy++){
        int ho = byo - jy;
        if (ho < 0 || ho >= 64) continue;
        int ki = ryo + jy*S;
        #pragma unroll
        for (int jx=0; jx<3; jx++){
            int wo = bxo - jx;
            if (wo < 0 || wo >= 64) continue;
            int kj = rxo + jx*S;
            int l = arg[b*4096 + ho*64 + wo];
            int ly = l>>6, lx = l&63;
            int srow = ly*S + ki - PD, scol = lx*S + kj - PD;
            if (srow>=0 && srow<H && scol>=0 && scol<H)
                acc += rimg[srow*H + scol];
        }
    }
    outT[gid] = acc * (1.0f/9.0f);
}

template<int LEV>
static void run_level(const float* refsr, const float* lrsr, float* ws,
                      size_t ws_size, hipStream_t stream, int* nch){
    constexpr int D = lev_D(LEV);
    const size_t PBfull = (size_t)49152 * D;   // 4096 rows * D * 2B * 6 planes
    // single-pass fused path: only when planes stay L3-resident (D<=2304)
    if (D <= 2304 && ws_size >= G_BASE_BYTES + PBfull){
        unsigned short* pl = (unsigned short*)((char*)ws + G_BASE_BYTES);
        nch[LEV] = 32;
        for (int b=0; b<2; b++){
            k_split<LEV,true ><<<2*D, 256, 0, stream>>>(refsr, ws, pl, b, 0, D);
            k_split<LEV,false><<<2*D, 256, 0, stream>>>(lrsr,  ws, pl + (size_t)3*4096*D, b, 0, D);
            k_gmfma<LEV,0><<<dim3(32,32), 256, 0, stream>>>(pl, ws, nullptr, b, D);
        }
        return;
    }
    // chunked path: K-chunks (<=2304) + fp32 G accumulation
    int kd = 0;
    for (int c = 2304; c >= 288; c >>= 1){
        if (D % c) continue;
        if (ws_size >= CHUNK_PLANE_BYTES + (size_t)49152*c){ kd = c; break; }
    }
    if (!kd){
        nch[LEV] = 8;
        k_corr<LEV><<<dim3(64,8,2), 256, 0, stream>>>(refsr, lrsr, ws);
        return;
    }
    unsigned short* pl = (unsigned short*)((char*)ws + CHUNK_PLANE_BYTES);
    float* G = ws + (G_BASE_BYTES >> 2);
    nch[LEV] = 8;
    const int nkc = D / kd;
    for (int b=0; b<2; b++){
        for (int kc=0; kc<nkc; kc++){
            k_split<LEV,true ><<<2*kd, 256, 0, stream>>>(refsr, ws, pl, b, kc*kd, kd);
            k_split<LEV,false><<<2*kd, 256, 0, stream>>>(lrsr,  ws, pl + (size_t)3*4096*kd, b, kc*kd, kd);
            if (kc == 0) k_gmfma<LEV,1><<<dim3(32,32), 256, 0, stream>>>(pl, ws, G, b, kd);
            else         k_gmfma<LEV,2><<<dim3(32,32), 256, 0, stream>>>(pl, ws, G, b, kd);
        }
        k_score<LEV><<<dim3(64,8), 256, 0, stream>>>(G, ws, b);
    }
}

extern "C" void kernel_launch(void* const* d_in, const int* in_sizes, int n_in,
                              void* d_out, int out_size, void* d_ws, size_t ws_size,
                              hipStream_t stream){
    const float* lrsr[3]  = { (const float*)d_in[2], (const float*)d_in[1], (const float*)d_in[0] };
    const float* refsr[3] = { (const float*)d_in[5], (const float*)d_in[4], (const float*)d_in[3] };
    const float* refp[3]  = { (const float*)d_in[8], (const float*)d_in[7], (const float*)d_in[6] };
    float* ws  = (float*)d_ws;
    float* out = (float*)d_out;

    hipMemsetAsync(d_ws, 0, 128, stream);  // zero scalar accumulators

    k_rownorm<0><<<2304/2, 256, 0, stream>>>(refsr[0], ws);
    k_rownorm<1><<<4608/2, 256, 0, stream>>>(refsr[1], ws);
    k_rownorm<2><<<9216/2, 256, 0, stream>>>(refsr[2], ws);
    k_colnorm<0><<<2048, 256, 0, stream>>>(lrsr[0], ws);
    k_colnorm<1><<<2048, 256, 0, stream>>>(lrsr[1], ws);
    k_colnorm<2><<<2048, 256, 0, stream>>>(lrsr[2], ws);
    k_pvec<0><<<2048, 256, 0, stream>>>(refsr[0], ws);
    k_pvec<1><<<2048, 256, 0, stream>>>(refsr[1], ws);
    k_pvec<2><<<2048, 256, 0, stream>>>(refsr[2], ws);
    k_finalize<<<1, 64, 0, stream>>>(ws);

    int nch[3];
    run_level<0>(refsr[0], lrsr[0], ws, ws_size, stream, nch);
    run_level<1>(refsr[1], lrsr[1], ws, ws_size, stream, nch);
    run_level<2>(refsr[2], lrsr[2], ws, ws_size, stream, nch);

    k_smax<<<32, 256, 0, stream>>>(ws, out, nch[0], nch[1], nch[2]);

    k_transfer<0><<< (2*256*64*64)/256,   256, 0, stream>>>(refp[0], ws, out + 32768);
    k_transfer<1><<< (2*128*128*128)/256, 256, 0, stream>>>(refp[1], ws, out + 2129920);
    k_transfer<2><<< (2*64*256*256)/256,  256, 0, stream>>>(refp[2], ws, out + 6324224);
}

// Round 4
// 7115.285 us; speedup vs baseline: 3.4688x; 1.1988x over previous
//
#include <hip/hip_runtime.h>
#include <cfloat>

// ---------------------------------------------------------------------------
// SearchTransfer (TTSR): 3-level patch correlation + argmax + gather/fold.
// Levels: 0 = lv3 (C=256,H=64,k=3,s=1,p=1,D=2304)
//         1 = lv2 (C=128,H=128,k=6,s=2,p=2,D=4608)
//         2 = lv1 (C=64,H=256,k=12,s=4,p=4,D=9216)
// L = M = 4096 patch positions per batch, B = 2.
//
// score(l,m) = ninv[m]*G[l,m] - mval*P[l] - mval*ninv[m]*csum[m] + D*mval^2
// G[l,m] = sum_d (u_rs[d,l]*rinv[d]) * u_lr[d,m]   (bf16x3 split MFMA, 6 prods)
//
// Scalar dependency order: mval/gx2 from rownorm (early, rs side only);
// ninv per (lev,b) after that b's plane stats; scale (needs lr-side gy2 over
// both b) applied only in k_smax (late). This lets lev0/lev1 run the fused
// MODE0 epilogue; lev2 K-chunks accumulate into fp32 G then k_score.
// ---------------------------------------------------------------------------

typedef short short8 __attribute__((ext_vector_type(8)));
typedef float f32x4  __attribute__((ext_vector_type(4)));

template<int LEV> struct LT;
template<> struct LT<0> { static constexpr int C=256, H=64,  K=3,  S=1, P=1; };
template<> struct LT<1> { static constexpr int C=128, H=128, K=6,  S=2, P=2; };
template<> struct LT<2> { static constexpr int C=64,  H=256, K=12, S=4, P=4; };

__host__ __device__ constexpr int lev_D(int lev){ return lev==0?2304:(lev==1?4608:9216); }
// ws float-index offsets
// [0,192): scalar slots: lev*64 + q*16 + slot   (q: 0=sum_rs,1=ssq_rs,2=sum_lr,3=ssq_lr)
// 200+lev: mval   204+lev: scale   208: gy2_lev0   212+lev: gx2
__host__ __device__ constexpr int rho_off(int lev){ return 256 + (lev>0?2*2304:0) + (lev>1?2*4608:0); } // end 32512
__host__ __device__ constexpr int p_off(int lev)   { return 32512  + lev*8192;   } // end 57088
__host__ __device__ constexpr int ninv_off(int lev){ return 57088  + lev*8192;   } // end 81664 (ssq until levfin)
__host__ __device__ constexpr int csum_off(int lev){ return 81664  + lev*8192;   } // end 106240
__host__ __device__ constexpr int pmax_off(int lev){ return 106240 + lev*262144; } // [b][32][4096], end 892672
__host__ __device__ constexpr int parg_off(int lev){ return 892672 + lev*262144; } // int, end 1679104
__host__ __device__ constexpr int arg_off(){ return 1679104; }                     // int, 8192
static constexpr size_t G_BASE_BYTES      = 8ull  << 20;  // fp32 G [4096][4096] = 64MB
static constexpr size_t CHUNK_PLANE_BYTES = 72ull << 20;  // chunked planes base

__device__ inline unsigned short f2bf(float f){
    unsigned int u = __float_as_uint(f);
    return (unsigned short)((u + 0x7fffu + ((u >> 16) & 1u)) >> 16);
}
__device__ inline float bf2f(unsigned short h){ return __uint_as_float(((unsigned)h) << 16); }

#define GLOAD16(g, l) __builtin_amdgcn_global_load_lds( \
    (const __attribute__((address_space(1))) unsigned int*)(g), \
    (__attribute__((address_space(3))) unsigned int*)(l), 16, 0, 0)

// --- per-(b,d) row norm of refsr unfold (normalize axis=2) + rs scalar slots ---
template<int LEV>
__global__ void k_rownorm(const float* __restrict__ refsr, float* __restrict__ ws){
    constexpr int C=LT<LEV>::C, H=LT<LEV>::H, K=LT<LEV>::K, S=LT<LEV>::S, PD=LT<LEV>::P;
    constexpr int D = C*K*K, KK=K*K;
    __shared__ float sh0[4], sh1[4];
    int tid = threadIdx.x, lane = tid & 63, w = tid >> 6;
    int wid = (blockIdx.x*blockDim.x + tid) >> 6;   // grid = D/2 blocks -> 2D waves
    int b = wid / D, d = wid % D;
    int c = d/KK, rem = d%KK, ki = rem/K, kj = rem%K;
    const float* img = refsr + (size_t)(b*C + c)*H*H;
    float sum=0.f, ssq=0.f;
    for (int idx=lane; idx<4096; idx+=64){
        int ho=idx>>6, wo=idx&63;
        int row = ho*S+ki-PD, col = wo*S+kj-PD;
        if (row>=0 && row<H && col>=0 && col<H){
            float v = img[row*H+col]; sum += v; ssq += v*v;
        }
    }
    #pragma unroll
    for (int off=32; off; off>>=1){ sum += __shfl_xor(sum,off); ssq += __shfl_xor(ssq,off); }
    if (lane==0){
        float rinv = 1.0f / fmaxf(sqrtf(ssq), 1e-12f);
        ws[rho_off(LEV) + b*D + d] = rinv;
        sh0[w] = sum*rinv;
        sh1[w] = ssq*rinv*rinv;
    }
    __syncthreads();
    if (tid==0){
        int s = blockIdx.x & 15;
        atomicAdd(&ws[LEV*64 + 0*16 + s], sh0[0]+sh0[1]+sh0[2]+sh0[3]);
        atomicAdd(&ws[LEV*64 + 1*16 + s], sh1[0]+sh1[1]+sh1[2]+sh1[3]);
    }
}

// --- mval & gx2 from rownorm slots (rs side only) ---
template<int LEV>
__global__ void k_scalar_early(float* __restrict__ ws){
    if (threadIdx.x || blockIdx.x) return;
    float s0=0.f, s1=0.f;
    for (int s=0;s<16;s++){ s0 += ws[LEV*64+s]; s1 += ws[LEV*64+16+s]; }
    float BDL = 2.0f * (float)lev_D(LEV) * 4096.0f;
    float m = s0 / BDL;
    ws[200+LEV] = m;
    ws[212+LEV] = s1 - 2.f*m*s0 + BDL*m*m;
}

// --- bf16x3 split materialization for K-range [kb0, kb0+kd):
//     planes[q][row][kd] local-K layout, 16B slots swizzled: slot ^= (row>>1)&3.
template<int LEV, bool ISA>
__global__ void k_split(const float* __restrict__ img4, const float* __restrict__ ws,
                        unsigned short* __restrict__ base, int b, int kb0, int kd){
    constexpr int C=LT<LEV>::C, H=LT<LEV>::H, K=LT<LEV>::K, S=LT<LEV>::S, PD=LT<LEV>::P;
    constexpr int KK=K*K;
    const size_t PS = (size_t)4096 * kd;
    int gid = blockIdx.x*256 + threadIdx.x;
    int kslots = kd >> 3;
    if (gid >= 4096*kslots) return;
    int kb = gid % kslots, l = gid / kslots;
    int kl0 = kb*8;
    int ly = l>>6, lx = l&63;
    const float* img = img4 + (size_t)b*C*H*H;
    const float* rinv = ws + rho_off(LEV) + b*lev_D(LEV);
    unsigned short h0[8], h1[8], h2[8];
    #pragma unroll
    for (int j=0;j<8;j++){
        int k = kb0 + kl0 + j; int c=k/KK, rem=k%KK, ki=rem/K, kj=rem%K;
        int row=ly*S+ki-PD, col=lx*S+kj-PD;
        float x = (row>=0 && row<H && col>=0 && col<H)
                  ? img[(size_t)(c*H+row)*H+col] : 0.f;
        if (ISA) x *= rinv[k];
        unsigned short a = f2bf(x); float r  = x - bf2f(a);
        unsigned short m = f2bf(r); float r2 = r - bf2f(m);
        unsigned short c2 = f2bf(r2);
        h0[j]=a; h1[j]=m; h2[j]=c2;
    }
    int slot = (kl0>>3)&3, sw = slot ^ ((l>>1)&3);
    size_t off = (size_t)l*kd + (size_t)(kl0 & ~31) + sw*8;
    uint4 u0, u1, u2;
    u0.x=h0[0]|((unsigned)h0[1]<<16); u0.y=h0[2]|((unsigned)h0[3]<<16);
    u0.z=h0[4]|((unsigned)h0[5]<<16); u0.w=h0[6]|((unsigned)h0[7]<<16);
    u1.x=h1[0]|((unsigned)h1[1]<<16); u1.y=h1[2]|((unsigned)h1[3]<<16);
    u1.z=h1[4]|((unsigned)h1[5]<<16); u1.w=h1[6]|((unsigned)h1[7]<<16);
    u2.x=h2[0]|((unsigned)h2[1]<<16); u2.y=h2[2]|((unsigned)h2[3]<<16);
    u2.z=h2[4]|((unsigned)h2[5]<<16); u2.w=h2[6]|((unsigned)h2[7]<<16);
    *(uint4*)(base + off)        = u0;
    *(uint4*)(base + PS + off)   = u1;
    *(uint4*)(base + 2*PS + off) = u2;
}

// --- per-row sums (and squares) from bf16x3 planes, coalesced.
// SSQ=false: P[l] from rs planes. SSQ=true: csum/ssq from lr planes.
template<bool SSQ>
__global__ void k_stats(const unsigned short* __restrict__ pl, size_t PS,
                        float* __restrict__ dst, float* __restrict__ dst2,
                        int kd, int first, int b){
    int tid = threadIdx.x, lane = tid & 63;
    int row = (blockIdx.x*256 + tid) >> 6;   // grid 1024 blocks -> 4096 rows
    int ns = kd >> 3;
    float sum = 0.f, ssq = 0.f;
    for (int s = lane; s < ns; s += 64){
        const unsigned short* p0 = pl + (size_t)row*kd + s*8;
        short8 v0 = *(const short8*)p0;
        short8 v1 = *(const short8*)(p0 + PS);
        short8 v2 = *(const short8*)(p0 + 2*PS);
        #pragma unroll
        for (int j=0;j<8;j++){
            float x = bf2f((unsigned short)v0[j]) + bf2f((unsigned short)v1[j])
                    + bf2f((unsigned short)v2[j]);
            sum += x; if (SSQ) ssq += x*x;
        }
    }
    #pragma unroll
    for (int off=32; off; off>>=1){
        sum += __shfl_xor(sum,off);
        if (SSQ) ssq += __shfl_xor(ssq,off);
    }
    if (lane==0){
        int o = b*4096 + row;
        if (first){ dst[o] = sum; if (SSQ) dst2[o] = ssq; }
        else      { dst[o] += sum; if (SSQ) dst2[o] += ssq; }
    }
}

// --- per-(lev,b): ssq -> ninv in place; lr-side scalar partials to slots ---
template<int LEV>
__global__ void k_levfin(float* __restrict__ ws, int b){
    __shared__ float r0[4], r1[4];
    int tid = threadIdx.x, lane = tid & 63, w = tid >> 6;
    int m = blockIdx.x*256 + tid;            // grid 16 blocks -> 4096 m
    float ssq = ws[ninv_off(LEV) + b*4096 + m];
    float ninv = 1.0f / fmaxf(sqrtf(ssq), 1e-12f);
    ws[ninv_off(LEV) + b*4096 + m] = ninv;
    float y0 = ws[csum_off(LEV) + b*4096 + m] * ninv;
    float y1 = ssq * ninv * ninv;
    #pragma unroll
    for (int off=32; off; off>>=1){ y0 += __shfl_xor(y0,off); y1 += __shfl_xor(y1,off); }
    if (lane==0){ r0[w]=y0; r1[w]=y1; }
    __syncthreads();
    if (tid==0){
        int s = blockIdx.x & 15;
        atomicAdd(&ws[LEV*64 + 2*16 + s], r0[0]+r0[1]+r0[2]+r0[3]);
        atomicAdd(&ws[LEV*64 + 3*16 + s], r1[0]+r1[1]+r1[2]+r1[3]);
    }
}

// --- scale (incl. reference's ym3 bug in R2: lev1 uses lev0's gy2) ---
template<int LEV>
__global__ void k_scalar_late(float* __restrict__ ws){
    if (threadIdx.x || blockIdx.x) return;
    float s2=0.f, s3=0.f;
    for (int s=0;s<16;s++){ s2 += ws[LEV*64+32+s]; s3 += ws[LEV*64+48+s]; }
    float BDL = 2.0f * (float)lev_D(LEV) * 4096.0f;
    float m = ws[200+LEV];
    float gy2 = s3 - 2.f*m*s2 + BDL*m*m;
    if (LEV==0) ws[208] = gy2;
    float gx2 = ws[212+LEV];
    float gyu = (LEV==1) ? ws[208] : gy2;
    ws[204+LEV] = 1.0f/(sqrtf(gx2)*sqrtf(gyu));
}

// --- MFMA GEMM (bf16x3, 6 products) over K-chunk of length kd.
// MODE 0: fused score/max/argmax epilogue (single chunk == full D).
// MODE 1: first chunk, write acc to G.  MODE 2: accumulate into G.
template<int LEV, int MODE>
__launch_bounds__(256, 2)
__global__ void k_gmfma(const unsigned short* __restrict__ planes,
                        float* __restrict__ ws, float* __restrict__ G,
                        int b, int kd){
    const size_t PS = (size_t)4096 * kd;
    __shared__ unsigned short lds[6*128*32];   // 6 tiles [128][32] bf16 = 48KB
    const int tid = threadIdx.x;
    const int w = tid >> 6, lane = tid & 63;
    const int mblk = blockIdx.x, lblk = blockIdx.y;
    const int lw = w >> 1, mw = w & 1;

    f32x4 acc[4][4];
    #pragma unroll
    for (int i=0;i<4;i++)
        #pragma unroll
        for (int j=0;j<4;j++) acc[i][j] = (f32x4){0.f,0.f,0.f,0.f};

    const int srow = lane >> 2, ssl = lane & 3;      // staging: 16 rows x 4 slots
    const int colrow = lane & 15, kk = lane >> 4;    // fragment addressing
    const int swz = (kk ^ ((lane >> 1) & 3)) * 8;    // inverse of split's slot swizzle
    const int aRow0 = lw*64 + colrow;
    const int bRow0 = mw*64 + colrow;

    for (int k0 = 0; k0 < kd; k0 += 32){
        #pragma unroll
        for (int p = 0; p < 6; p++){
            const int rb = (p < 3 ? lblk : mblk)*128 + w*32 + srow;
            const unsigned short* gp0 = planes + (size_t)p*PS
                                        + (size_t)rb*kd + (size_t)k0 + ssl*8;
            unsigned short* lp0 = &lds[p*4096 + w*1024];
            GLOAD16(gp0, lp0);
            GLOAD16(gp0 + (size_t)16*kd, lp0 + 512);
        }
        __syncthreads();

        short8 aF[3][4];
        #pragma unroll
        for (int pa=0; pa<3; pa++)
            #pragma unroll
            for (int i=0;i<4;i++)
                aF[pa][i] = *(const short8*)&lds[pa*4096 + (aRow0 + i*16)*32 + swz];
        #pragma unroll
        for (int pb=0; pb<3; pb++){
            short8 bF[4];
            #pragma unroll
            for (int j=0;j<4;j++)
                bF[j] = *(const short8*)&lds[(3+pb)*4096 + (bRow0 + j*16)*32 + swz];
            const int npa = (pb==0) ? 3 : (pb==1 ? 2 : 1);
            for (int pa=0; pa<npa; pa++)
                #pragma unroll
                for (int i=0;i<4;i++)
                    #pragma unroll
                    for (int j=0;j<4;j++)
                        acc[i][j] = __builtin_amdgcn_mfma_f32_16x16x32_bf16(
                                        aF[pa][i], bF[j], acc[i][j], 0, 0, 0);
        }
        __syncthreads();
    }

    const int lbase = lblk*128 + lw*64;
    const int mbase = mblk*128 + mw*64;
    const int rgrp = lane >> 4;

    if (MODE != 0){
        #pragma unroll
        for (int i=0;i<4;i++){
            #pragma unroll
            for (int rg=0; rg<4; rg++){
                float* gp = G + (size_t)(lbase + i*16 + rgrp*4 + rg)*4096
                              + mbase + colrow;
                #pragma unroll
                for (int j=0;j<4;j++){
                    float v = acc[i][j][rg];
                    if (MODE == 2) v += gp[j*16];
                    gp[j*16] = v;
                }
            }
        }
        return;
    }

    // ---- MODE 0 epilogue: score + per-m max/argmax over this block's 128 l ----
    constexpr int D = lev_D(LEV);
    const float mval = ws[200+LEV];
    const float Dm2 = (float)D * mval * mval;
    const float* Pv  = ws + p_off(LEV)    + b*4096;
    const float* NIv = ws + ninv_off(LEV) + b*4096;
    const float* CSv = ws + csum_off(LEV) + b*4096;
    float* smax = (float*)lds;          // [4][64]
    int*   sarg = (int*)&lds[512];      // [4][64]
    #pragma unroll
    for (int j=0;j<4;j++){
        int m = mbase + j*16 + colrow;
        float nv = NIv[m];
        float cmv = -mval*nv*CSv[m] + Dm2;
        float v = -FLT_MAX; int vi = 0x7fffffff;
        #pragma unroll
        for (int i=0;i<4;i++){
            #pragma unroll
            for (int rg=0; rg<4; rg++){
                int l = lbase + i*16 + rgrp*4 + rg;
                float sc = nv*acc[i][j][rg] - mval*Pv[l] + cmv;
                if (sc > v){ v = sc; vi = l; }
            }
        }
        #pragma unroll
        for (int off=16; off<64; off<<=1){
            float ov = __shfl_xor(v, off);
            int   oi = __shfl_xor(vi, off);
            if (ov > v || (ov == v && oi < vi)){ v = ov; vi = oi; }
        }
        if (rgrp == 0){
            smax[w*64 + j*16 + colrow] = v;
            sarg[w*64 + j*16 + colrow] = vi;
        }
    }
    __syncthreads();
    if (tid < 128){
        int mg = tid >> 6, idx = tid & 63;
        float v0 = smax[mg*64 + idx];     int a0 = sarg[mg*64 + idx];
        float v1 = smax[(mg+2)*64 + idx]; int a1 = sarg[(mg+2)*64 + idx];
        if (v1 > v0 || (v1 == v0 && a1 < a0)){ v0 = v1; a0 = a1; }
        int m = mblk*128 + mg*64 + idx;
        int o = (b*32 + lblk)*4096 + m;
        ws[pmax_off(LEV) + o] = v0;
        ((int*)ws)[parg_off(LEV) + o] = a0;
    }
}

// --- score + max/argmax from accumulated G; grid (64 mblk, 8 lsplit) ---
template<int LEV>
__global__ void k_score(const float* __restrict__ G, float* __restrict__ ws, int b){
    constexpr int D = lev_D(LEV);
    __shared__ float smax[4][64];
    __shared__ int   sarg[4][64];
    int tid = threadIdx.x, mloc = tid & 63, r = tid >> 6;
    int m = blockIdx.x*64 + mloc;
    int l0 = blockIdx.y*512;
    float mval = ws[200+LEV];
    float nv = ws[ninv_off(LEV) + b*4096 + m];
    float cmv = -mval*nv*ws[csum_off(LEV) + b*4096 + m] + (float)D*mval*mval;
    const float* Pv = ws + p_off(LEV) + b*4096;
    float best = -FLT_MAX; int bi = 0x7fffffff;
    for (int lt=0; lt<128; lt++){
        int l = l0 + lt*4 + r;
        float sc = nv*G[(size_t)l*4096 + m] - mval*Pv[l] + cmv;
        if (sc > best){ best = sc; bi = l; }
    }
    smax[r][mloc] = best; sarg[r][mloc] = bi;
    __syncthreads();
    if (tid < 64){
        float v = smax[0][tid]; int vi = sarg[0][tid];
        #pragma unroll
        for (int rr=1; rr<4; rr++){
            float ov = smax[rr][tid]; int oi = sarg[rr][tid];
            if (ov > v || (ov == v && oi < vi)){ v = ov; vi = oi; }
        }
        int o = (b*32 + blockIdx.y)*4096 + blockIdx.x*64 + tid;
        ws[pmax_off(LEV) + o] = v;
        ((int*)ws)[parg_off(LEV) + o] = vi;
    }
}

// --- reduce l-chunks -> S3,S2,S1,arg outputs (applies late scale) ---
__global__ void k_smax(float* __restrict__ ws, float* __restrict__ out,
                       int nch0, int nch1, int nch2){
    int gid = blockIdx.x*256 + threadIdx.x;
    if (gid >= 8192) return;
    int b = gid >> 12, m = gid & 4095;
    int nchs[3] = {nch0, nch1, nch2};
    for (int lev=0; lev<3; lev++){
        float mv = -FLT_MAX; int ma = 0x7fffffff;
        for (int ch=0; ch<nchs[lev]; ch++){
            int o = ((b*32+ch)<<12) + m;
            float v = ws[pmax_off(lev) + o];
            int   a = ((const int*)ws)[parg_off(lev) + o];
            if (v > mv || (v == mv && a < ma)){ mv=v; ma=a; }
        }
        out[lev*8192 + gid] = mv * ws[204+lev];
        if (lev==0){
            out[3*8192 + gid] = (float)ma;
            ((int*)ws)[arg_off() + gid] = ma;
        }
    }
}

// --- T = fold(gather(unfold(ref), arg)) / 9 ---
template<int LEV>
__global__ void k_transfer(const float* __restrict__ ref, const float* __restrict__ wsf,
                           float* __restrict__ outT){
    constexpr int C=LT<LEV>::C, H=LT<LEV>::H, K=LT<LEV>::K, S=LT<LEV>::S, PD=LT<LEV>::P;
    const int* arg = (const int*)wsf + arg_off();
    size_t gid = (size_t)blockIdx.x*256 + threadIdx.x;
    size_t total = (size_t)2*C*H*H;
    if (gid >= total) return;
    int x = (int)(gid % H);
    int y = (int)((gid / H) % H);
    int c = (int)((gid / ((size_t)H*H)) % C);
    int b = (int)(gid / ((size_t)C*H*H));
    const float* rimg = ref + (size_t)(b*C+c)*H*H;
    int byo = (y+PD)/S, ryo = (y+PD)%S;
    int bxo = (x+PD)/S, rxo = (x+PD)%S;
    float acc = 0.f;
    #pragma unroll
    for (int jy=0; jy<3; jy++){
        int ho = byo - jy;
        if (ho < 0 || ho >= 64) continue;
        int ki = ryo + jy*S;
        #pragma unroll
        for (int jx=0; jx<3; jx++){
            int wo = bxo - jx;
            if (wo < 0 || wo >= 64) continue;
            int kj = rxo + jx*S;
            int l = arg[b*4096 + ho*64 + wo];
            int ly = l>>6, lx = l&63;
            int srow = ly*S + ki - PD, scol = lx*S + kj - PD;
            if (srow>=0 && srow<H && scol>=0 && scol<H)
                acc += rimg[srow*H + scol];
        }
    }
    outT[gid] = acc * (1.0f/9.0f);
}

template<int LEV>
static void run_level(const float* refsr, const float* lrsr, float* ws,
                      size_t ws_size, hipStream_t stream, int* nch){
    constexpr int D = lev_D(LEV);
    k_rownorm<LEV><<<D/2, 256, 0, stream>>>(refsr, ws);
    k_scalar_early<LEV><<<1, 64, 0, stream>>>(ws);

    // pick chunk size: fused single-chunk if planes fit at 8MB; else largest
    // divisor chunk fitting beside the 64MB G buffer.
    bool fused = (ws_size >= G_BASE_BYTES + (size_t)49152*D);
    int kd = D;
    if (!fused){
        kd = 0;
        for (int div = 2; div <= 16; div <<= 1){
            if (ws_size >= CHUNK_PLANE_BYTES + (size_t)49152*(D/div)){ kd = D/div; break; }
        }
        if (!kd) kd = D/16;
    }
    unsigned short* pl = (unsigned short*)((char*)ws + (fused ? G_BASE_BYTES : CHUNK_PLANE_BYTES));
    float* G = ws + (G_BASE_BYTES >> 2);
    const size_t PS = (size_t)4096 * kd;
    const int nkc = D / kd;
    nch[LEV] = fused ? 32 : 8;

    for (int b=0; b<2; b++){
        for (int kc=0; kc<nkc; kc++){
            k_split<LEV,true ><<<2*kd, 256, 0, stream>>>(refsr, ws, pl, b, kc*kd, kd);
            k_split<LEV,false><<<2*kd, 256, 0, stream>>>(lrsr,  ws, pl + 3*PS, b, kc*kd, kd);
            k_stats<false><<<1024, 256, 0, stream>>>(pl,        PS, ws + p_off(LEV),    nullptr,             kd, kc==0, b);
            k_stats<true ><<<1024, 256, 0, stream>>>(pl + 3*PS, PS, ws + csum_off(LEV), ws + ninv_off(LEV),  kd, kc==0, b);
            if (!fused){
                if (kc==0) k_gmfma<LEV,1><<<dim3(32,32), 256, 0, stream>>>(pl, ws, G, b, kd);
                else       k_gmfma<LEV,2><<<dim3(32,32), 256, 0, stream>>>(pl, ws, G, b, kd);
            }
        }
        k_levfin<LEV><<<16, 256, 0, stream>>>(ws, b);
        if (fused) k_gmfma<LEV,0><<<dim3(32,32), 256, 0, stream>>>(pl, ws, G, b, kd);
        else       k_score<LEV><<<dim3(64,8), 256, 0, stream>>>(G, ws, b);
    }
    k_scalar_late<LEV><<<1, 64, 0, stream>>>(ws);
}

extern "C" void kernel_launch(void* const* d_in, const int* in_sizes, int n_in,
                              void* d_out, int out_size, void* d_ws, size_t ws_size,
                              hipStream_t stream){
    const float* lrsr[3]  = { (const float*)d_in[2], (const float*)d_in[1], (const float*)d_in[0] };
    const float* refsr[3] = { (const float*)d_in[5], (const float*)d_in[4], (const float*)d_in[3] };
    const float* refp[3]  = { (const float*)d_in[8], (const float*)d_in[7], (const float*)d_in[6] };
    float* ws  = (float*)d_ws;
    float* out = (float*)d_out;

    hipMemsetAsync(d_ws, 0, 4096, stream);  // zero scalar slots + scalars

    int nch[3];
    run_level<0>(refsr[0], lrsr[0], ws, ws_size, stream, nch);
    run_level<1>(refsr[1], lrsr[1], ws, ws_size, stream, nch);
    run_level<2>(refsr[2], lrsr[2], ws, ws_size, stream, nch);

    k_smax<<<32, 256, 0, stream>>>(ws, out, nch[0], nch[1], nch[2]);

    k_transfer<0><<< (2*256*64*64)/256,   256, 0, stream>>>(refp[0], ws, out + 32768);
    k_transfer<1><<< (2*128*128*128)/256, 256, 0, stream>>>(refp[1], ws, out + 2129920);
    k_transfer<2><<< (2*64*256*256)/256,  256, 0, stream>>>(refp[2], ws, out + 6324224);
}

// Round 5
// 5269.455 us; speedup vs baseline: 4.6839x; 1.3503x over previous
//
#include <hip/hip_runtime.h>
#include <cfloat>

// ---------------------------------------------------------------------------
// SearchTransfer (TTSR): 3-level patch correlation + argmax + gather/fold.
// Levels: 0 = lv3 (C=256,H=64,k=3,s=1,p=1,D=2304)
//         1 = lv2 (C=128,H=128,k=6,s=2,p=2,D=4608)
//         2 = lv1 (C=64,H=256,k=12,s=4,p=4,D=9216)
// L = M = 4096 patch positions per batch, B = 2.
//
// score(l,m) = ninv[m]*G[l,m] - mval*P[l] - mval*ninv[m]*csum[m] + D*mval^2
// G[l,m] = sum_d (u_rs[d,l]*rinv[d]) * u_lr[d,m]
//
// Precision strategy: only lev0's argmax is consumed downstream (arg, T1-T3).
// lev0 uses bf16x3 split / 6 MFMA products (error ~2^-27, matches np argmax
// exactly). lev1/lev2 only export max VALUES -> bf16x2 split / 3 products
// (score error ~1e-7, invisible vs output threshold) at half the FLOPs.
// ---------------------------------------------------------------------------

typedef short short8 __attribute__((ext_vector_type(8)));
typedef float f32x4  __attribute__((ext_vector_type(4)));

template<int LEV> struct LT;
template<> struct LT<0> { static constexpr int C=256, H=64,  K=3,  S=1, P=1; };
template<> struct LT<1> { static constexpr int C=128, H=128, K=6,  S=2, P=2; };
template<> struct LT<2> { static constexpr int C=64,  H=256, K=12, S=4, P=4; };

__host__ __device__ constexpr int lev_D(int lev){ return lev==0?2304:(lev==1?4608:9216); }
// ws float-index offsets
// [0,192): scalar slots: lev*64 + q*16 + slot   (q: 0=sum_rs,1=ssq_rs,2=sum_lr,3=ssq_lr)
// 200+lev: mval   204+lev: scale   208: gy2_lev0   212+lev: gx2
__host__ __device__ constexpr int rho_off(int lev){ return 256 + (lev>0?2*2304:0) + (lev>1?2*4608:0); } // end 32512
__host__ __device__ constexpr int p_off(int lev)   { return 32512  + lev*8192;   } // end 57088
__host__ __device__ constexpr int ninv_off(int lev){ return 57088  + lev*8192;   } // end 81664 (ssq until levfin)
__host__ __device__ constexpr int csum_off(int lev){ return 81664  + lev*8192;   } // end 106240
__host__ __device__ constexpr int pmax_off(int lev){ return 106240 + lev*262144; } // [b][32][4096], end 892672
__host__ __device__ constexpr int parg_off(int lev){ return 892672 + lev*262144; } // int, end 1679104
__host__ __device__ constexpr int arg_off(){ return 1679104; }                     // int, 8192
static constexpr size_t G_BASE_BYTES      = 8ull  << 20;  // fp32 G [4096][4096] = 64MB
static constexpr size_t CHUNK_PLANE_BYTES = 72ull << 20;  // chunked planes base

__device__ inline unsigned short f2bf(float f){
    unsigned int u = __float_as_uint(f);
    return (unsigned short)((u + 0x7fffu + ((u >> 16) & 1u)) >> 16);
}
__device__ inline float bf2f(unsigned short h){ return __uint_as_float(((unsigned)h) << 16); }

#define GLOAD16(g, l) __builtin_amdgcn_global_load_lds( \
    (const __attribute__((address_space(1))) unsigned int*)(g), \
    (__attribute__((address_space(3))) unsigned int*)(l), 16, 0, 0)

// --- per-(b,d) row norm of refsr unfold (normalize axis=2) + rs scalar slots ---
template<int LEV>
__global__ void k_rownorm(const float* __restrict__ refsr, float* __restrict__ ws){
    constexpr int C=LT<LEV>::C, H=LT<LEV>::H, K=LT<LEV>::K, S=LT<LEV>::S, PD=LT<LEV>::P;
    constexpr int D = C*K*K, KK=K*K;
    __shared__ float sh0[4], sh1[4];
    int tid = threadIdx.x, lane = tid & 63, w = tid >> 6;
    int wid = (blockIdx.x*blockDim.x + tid) >> 6;   // grid = D/2 blocks -> 2D waves
    int b = wid / D, d = wid % D;
    int c = d/KK, rem = d%KK, ki = rem/K, kj = rem%K;
    const float* img = refsr + (size_t)(b*C + c)*H*H;
    float sum=0.f, ssq=0.f;
    for (int idx=lane; idx<4096; idx+=64){
        int ho=idx>>6, wo=idx&63;
        int row = ho*S+ki-PD, col = wo*S+kj-PD;
        if (row>=0 && row<H && col>=0 && col<H){
            float v = img[row*H+col]; sum += v; ssq += v*v;
        }
    }
    #pragma unroll
    for (int off=32; off; off>>=1){ sum += __shfl_xor(sum,off); ssq += __shfl_xor(ssq,off); }
    if (lane==0){
        float rinv = 1.0f / fmaxf(sqrtf(ssq), 1e-12f);
        ws[rho_off(LEV) + b*D + d] = rinv;
        sh0[w] = sum*rinv;
        sh1[w] = ssq*rinv*rinv;
    }
    __syncthreads();
    if (tid==0){
        int s = blockIdx.x & 15;
        atomicAdd(&ws[LEV*64 + 0*16 + s], sh0[0]+sh0[1]+sh0[2]+sh0[3]);
        atomicAdd(&ws[LEV*64 + 1*16 + s], sh1[0]+sh1[1]+sh1[2]+sh1[3]);
    }
}

// --- mval & gx2 from rownorm slots (rs side only) ---
template<int LEV>
__global__ void k_scalar_early(float* __restrict__ ws){
    if (threadIdx.x || blockIdx.x) return;
    float s0=0.f, s1=0.f;
    for (int s=0;s<16;s++){ s0 += ws[LEV*64+s]; s1 += ws[LEV*64+16+s]; }
    float BDL = 2.0f * (float)lev_D(LEV) * 4096.0f;
    float m = s0 / BDL;
    ws[200+LEV] = m;
    ws[212+LEV] = s1 - 2.f*m*s0 + BDL*m*m;
}

// --- bf16 split (NSP planes) for K-range [kb0, kb0+kd):
//     planes[q][row][kd] local-K layout, 16B slots swizzled: slot ^= (row>>1)&3.
template<int LEV, bool ISA, int NSP>
__global__ void k_split(const float* __restrict__ img4, const float* __restrict__ ws,
                        unsigned short* __restrict__ base, int b, int kb0, int kd){
    constexpr int C=LT<LEV>::C, H=LT<LEV>::H, K=LT<LEV>::K, S=LT<LEV>::S, PD=LT<LEV>::P;
    constexpr int KK=K*K;
    const size_t PS = (size_t)4096 * kd;
    int gid = blockIdx.x*256 + threadIdx.x;
    int kslots = kd >> 3;
    if (gid >= 4096*kslots) return;
    int kb = gid % kslots, l = gid / kslots;
    int kl0 = kb*8;
    int ly = l>>6, lx = l&63;
    const float* img = img4 + (size_t)b*C*H*H;
    const float* rinv = ws + rho_off(LEV) + b*lev_D(LEV);
    unsigned short h[NSP][8];
    #pragma unroll
    for (int j=0;j<8;j++){
        int k = kb0 + kl0 + j; int c=k/KK, rem=k%KK, ki=rem/K, kj=rem%K;
        int row=ly*S+ki-PD, col=lx*S+kj-PD;
        float x = (row>=0 && row<H && col>=0 && col<H)
                  ? img[(size_t)(c*H+row)*H+col] : 0.f;
        if (ISA) x *= rinv[k];
        unsigned short a = f2bf(x); h[0][j]=a;
        float r = x - bf2f(a);
        unsigned short m = f2bf(r); h[1][j]=m;
        if (NSP==3){ float r2 = r - bf2f(m); h[2][j]=f2bf(r2); }
    }
    int slot = (kl0>>3)&3, sw = slot ^ ((l>>1)&3);
    size_t off = (size_t)l*kd + (size_t)(kl0 & ~31) + sw*8;
    #pragma unroll
    for (int q=0;q<NSP;q++){
        uint4 u;
        u.x=h[q][0]|((unsigned)h[q][1]<<16); u.y=h[q][2]|((unsigned)h[q][3]<<16);
        u.z=h[q][4]|((unsigned)h[q][5]<<16); u.w=h[q][6]|((unsigned)h[q][7]<<16);
        *(uint4*)(base + q*PS + off) = u;
    }
}

// --- per-row sums (and squares) from split planes, coalesced.
// SSQ=false: P[l] from rs planes. SSQ=true: csum/ssq from lr planes.
template<bool SSQ, int NSP>
__global__ void k_stats(const unsigned short* __restrict__ pl, size_t PS,
                        float* __restrict__ dst, float* __restrict__ dst2,
                        int kd, int first, int b){
    int tid = threadIdx.x, lane = tid & 63;
    int row = (blockIdx.x*256 + tid) >> 6;   // grid 1024 blocks -> 4096 rows
    int ns = kd >> 3;
    float sum = 0.f, ssq = 0.f;
    for (int s = lane; s < ns; s += 64){
        const unsigned short* p0 = pl + (size_t)row*kd + s*8;
        short8 v0 = *(const short8*)p0;
        short8 v1 = *(const short8*)(p0 + PS);
        short8 v2;
        if (NSP==3) v2 = *(const short8*)(p0 + 2*PS);
        #pragma unroll
        for (int j=0;j<8;j++){
            float x = bf2f((unsigned short)v0[j]) + bf2f((unsigned short)v1[j]);
            if (NSP==3) x += bf2f((unsigned short)v2[j]);
            sum += x; if (SSQ) ssq += x*x;
        }
    }
    #pragma unroll
    for (int off=32; off; off>>=1){
        sum += __shfl_xor(sum,off);
        if (SSQ) ssq += __shfl_xor(ssq,off);
    }
    if (lane==0){
        int o = b*4096 + row;
        if (first){ dst[o] = sum; if (SSQ) dst2[o] = ssq; }
        else      { dst[o] += sum; if (SSQ) dst2[o] += ssq; }
    }
}

// --- per-(lev,b): ssq -> ninv in place; lr-side scalar partials to slots ---
template<int LEV>
__global__ void k_levfin(float* __restrict__ ws, int b){
    __shared__ float r0[4], r1[4];
    int tid = threadIdx.x, lane = tid & 63, w = tid >> 6;
    int m = blockIdx.x*256 + tid;            // grid 16 blocks -> 4096 m
    float ssq = ws[ninv_off(LEV) + b*4096 + m];
    float ninv = 1.0f / fmaxf(sqrtf(ssq), 1e-12f);
    ws[ninv_off(LEV) + b*4096 + m] = ninv;
    float y0 = ws[csum_off(LEV) + b*4096 + m] * ninv;
    float y1 = ssq * ninv * ninv;
    #pragma unroll
    for (int off=32; off; off>>=1){ y0 += __shfl_xor(y0,off); y1 += __shfl_xor(y1,off); }
    if (lane==0){ r0[w]=y0; r1[w]=y1; }
    __syncthreads();
    if (tid==0){
        int s = blockIdx.x & 15;
        atomicAdd(&ws[LEV*64 + 2*16 + s], r0[0]+r0[1]+r0[2]+r0[3]);
        atomicAdd(&ws[LEV*64 + 3*16 + s], r1[0]+r1[1]+r1[2]+r1[3]);
    }
}

// --- scale (incl. reference's ym3 bug in R2: lev1 uses lev0's gy2) ---
template<int LEV>
__global__ void k_scalar_late(float* __restrict__ ws){
    if (threadIdx.x || blockIdx.x) return;
    float s2=0.f, s3=0.f;
    for (int s=0;s<16;s++){ s2 += ws[LEV*64+32+s]; s3 += ws[LEV*64+48+s]; }
    float BDL = 2.0f * (float)lev_D(LEV) * 4096.0f;
    float m = ws[200+LEV];
    float gy2 = s3 - 2.f*m*s2 + BDL*m*m;
    if (LEV==0) ws[208] = gy2;
    float gx2 = ws[212+LEV];
    float gyu = (LEV==1) ? ws[208] : gy2;
    ws[204+LEV] = 1.0f/(sqrtf(gx2)*sqrtf(gyu));
}

// --- MFMA GEMM over K-chunk of length kd. NSP planes/side; products pa+pb<NSP.
// MODE 0: fused score/max/argmax epilogue (single chunk == full D).
// MODE 1: first chunk, write acc to G.  MODE 2: accumulate into G.
template<int LEV, int MODE, int NSP>
__launch_bounds__(256, (NSP==2)?3:2)
__global__ void k_gmfma(const unsigned short* __restrict__ planes,
                        float* __restrict__ ws, float* __restrict__ G,
                        int b, int kd){
    const size_t PS = (size_t)4096 * kd;
    __shared__ unsigned short lds[2*NSP*128*32];   // 2*NSP tiles [128][32] bf16
    const int tid = threadIdx.x;
    const int w = tid >> 6, lane = tid & 63;
    const int mblk = blockIdx.x, lblk = blockIdx.y;
    const int lw = w >> 1, mw = w & 1;

    f32x4 acc[4][4];
    #pragma unroll
    for (int i=0;i<4;i++)
        #pragma unroll
        for (int j=0;j<4;j++) acc[i][j] = (f32x4){0.f,0.f,0.f,0.f};

    const int srow = lane >> 2, ssl = lane & 3;      // staging: 16 rows x 4 slots
    const int colrow = lane & 15, kk = lane >> 4;    // fragment addressing
    const int swz = (kk ^ ((lane >> 1) & 3)) * 8;    // inverse of split's slot swizzle
    const int aRow0 = lw*64 + colrow;
    const int bRow0 = mw*64 + colrow;

    for (int k0 = 0; k0 < kd; k0 += 32){
        #pragma unroll
        for (int p = 0; p < 2*NSP; p++){
            const int rb = (p < NSP ? lblk : mblk)*128 + w*32 + srow;
            const unsigned short* gp0 = planes + (size_t)p*PS
                                        + (size_t)rb*kd + (size_t)k0 + ssl*8;
            unsigned short* lp0 = &lds[p*4096 + w*1024];
            GLOAD16(gp0, lp0);
            GLOAD16(gp0 + (size_t)16*kd, lp0 + 512);
        }
        __syncthreads();

        short8 aF[NSP][4];
        #pragma unroll
        for (int pa=0; pa<NSP; pa++)
            #pragma unroll
            for (int i=0;i<4;i++)
                aF[pa][i] = *(const short8*)&lds[pa*4096 + (aRow0 + i*16)*32 + swz];
        #pragma unroll
        for (int pb=0; pb<NSP; pb++){
            short8 bF[4];
            #pragma unroll
            for (int j=0;j<4;j++)
                bF[j] = *(const short8*)&lds[(NSP+pb)*4096 + (bRow0 + j*16)*32 + swz];
            const int npa = NSP - pb;
            for (int pa=0; pa<npa; pa++)
                #pragma unroll
                for (int i=0;i<4;i++)
                    #pragma unroll
                    for (int j=0;j<4;j++)
                        acc[i][j] = __builtin_amdgcn_mfma_f32_16x16x32_bf16(
                                        aF[pa][i], bF[j], acc[i][j], 0, 0, 0);
        }
        __syncthreads();
    }

    const int lbase = lblk*128 + lw*64;
    const int mbase = mblk*128 + mw*64;
    const int rgrp = lane >> 4;

    if (MODE != 0){
        #pragma unroll
        for (int i=0;i<4;i++){
            #pragma unroll
            for (int rg=0; rg<4; rg++){
                float* gp = G + (size_t)(lbase + i*16 + rgrp*4 + rg)*4096
                              + mbase + colrow;
                #pragma unroll
                for (int j=0;j<4;j++){
                    float v = acc[i][j][rg];
                    if (MODE == 2) v += gp[j*16];
                    gp[j*16] = v;
                }
            }
        }
        return;
    }

    // ---- MODE 0 epilogue: score + per-m max/argmax over this block's 128 l ----
    constexpr int D = lev_D(LEV);
    const float mval = ws[200+LEV];
    const float Dm2 = (float)D * mval * mval;
    const float* Pv  = ws + p_off(LEV)    + b*4096;
    const float* NIv = ws + ninv_off(LEV) + b*4096;
    const float* CSv = ws + csum_off(LEV) + b*4096;
    float* smax = (float*)lds;          // [4][64]
    int*   sarg = (int*)&lds[512];      // [4][64]
    #pragma unroll
    for (int j=0;j<4;j++){
        int m = mbase + j*16 + colrow;
        float nv = NIv[m];
        float cmv = -mval*nv*CSv[m] + Dm2;
        float v = -FLT_MAX; int vi = 0x7fffffff;
        #pragma unroll
        for (int i=0;i<4;i++){
            #pragma unroll
            for (int rg=0; rg<4; rg++){
                int l = lbase + i*16 + rgrp*4 + rg;
                float sc = nv*acc[i][j][rg] - mval*Pv[l] + cmv;
                if (sc > v){ v = sc; vi = l; }
            }
        }
        #pragma unroll
        for (int off=16; off<64; off<<=1){
            float ov = __shfl_xor(v, off);
            int   oi = __shfl_xor(vi, off);
            if (ov > v || (ov == v && oi < vi)){ v = ov; vi = oi; }
        }
        if (rgrp == 0){
            smax[w*64 + j*16 + colrow] = v;
            sarg[w*64 + j*16 + colrow] = vi;
        }
    }
    __syncthreads();
    if (tid < 128){
        int mg = tid >> 6, idx = tid & 63;
        float v0 = smax[mg*64 + idx];     int a0 = sarg[mg*64 + idx];
        float v1 = smax[(mg+2)*64 + idx]; int a1 = sarg[(mg+2)*64 + idx];
        if (v1 > v0 || (v1 == v0 && a1 < a0)){ v0 = v1; a0 = a1; }
        int m = mblk*128 + mg*64 + idx;
        int o = (b*32 + lblk)*4096 + m;
        ws[pmax_off(LEV) + o] = v0;
        ((int*)ws)[parg_off(LEV) + o] = a0;
    }
}

// --- score + max/argmax from accumulated G; grid (64 mblk, 8 lsplit) ---
template<int LEV>
__global__ void k_score(const float* __restrict__ G, float* __restrict__ ws, int b){
    constexpr int D = lev_D(LEV);
    __shared__ float smax[4][64];
    __shared__ int   sarg[4][64];
    int tid = threadIdx.x, mloc = tid & 63, r = tid >> 6;
    int m = blockIdx.x*64 + mloc;
    int l0 = blockIdx.y*512;
    float mval = ws[200+LEV];
    float nv = ws[ninv_off(LEV) + b*4096 + m];
    float cmv = -mval*nv*ws[csum_off(LEV) + b*4096 + m] + (float)D*mval*mval;
    const float* Pv = ws + p_off(LEV) + b*4096;
    float best = -FLT_MAX; int bi = 0x7fffffff;
    for (int lt=0; lt<128; lt++){
        int l = l0 + lt*4 + r;
        float sc = nv*G[(size_t)l*4096 + m] - mval*Pv[l] + cmv;
        if (sc > best){ best = sc; bi = l; }
    }
    smax[r][mloc] = best; sarg[r][mloc] = bi;
    __syncthreads();
    if (tid < 64){
        float v = smax[0][tid]; int vi = sarg[0][tid];
        #pragma unroll
        for (int rr=1; rr<4; rr++){
            float ov = smax[rr][tid]; int oi = sarg[rr][tid];
            if (ov > v || (ov == v && oi < vi)){ v = ov; vi = oi; }
        }
        int o = (b*32 + blockIdx.y)*4096 + blockIdx.x*64 + tid;
        ws[pmax_off(LEV) + o] = v;
        ((int*)ws)[parg_off(LEV) + o] = vi;
    }
}

// --- reduce l-chunks -> S3,S2,S1,arg outputs (applies late scale) ---
__global__ void k_smax(float* __restrict__ ws, float* __restrict__ out,
                       int nch0, int nch1, int nch2){
    int gid = blockIdx.x*256 + threadIdx.x;
    if (gid >= 8192) return;
    int b = gid >> 12, m = gid & 4095;
    int nchs[3] = {nch0, nch1, nch2};
    for (int lev=0; lev<3; lev++){
        float mv = -FLT_MAX; int ma = 0x7fffffff;
        for (int ch=0; ch<nchs[lev]; ch++){
            int o = ((b*32+ch)<<12) + m;
            float v = ws[pmax_off(lev) + o];
            int   a = ((const int*)ws)[parg_off(lev) + o];
            if (v > mv || (v == mv && a < ma)){ mv=v; ma=a; }
        }
        out[lev*8192 + gid] = mv * ws[204+lev];
        if (lev==0){
            out[3*8192 + gid] = (float)ma;
            ((int*)ws)[arg_off() + gid] = ma;
        }
    }
}

// --- T = fold(gather(unfold(ref), arg)) / 9 ---
template<int LEV>
__global__ void k_transfer(const float* __restrict__ ref, const float* __restrict__ wsf,
                           float* __restrict__ outT){
    constexpr int C=LT<LEV>::C, H=LT<LEV>::H, K=LT<LEV>::K, S=LT<LEV>::S, PD=LT<LEV>::P;
    const int* arg = (const int*)wsf + arg_off();
    size_t gid = (size_t)blockIdx.x*256 + threadIdx.x;
    size_t total = (size_t)2*C*H*H;
    if (gid >= total) return;
    int x = (int)(gid % H);
    int y = (int)((gid / H) % H);
    int c = (int)((gid / ((size_t)H*H)) % C);
    int b = (int)(gid / ((size_t)C*H*H));
    const float* rimg = ref + (size_t)(b*C+c)*H*H;
    int byo = (y+PD)/S, ryo = (y+PD)%S;
    int bxo = (x+PD)/S, rxo = (x+PD)%S;
    float acc = 0.f;
    #pragma unroll
    for (int jy=0; jy<3; jy++){
        int ho = byo - jy;
        if (ho < 0 || ho >= 64) continue;
        int ki = ryo + jy*S;
        #pragma unroll
        for (int jx=0; jx<3; jx++){
            int wo = bxo - jx;
            if (wo < 0 || wo >= 64) continue;
            int kj = rxo + jx*S;
            int l = arg[b*4096 + ho*64 + wo];
            int ly = l>>6, lx = l&63;
            int srow = ly*S + ki - PD, scol = lx*S + kj - PD;
            if (srow>=0 && srow<H && scol>=0 && scol<H)
                acc += rimg[srow*H + scol];
        }
    }
    outT[gid] = acc * (1.0f/9.0f);
}

template<int LEV>
static void run_level(const float* refsr, const float* lrsr, float* ws,
                      size_t ws_size, hipStream_t stream, int* nch){
    constexpr int D = lev_D(LEV);
    constexpr int NSP = (LEV==0) ? 3 : 2;       // lev0 exact argmax; others value-only
    k_rownorm<LEV><<<D/2, 256, 0, stream>>>(refsr, ws);
    k_scalar_early<LEV><<<1, 64, 0, stream>>>(ws);

    // bytes for both sides' planes at chunk length c: 2*NSP * 4096 * c * 2B
    auto planeBytes = [](int c){ return (size_t)4*NSP*4096*c; };
    bool fused = (ws_size >= G_BASE_BYTES + planeBytes(D));
    int kd = D;
    if (!fused){
        kd = 0;
        for (int div = 2; div <= 16; div <<= 1){
            if (ws_size >= CHUNK_PLANE_BYTES + planeBytes(D/div)){ kd = D/div; break; }
        }
        if (!kd) kd = D/16;
    }
    unsigned short* pl = (unsigned short*)((char*)ws + (fused ? G_BASE_BYTES : CHUNK_PLANE_BYTES));
    float* G = ws + (G_BASE_BYTES >> 2);
    const size_t PS = (size_t)4096 * kd;
    const int nkc = D / kd;
    nch[LEV] = fused ? 32 : 8;

    for (int b=0; b<2; b++){
        for (int kc=0; kc<nkc; kc++){
            k_split<LEV,true ,NSP><<<2*kd, 256, 0, stream>>>(refsr, ws, pl, b, kc*kd, kd);
            k_split<LEV,false,NSP><<<2*kd, 256, 0, stream>>>(lrsr,  ws, pl + NSP*PS, b, kc*kd, kd);
            k_stats<false,NSP><<<1024, 256, 0, stream>>>(pl,          PS, ws + p_off(LEV),    nullptr,            kd, kc==0, b);
            k_stats<true ,NSP><<<1024, 256, 0, stream>>>(pl + NSP*PS, PS, ws + csum_off(LEV), ws + ninv_off(LEV), kd, kc==0, b);
            if (!fused){
                if (kc==0) k_gmfma<LEV,1,NSP><<<dim3(32,32), 256, 0, stream>>>(pl, ws, G, b, kd);
                else       k_gmfma<LEV,2,NSP><<<dim3(32,32), 256, 0, stream>>>(pl, ws, G, b, kd);
            }
        }
        k_levfin<LEV><<<16, 256, 0, stream>>>(ws, b);
        if (fused) k_gmfma<LEV,0,NSP><<<dim3(32,32), 256, 0, stream>>>(pl, ws, G, b, kd);
        else       k_score<LEV><<<dim3(64,8), 256, 0, stream>>>(G, ws, b);
    }
    k_scalar_late<LEV><<<1, 64, 0, stream>>>(ws);
}

extern "C" void kernel_launch(void* const* d_in, const int* in_sizes, int n_in,
                              void* d_out, int out_size, void* d_ws, size_t ws_size,
                              hipStream_t stream){
    const float* lrsr[3]  = { (const float*)d_in[2], (const float*)d_in[1], (const float*)d_in[0] };
    const float* refsr[3] = { (const float*)d_in[5], (const float*)d_in[4], (const float*)d_in[3] };
    const float* refp[3]  = { (const float*)d_in[8], (const float*)d_in[7], (const float*)d_in[6] };
    float* ws  = (float*)d_ws;
    float* out = (float*)d_out;

    hipMemsetAsync(d_ws, 0, 4096, stream);  // zero scalar slots + scalars

    int nch[3];
    run_level<0>(refsr[0], lrsr[0], ws, ws_size, stream, nch);
    run_level<1>(refsr[1], lrsr[1], ws, ws_size, stream, nch);
    run_level<2>(refsr[2], lrsr[2], ws, ws_size, stream, nch);

    k_smax<<<32, 256, 0, stream>>>(ws, out, nch[0], nch[1], nch[2]);

    k_transfer<0><<< (2*256*64*64)/256,   256, 0, stream>>>(refp[0], ws, out + 32768);
    k_transfer<1><<< (2*128*128*128)/256, 256, 0, stream>>>(refp[1], ws, out + 2129920);
    k_transfer<2><<< (2*64*256*256)/256,  256, 0, stream>>>(refp[2], ws, out + 6324224);
}

// Round 6
// 4315.794 us; speedup vs baseline: 5.7189x; 1.2210x over previous
//
#include <hip/hip_runtime.h>
#include <cfloat>

// ---------------------------------------------------------------------------
// SearchTransfer (TTSR): 3-level patch correlation + argmax + gather/fold.
// Levels: 0 = lv3 (C=256,H=64,k=3,s=1,p=1,D=2304)
//         1 = lv2 (C=128,H=128,k=6,s=2,p=2,D=4608)
//         2 = lv1 (C=64,H=256,k=12,s=4,p=4,D=9216)
//
// score(l,m) = ninv[m]*G[l,m] - mval*P[l] - mval*ninv[m]*csum[m] + D*mval^2
// lev0: bf16x3 split, 6 products (exact argmax chain, old 128^2 kernel).
// lev1/2: bf16x2 split, 3 products, NEW 256^2 counted-vmcnt phase kernel.
// ---------------------------------------------------------------------------

typedef short short8 __attribute__((ext_vector_type(8)));
typedef float f32x4  __attribute__((ext_vector_type(4)));

template<int LEV> struct LT;
template<> struct LT<0> { static constexpr int C=256, H=64,  K=3,  S=1, P=1; };
template<> struct LT<1> { static constexpr int C=128, H=128, K=6,  S=2, P=2; };
template<> struct LT<2> { static constexpr int C=64,  H=256, K=12, S=4, P=4; };

__host__ __device__ constexpr int lev_D(int lev){ return lev==0?2304:(lev==1?4608:9216); }
// ws float-index offsets
// [0,192): scalar slots: lev*64 + q*16 + slot (q:0=sum_rs,1=ssq_rs,2=sum_lr,3=ssq_lr)
// 200+lev: mval  204+lev: scale  208: gy2_lev0  212+lev: gx2
__host__ __device__ constexpr int rho_off(int lev){ return 256 + (lev>0?2*2304:0) + (lev>1?2*4608:0); }
__host__ __device__ constexpr int p_off(int lev)   { return 32512  + lev*8192;   }
__host__ __device__ constexpr int ninv_off(int lev){ return 57088  + lev*8192;   }
__host__ __device__ constexpr int csum_off(int lev){ return 81664  + lev*8192;   }
__host__ __device__ constexpr int pmax_off(int lev){ return 106240 + lev*262144; }
__host__ __device__ constexpr int parg_off(int lev){ return 892672 + lev*262144; }
__host__ __device__ constexpr int arg_off(){ return 1679104; }
static constexpr size_t G_BASE_BYTES      = 8ull  << 20;
static constexpr size_t CHUNK_PLANE_BYTES = 72ull << 20;

__device__ inline unsigned short f2bf(float f){
    unsigned int u = __float_as_uint(f);
    return (unsigned short)((u + 0x7fffu + ((u >> 16) & 1u)) >> 16);
}
__device__ inline float bf2f(unsigned short h){ return __uint_as_float(((unsigned)h) << 16); }

#define GLOAD16(g, l) __builtin_amdgcn_global_load_lds( \
    (const __attribute__((address_space(1))) unsigned int*)(g), \
    (__attribute__((address_space(3))) unsigned int*)(l), 16, 0, 0)

__device__ __forceinline__ void barx(){
    __builtin_amdgcn_sched_barrier(0);
    __builtin_amdgcn_s_barrier();
    __builtin_amdgcn_sched_barrier(0);
}

// --- per-(b,d) row norm of refsr unfold + rs scalar slots ---
template<int LEV>
__global__ void k_rownorm(const float* __restrict__ refsr, float* __restrict__ ws){
    constexpr int C=LT<LEV>::C, H=LT<LEV>::H, K=LT<LEV>::K, S=LT<LEV>::S, PD=LT<LEV>::P;
    constexpr int D = C*K*K, KK=K*K;
    __shared__ float sh0[4], sh1[4];
    int tid = threadIdx.x, lane = tid & 63, w = tid >> 6;
    int wid = (blockIdx.x*blockDim.x + tid) >> 6;
    int b = wid / D, d = wid % D;
    int c = d/KK, rem = d%KK, ki = rem/K, kj = rem%K;
    const float* img = refsr + (size_t)(b*C + c)*H*H;
    float sum=0.f, ssq=0.f;
    for (int idx=lane; idx<4096; idx+=64){
        int ho=idx>>6, wo=idx&63;
        int row = ho*S+ki-PD, col = wo*S+kj-PD;
        if (row>=0 && row<H && col>=0 && col<H){
            float v = img[row*H+col]; sum += v; ssq += v*v;
        }
    }
    #pragma unroll
    for (int off=32; off; off>>=1){ sum += __shfl_xor(sum,off); ssq += __shfl_xor(ssq,off); }
    if (lane==0){
        float rinv = 1.0f / fmaxf(sqrtf(ssq), 1e-12f);
        ws[rho_off(LEV) + b*D + d] = rinv;
        sh0[w] = sum*rinv;
        sh1[w] = ssq*rinv*rinv;
    }
    __syncthreads();
    if (tid==0){
        int s = blockIdx.x & 15;
        atomicAdd(&ws[LEV*64 + 0*16 + s], sh0[0]+sh0[1]+sh0[2]+sh0[3]);
        atomicAdd(&ws[LEV*64 + 1*16 + s], sh1[0]+sh1[1]+sh1[2]+sh1[3]);
    }
}

template<int LEV>
__global__ void k_scalar_early(float* __restrict__ ws){
    if (threadIdx.x || blockIdx.x) return;
    float s0=0.f, s1=0.f;
    for (int s=0;s<16;s++){ s0 += ws[LEV*64+s]; s1 += ws[LEV*64+16+s]; }
    float BDL = 2.0f * (float)lev_D(LEV) * 4096.0f;
    float m = s0 / BDL;
    ws[200+LEV] = m;
    ws[212+LEV] = s1 - 2.f*m*s0 + BDL*m*m;
}

// --- bf16 split (NSP planes), 16B slots swizzled: slot ^= (row>>1)&3 ---
template<int LEV, bool ISA, int NSP>
__global__ void k_split(const float* __restrict__ img4, const float* __restrict__ ws,
                        unsigned short* __restrict__ base, int b, int kb0, int kd){
    constexpr int C=LT<LEV>::C, H=LT<LEV>::H, K=LT<LEV>::K, S=LT<LEV>::S, PD=LT<LEV>::P;
    constexpr int KK=K*K;
    const size_t PS = (size_t)4096 * kd;
    int gid = blockIdx.x*256 + threadIdx.x;
    int kslots = kd >> 3;
    if (gid >= 4096*kslots) return;
    int kb = gid % kslots, l = gid / kslots;
    int kl0 = kb*8;
    int ly = l>>6, lx = l&63;
    const float* img = img4 + (size_t)b*C*H*H;
    const float* rinv = ws + rho_off(LEV) + b*lev_D(LEV);
    unsigned short h[NSP][8];
    #pragma unroll
    for (int j=0;j<8;j++){
        int k = kb0 + kl0 + j; int c=k/KK, rem=k%KK, ki=rem/K, kj=rem%K;
        int row=ly*S+ki-PD, col=lx*S+kj-PD;
        float x = (row>=0 && row<H && col>=0 && col<H)
                  ? img[(size_t)(c*H+row)*H+col] : 0.f;
        if (ISA) x *= rinv[k];
        unsigned short a = f2bf(x); h[0][j]=a;
        float r = x - bf2f(a);
        unsigned short m = f2bf(r); h[1][j]=m;
        if (NSP==3){ float r2 = r - bf2f(m); h[2][j]=f2bf(r2); }
    }
    int slot = (kl0>>3)&3, sw = slot ^ ((l>>1)&3);
    size_t off = (size_t)l*kd + (size_t)(kl0 & ~31) + sw*8;
    #pragma unroll
    for (int q=0;q<NSP;q++){
        uint4 u;
        u.x=h[q][0]|((unsigned)h[q][1]<<16); u.y=h[q][2]|((unsigned)h[q][3]<<16);
        u.z=h[q][4]|((unsigned)h[q][5]<<16); u.w=h[q][6]|((unsigned)h[q][7]<<16);
        *(uint4*)(base + q*PS + off) = u;
    }
}

// --- merged row-stat kernel: side0 (rs) -> P[l]; side1 (lr) -> csum+ssq ---
template<int NSP>
__global__ void k_stats2(const unsigned short* __restrict__ rs,
                         const unsigned short* __restrict__ lr, size_t PS,
                         float* __restrict__ Pdst, float* __restrict__ csum,
                         float* __restrict__ ssqd, int kd, int first, int b){
    int tid = threadIdx.x, lane = tid & 63;
    int idx = (blockIdx.x*256 + tid) >> 6;   // 0..8191
    int side = idx >> 12, row = idx & 4095;
    const unsigned short* pl = side ? lr : rs;
    int ns = kd >> 3;
    float sum = 0.f, ssq = 0.f;
    for (int s = lane; s < ns; s += 64){
        const unsigned short* p0 = pl + (size_t)row*kd + s*8;
        short8 v0 = *(const short8*)p0;
        short8 v1 = *(const short8*)(p0 + PS);
        short8 v2{};
        if (NSP==3) v2 = *(const short8*)(p0 + 2*PS);
        #pragma unroll
        for (int j=0;j<8;j++){
            float x = bf2f((unsigned short)v0[j]) + bf2f((unsigned short)v1[j]);
            if (NSP==3) x += bf2f((unsigned short)v2[j]);
            sum += x; ssq += x*x;
        }
    }
    #pragma unroll
    for (int off=32; off; off>>=1){ sum += __shfl_xor(sum,off); ssq += __shfl_xor(ssq,off); }
    if (lane==0){
        int o = b*4096 + row;
        if (!side){ if (first) Pdst[o] = sum; else Pdst[o] += sum; }
        else {
            if (first){ csum[o] = sum; ssqd[o] = ssq; }
            else      { csum[o] += sum; ssqd[o] += ssq; }
        }
    }
}

template<int LEV>
__global__ void k_levfin(float* __restrict__ ws, int b){
    __shared__ float r0[4], r1[4];
    int tid = threadIdx.x, lane = tid & 63, w = tid >> 6;
    int m = blockIdx.x*256 + tid;
    float ssq = ws[ninv_off(LEV) + b*4096 + m];
    float ninv = 1.0f / fmaxf(sqrtf(ssq), 1e-12f);
    ws[ninv_off(LEV) + b*4096 + m] = ninv;
    float y0 = ws[csum_off(LEV) + b*4096 + m] * ninv;
    float y1 = ssq * ninv * ninv;
    #pragma unroll
    for (int off=32; off; off>>=1){ y0 += __shfl_xor(y0,off); y1 += __shfl_xor(y1,off); }
    if (lane==0){ r0[w]=y0; r1[w]=y1; }
    __syncthreads();
    if (tid==0){
        int s = blockIdx.x & 15;
        atomicAdd(&ws[LEV*64 + 2*16 + s], r0[0]+r0[1]+r0[2]+r0[3]);
        atomicAdd(&ws[LEV*64 + 3*16 + s], r1[0]+r1[1]+r1[2]+r1[3]);
    }
}

template<int LEV>
__global__ void k_scalar_late(float* __restrict__ ws){
    if (threadIdx.x || blockIdx.x) return;
    float s2=0.f, s3=0.f;
    for (int s=0;s<16;s++){ s2 += ws[LEV*64+32+s]; s3 += ws[LEV*64+48+s]; }
    float BDL = 2.0f * (float)lev_D(LEV) * 4096.0f;
    float m = ws[200+LEV];
    float gy2 = s3 - 2.f*m*s2 + BDL*m*m;
    if (LEV==0) ws[208] = gy2;
    float gx2 = ws[212+LEV];
    float gyu = (LEV==1) ? ws[208] : gy2;
    ws[204+LEV] = 1.0f/(sqrtf(gx2)*sqrtf(gyu));
}

// ===========================================================================
// NEW: 256^2 counted-vmcnt phase GEMM, NSP=2 (3 products). 512 thr, 128KB LDS.
// MODE 0: fused score/max/argmax. MODE 1: G = acc. MODE 2: G += acc.
// ===========================================================================
template<int LEV, int MODE>
__launch_bounds__(512, 2)
__global__ void k_g8(const unsigned short* __restrict__ planes,
                     float* __restrict__ ws, float* __restrict__ G,
                     int b, int kd){
    const size_t PS = (size_t)4096 * kd;
    __shared__ unsigned short lds[2*4*256*32];   // 128 KB
    const int tid = threadIdx.x;
    const int w = tid >> 6, lane = tid & 63;
    const int mblk = blockIdx.x, lblk = blockIdx.y;
    const int wm = w >> 2, wn = w & 3;
    const int colrow = lane & 15, rgrp = lane >> 4;
    const int swz = (rgrp ^ ((lane >> 1) & 3)) * 8;
    const int abase = wm*4096 + colrow*32 + swz;          // + pl*8192 + i*512
    const int bbase = 2*8192 + wn*2048 + colrow*32 + swz; // + pl*8192 + j*512
    const int NT = kd >> 5;

    f32x4 acc[8][4];
    #pragma unroll
    for (int i=0;i<8;i++)
        #pragma unroll
        for (int j=0;j<4;j++) acc[i][j] = (f32x4){0.f,0.f,0.f,0.f};

    short8 aF[2][4], bF[2][4];

#define STAGE2(bufv, k0v, q0v) do { \
    _Pragma("unroll") \
    for (int e=0;e<2;e++){ \
        int flat = w*8 + (q0v) + e; \
        int p = flat >> 4; \
        int rb = (flat & 15) << 4; \
        int rowbase = (p < 2 ? lblk : mblk) << 8; \
        const unsigned short* g = planes + (size_t)p*PS \
            + (size_t)(rowbase + rb + (lane>>2))*kd + (size_t)(k0v) + (lane&3)*8; \
        unsigned short* lp = (unsigned short*)&lds[(bufv)*32768 + p*8192 + rb*32]; \
        GLOAD16(g, lp); \
    } \
} while(0)

#define RDA(bufv, half) do { \
    _Pragma("unroll") \
    for (int pl=0; pl<2; pl++) \
        _Pragma("unroll") \
        for (int i=0;i<4;i++) \
            aF[pl][i] = *(const short8*)&lds[(bufv)*32768 + pl*8192 + abase + ((half)*4+i)*512]; \
} while(0)

#define RDB(bufv, half) do { \
    _Pragma("unroll") \
    for (int pl=0; pl<2; pl++) \
        _Pragma("unroll") \
        for (int j=0;j<2;j++) \
            bF[pl][(half)*2+j] = *(const short8*)&lds[(bufv)*32768 + pl*8192 + bbase + ((half)*2+j)*512]; \
} while(0)

#define MM(ihalf, jhalf) do { \
    __builtin_amdgcn_s_setprio(1); \
    _Pragma("unroll") \
    for (int i=0;i<4;i++) \
        _Pragma("unroll") \
        for (int j=0;j<2;j++){ \
            const int ai = (ihalf)*4+i, bj = (jhalf)*2+j; \
            acc[ai][bj] = __builtin_amdgcn_mfma_f32_16x16x32_bf16(aF[0][i], bF[0][bj], acc[ai][bj],0,0,0); \
            acc[ai][bj] = __builtin_amdgcn_mfma_f32_16x16x32_bf16(aF[0][i], bF[1][bj], acc[ai][bj],0,0,0); \
            acc[ai][bj] = __builtin_amdgcn_mfma_f32_16x16x32_bf16(aF[1][i], bF[0][bj], acc[ai][bj],0,0,0); \
        } \
    __builtin_amdgcn_s_setprio(0); \
} while(0)

    // prologue: stage tile 0 into buf0, no drain (loop's vmcnt(2) handles it)
    STAGE2(0, 0, 0); STAGE2(0, 0, 2); STAGE2(0, 0, 4); STAGE2(0, 0, 6);

    int cur = 0;
    for (int kt = 0; kt < NT-1; kt++){
        const int k0n = (kt+1) << 5;
        STAGE2(cur^1, k0n, 0);
        asm volatile("s_waitcnt vmcnt(2)" ::: "memory");
        barx();                       // current tile fully resident for all waves
        RDB(cur, 0); RDA(cur, 0);
        MM(0, 0);
        STAGE2(cur^1, k0n, 2);
        RDB(cur, 1);
        MM(0, 1);
        STAGE2(cur^1, k0n, 4);
        RDA(cur, 1);
        MM(1, 1);
        STAGE2(cur^1, k0n, 6);
        MM(1, 0);
        barx();                       // all reads of buf[cur] done before reuse
        cur ^= 1;
    }
    // last tile (no further staging)
    asm volatile("s_waitcnt vmcnt(0)" ::: "memory");
    barx();
    RDB(cur, 0); RDA(cur, 0); MM(0, 0);
    RDB(cur, 1); MM(0, 1);
    RDA(cur, 1); MM(1, 1);
    MM(1, 0);

#undef STAGE2
#undef RDA
#undef RDB
#undef MM

    const int lbase = (lblk<<8) + wm*128;
    const int mbase = (mblk<<8) + wn*64;

    if (MODE != 0){
        #pragma unroll
        for (int i=0;i<8;i++){
            #pragma unroll
            for (int rg=0; rg<4; rg++){
                float* gp = G + (size_t)(lbase + i*16 + rgrp*4 + rg)*4096 + mbase + colrow;
                #pragma unroll
                for (int j=0;j<4;j++){
                    float v = acc[i][j][rg];
                    if (MODE == 2) v += gp[j*16];
                    gp[j*16] = v;
                }
            }
        }
        return;
    }

    // MODE 0: score + per-m max/argmax over this block's 256 l
    constexpr int D = lev_D(LEV);
    const float mval = ws[200+LEV];
    const float Dm2 = (float)D * mval * mval;
    const float* Pv  = ws + p_off(LEV)    + b*4096;
    const float* NIv = ws + ninv_off(LEV) + b*4096;
    const float* CSv = ws + csum_off(LEV) + b*4096;
    barx();                           // safe to reuse LDS
    float* smax = (float*)lds;                 // [2][256]
    int*   sarg = (int*)((char*)lds + 2048);   // [2][256]
    #pragma unroll
    for (int j=0;j<4;j++){
        int m = mbase + j*16 + colrow;
        float nv = NIv[m];
        float cmv = -mval*nv*CSv[m] + Dm2;
        float v = -FLT_MAX; int vi = 0x7fffffff;
        #pragma unroll
        for (int i=0;i<8;i++){
            #pragma unroll
            for (int rg=0; rg<4; rg++){
                int l = lbase + i*16 + rgrp*4 + rg;
                float sc = nv*acc[i][j][rg] - mval*Pv[l] + cmv;
                if (sc > v){ v = sc; vi = l; }
            }
        }
        #pragma unroll
        for (int off=16; off<64; off<<=1){
            float ov = __shfl_xor(v, off);
            int   oi = __shfl_xor(vi, off);
            if (ov > v || (ov == v && oi < vi)){ v = ov; vi = oi; }
        }
        if (rgrp == 0){
            smax[wm*256 + wn*64 + j*16 + colrow] = v;
            sarg[wm*256 + wn*64 + j*16 + colrow] = vi;
        }
    }
    barx();
    if (tid < 256){
        float v0 = smax[tid];     int a0 = sarg[tid];
        float v1 = smax[256+tid]; int a1 = sarg[256+tid];
        if (v1 > v0 || (v1 == v0 && a1 < a0)){ v0 = v1; a0 = a1; }
        int o = (b*32 + lblk)*4096 + (mblk<<8) + tid;
        ws[pmax_off(LEV) + o] = v0;
        ((int*)ws)[parg_off(LEV) + o] = a0;
    }
}

// --- OLD 128^2 MFMA GEMM (kept for lev0 bf16x3 exact chain) ---
template<int LEV, int MODE, int NSP>
__launch_bounds__(256, 2)
__global__ void k_gmfma(const unsigned short* __restrict__ planes,
                        float* __restrict__ ws, float* __restrict__ G,
                        int b, int kd){
    const size_t PS = (size_t)4096 * kd;
    __shared__ unsigned short lds[2*NSP*128*32];
    const int tid = threadIdx.x;
    const int w = tid >> 6, lane = tid & 63;
    const int mblk = blockIdx.x, lblk = blockIdx.y;
    const int lw = w >> 1, mw = w & 1;

    f32x4 acc[4][4];
    #pragma unroll
    for (int i=0;i<4;i++)
        #pragma unroll
        for (int j=0;j<4;j++) acc[i][j] = (f32x4){0.f,0.f,0.f,0.f};

    const int srow = lane >> 2, ssl = lane & 3;
    const int colrow = lane & 15, kk = lane >> 4;
    const int swz = (kk ^ ((lane >> 1) & 3)) * 8;
    const int aRow0 = lw*64 + colrow;
    const int bRow0 = mw*64 + colrow;

    for (int k0 = 0; k0 < kd; k0 += 32){
        #pragma unroll
        for (int p = 0; p < 2*NSP; p++){
            const int rb = (p < NSP ? lblk : mblk)*128 + w*32 + srow;
            const unsigned short* gp0 = planes + (size_t)p*PS
                                        + (size_t)rb*kd + (size_t)k0 + ssl*8;
            unsigned short* lp0 = &lds[p*4096 + w*1024];
            GLOAD16(gp0, lp0);
            GLOAD16(gp0 + (size_t)16*kd, lp0 + 512);
        }
        __syncthreads();

        short8 aF[NSP][4];
        #pragma unroll
        for (int pa=0; pa<NSP; pa++)
            #pragma unroll
            for (int i=0;i<4;i++)
                aF[pa][i] = *(const short8*)&lds[pa*4096 + (aRow0 + i*16)*32 + swz];
        #pragma unroll
        for (int pb=0; pb<NSP; pb++){
            short8 bF[4];
            #pragma unroll
            for (int j=0;j<4;j++)
                bF[j] = *(const short8*)&lds[(NSP+pb)*4096 + (bRow0 + j*16)*32 + swz];
            const int npa = NSP - pb;
            for (int pa=0; pa<npa; pa++)
                #pragma unroll
                for (int i=0;i<4;i++)
                    #pragma unroll
                    for (int j=0;j<4;j++)
                        acc[i][j] = __builtin_amdgcn_mfma_f32_16x16x32_bf16(
                                        aF[pa][i], bF[j], acc[i][j], 0, 0, 0);
        }
        __syncthreads();
    }

    const int lbase = lblk*128 + lw*64;
    const int mbase = mblk*128 + mw*64;
    const int rgrp = lane >> 4;

    if (MODE != 0){
        #pragma unroll
        for (int i=0;i<4;i++){
            #pragma unroll
            for (int rg=0; rg<4; rg++){
                float* gp = G + (size_t)(lbase + i*16 + rgrp*4 + rg)*4096
                              + mbase + colrow;
                #pragma unroll
                for (int j=0;j<4;j++){
                    float v = acc[i][j][rg];
                    if (MODE == 2) v += gp[j*16];
                    gp[j*16] = v;
                }
            }
        }
        return;
    }

    constexpr int D = lev_D(LEV);
    const float mval = ws[200+LEV];
    const float Dm2 = (float)D * mval * mval;
    const float* Pv  = ws + p_off(LEV)    + b*4096;
    const float* NIv = ws + ninv_off(LEV) + b*4096;
    const float* CSv = ws + csum_off(LEV) + b*4096;
    float* smax = (float*)lds;
    int*   sarg = (int*)&lds[512];
    #pragma unroll
    for (int j=0;j<4;j++){
        int m = mbase + j*16 + colrow;
        float nv = NIv[m];
        float cmv = -mval*nv*CSv[m] + Dm2;
        float v = -FLT_MAX; int vi = 0x7fffffff;
        #pragma unroll
        for (int i=0;i<4;i++){
            #pragma unroll
            for (int rg=0; rg<4; rg++){
                int l = lbase + i*16 + rgrp*4 + rg;
                float sc = nv*acc[i][j][rg] - mval*Pv[l] + cmv;
                if (sc > v){ v = sc; vi = l; }
            }
        }
        #pragma unroll
        for (int off=16; off<64; off<<=1){
            float ov = __shfl_xor(v, off);
            int   oi = __shfl_xor(vi, off);
            if (ov > v || (ov == v && oi < vi)){ v = ov; vi = oi; }
        }
        if (rgrp == 0){
            smax[w*64 + j*16 + colrow] = v;
            sarg[w*64 + j*16 + colrow] = vi;
        }
    }
    __syncthreads();
    if (tid < 128){
        int mg = tid >> 6, idx = tid & 63;
        float v0 = smax[mg*64 + idx];     int a0 = sarg[mg*64 + idx];
        float v1 = smax[(mg+2)*64 + idx]; int a1 = sarg[(mg+2)*64 + idx];
        if (v1 > v0 || (v1 == v0 && a1 < a0)){ v0 = v1; a0 = a1; }
        int m = mblk*128 + mg*64 + idx;
        int o = (b*32 + lblk)*4096 + m;
        ws[pmax_off(LEV) + o] = v0;
        ((int*)ws)[parg_off(LEV) + o] = a0;
    }
}

// --- score + max/argmax from accumulated G; grid (64 mblk, 8 lsplit) ---
template<int LEV>
__global__ void k_score(const float* __restrict__ G, float* __restrict__ ws, int b){
    constexpr int D = lev_D(LEV);
    __shared__ float smax[4][64];
    __shared__ int   sarg[4][64];
    int tid = threadIdx.x, mloc = tid & 63, r = tid >> 6;
    int m = blockIdx.x*64 + mloc;
    int l0 = blockIdx.y*512;
    float mval = ws[200+LEV];
    float nv = ws[ninv_off(LEV) + b*4096 + m];
    float cmv = -mval*nv*ws[csum_off(LEV) + b*4096 + m] + (float)D*mval*mval;
    const float* Pv = ws + p_off(LEV) + b*4096;
    float best = -FLT_MAX; int bi = 0x7fffffff;
    for (int lt=0; lt<128; lt++){
        int l = l0 + lt*4 + r;
        float sc = nv*G[(size_t)l*4096 + m] - mval*Pv[l] + cmv;
        if (sc > best){ best = sc; bi = l; }
    }
    smax[r][mloc] = best; sarg[r][mloc] = bi;
    __syncthreads();
    if (tid < 64){
        float v = smax[0][tid]; int vi = sarg[0][tid];
        #pragma unroll
        for (int rr=1; rr<4; rr++){
            float ov = smax[rr][tid]; int oi = sarg[rr][tid];
            if (ov > v || (ov == v && oi < vi)){ v = ov; vi = oi; }
        }
        int o = (b*32 + blockIdx.y)*4096 + blockIdx.x*64 + tid;
        ws[pmax_off(LEV) + o] = v;
        ((int*)ws)[parg_off(LEV) + o] = vi;
    }
}

// --- fp32 VALU fallback GEMM (last-resort, tiny ws) ---
template<int LEV>
__launch_bounds__(256)
__global__ void k_corr(const float* __restrict__ refsr, const float* __restrict__ lrsr,
                       float* __restrict__ ws){
    constexpr int C=LT<LEV>::C, H=LT<LEV>::H, K=LT<LEV>::K, S=LT<LEV>::S, PD=LT<LEV>::P;
    constexpr int D = C*K*K, KK=K*K;
    __shared__ float As[32][64];
    __shared__ float Bs[32][64];
    int tid = threadIdx.x, tr = tid & 15, tc = tid >> 4;
    int my = blockIdx.x, lchunk = blockIdx.y, b = blockIdx.z;
    const float* rimg = refsr + (size_t)b*C*H*H;
    const float* limg = lrsr  + (size_t)b*C*H*H;
    const float* rinv = ws + rho_off(LEV) + b*D;

    float mval = ws[200+LEV];
    float Dm2 = (float)D * mval * mval;
    float niv[4], cm[4];
    #pragma unroll
    for (int j=0;j<4;j++){
        int m = my*64 + tc*4 + j;
        float nv = ws[ninv_off(LEV) + b*4096 + m];
        niv[j] = nv;
        cm[j] = -mval*nv*ws[csum_off(LEV) + b*4096 + m] + Dm2;
    }
    float rmax[4] = {-FLT_MAX,-FLT_MAX,-FLT_MAX,-FLT_MAX};
    int   rarg[4] = {0x7fffffff,0x7fffffff,0x7fffffff,0x7fffffff};

    for (int lt=0; lt<8; lt++){
        int ly = lchunk*8 + lt;
        float acc[4][4];
        #pragma unroll
        for (int i=0;i<4;i++)
            #pragma unroll
            for (int j=0;j<4;j++) acc[i][j]=0.f;

        for (int d0=0; d0<D; d0+=32){
            #pragma unroll
            for (int it=0; it<8; it++){
                int e = tid + it*256;
                int t = e>>6, xx = e&63;
                int d = d0+t;
                int c = d/KK, rem = d%KK, ki = rem/K, kj = rem%K;
                int arow = ly*S+ki-PD, acol = xx*S+kj-PD;
                float av = (arow>=0 && arow<H && acol>=0 && acol<H)
                           ? rimg[(size_t)(c*H+arow)*H + acol] : 0.f;
                As[t][xx] = av * rinv[d];
                int brow = my*S+ki-PD, bcol = xx*S+kj-PD;
                Bs[t][xx] = (brow>=0 && brow<H && bcol>=0 && bcol<H)
                           ? limg[(size_t)(c*H+brow)*H + bcol] : 0.f;
            }
            __syncthreads();
            #pragma unroll 8
            for (int t=0;t<32;t++){
                float av[4], bv[4];
                *(float4*)av = *(const float4*)&As[t][tr*4];
                *(float4*)bv = *(const float4*)&Bs[t][tc*4];
                #pragma unroll
                for (int i=0;i<4;i++)
                    #pragma unroll
                    for (int j=0;j<4;j++)
                        acc[i][j] = fmaf(av[i], bv[j], acc[i][j]);
            }
            __syncthreads();
        }

        float Pl[4];
        #pragma unroll
        for (int i=0;i<4;i++) Pl[i] = ws[p_off(LEV) + b*4096 + ly*64 + tr*4 + i];
        #pragma unroll
        for (int j=0;j<4;j++){
            float v = -FLT_MAX; int vi = 0x7fffffff;
            #pragma unroll
            for (int i=0;i<4;i++){
                float sc = niv[j]*acc[i][j] - mval*Pl[i] + cm[j];
                if (sc > v){ v = sc; vi = ly*64 + tr*4 + i; }
            }
            #pragma unroll
            for (int off=1; off<16; off<<=1){
                float ov = __shfl_xor(v, off, 16);
                int   oi = __shfl_xor(vi, off, 16);
                if (ov > v || (ov == v && oi < vi)){ v = ov; vi = oi; }
            }
            if (v > rmax[j] || (v == rmax[j] && vi < rarg[j])){ rmax[j]=v; rarg[j]=vi; }
        }
    }
    if (tr==0){
        #pragma unroll
        for (int j=0;j<4;j++){
            int m = my*64 + tc*4 + j;
            int o = (b*32 + lchunk)*4096 + m;
            ws[pmax_off(LEV) + o] = rmax[j];
            ((int*)ws)[parg_off(LEV) + o] = rarg[j];
        }
    }
}

// --- reduce l-chunks -> S3,S2,S1,arg outputs (applies late scale) ---
__global__ void k_smax(float* __restrict__ ws, float* __restrict__ out,
                       int nch0, int nch1, int nch2){
    int gid = blockIdx.x*256 + threadIdx.x;
    if (gid >= 8192) return;
    int b = gid >> 12, m = gid & 4095;
    int nchs[3] = {nch0, nch1, nch2};
    for (int lev=0; lev<3; lev++){
        float mv = -FLT_MAX; int ma = 0x7fffffff;
        for (int ch=0; ch<nchs[lev]; ch++){
            int o = ((b*32+ch)<<12) + m;
            float v = ws[pmax_off(lev) + o];
            int   a = ((const int*)ws)[parg_off(lev) + o];
            if (v > mv || (v == mv && a < ma)){ mv=v; ma=a; }
        }
        out[lev*8192 + gid] = mv * ws[204+lev];
        if (lev==0){
            out[3*8192 + gid] = (float)ma;
            ((int*)ws)[arg_off() + gid] = ma;
        }
    }
}

// --- T = fold(gather(unfold(ref), arg)) / 9 ---
template<int LEV>
__global__ void k_transfer(const float* __restrict__ ref, const float* __restrict__ wsf,
                           float* __restrict__ outT){
    constexpr int C=LT<LEV>::C, H=LT<LEV>::H, K=LT<LEV>::K, S=LT<LEV>::S, PD=LT<LEV>::P;
    const int* arg = (const int*)wsf + arg_off();
    size_t gid = (size_t)blockIdx.x*256 + threadIdx.x;
    size_t total = (size_t)2*C*H*H;
    if (gid >= total) return;
    int x = (int)(gid % H);
    int y = (int)((gid / H) % H);
    int c = (int)((gid / ((size_t)H*H)) % C);
    int b = (int)(gid / ((size_t)C*H*H));
    const float* rimg = ref + (size_t)(b*C+c)*H*H;
    int byo = (y+PD)/S, ryo = (y+PD)%S;
    int bxo = (x+PD)/S, rxo = (x+PD)%S;
    float acc = 0.f;
    #pragma unroll
    for (int jy=0; jy<3; jy++){
        int ho = byo - jy;
        if (ho < 0 || ho >= 64) continue;
        int ki = ryo + jy*S;
        #pragma unroll
        for (int jx=0; jx<3; jx++){
            int wo = bxo - jx;
            if (wo < 0 || wo >= 64) continue;
            int kj = rxo + jx*S;
            int l = arg[b*4096 + ho*64 + wo];
            int ly = l>>6, lx = l&63;
            int srow = ly*S + ki - PD, scol = lx*S + kj - PD;
            if (srow>=0 && srow<H && scol>=0 && scol<H)
                acc += rimg[srow*H + scol];
        }
    }
    outT[gid] = acc * (1.0f/9.0f);
}

template<int LEV>
static void run_level(const float* refsr, const float* lrsr, float* ws,
                      size_t ws_size, hipStream_t stream, int* nch){
    constexpr int D = lev_D(LEV);
    constexpr int NSP = (LEV==0) ? 3 : 2;
    k_rownorm<LEV><<<D/2, 256, 0, stream>>>(refsr, ws);
    k_scalar_early<LEV><<<1, 64, 0, stream>>>(ws);

    auto planeBytes = [](int c){ return (size_t)4*NSP*4096*c; };
    bool fused = (ws_size >= G_BASE_BYTES + planeBytes(D));
    int kd = D;
    if (!fused){
        kd = 0;
        for (int div = 2; div <= 16; div <<= 1){
            if (ws_size >= CHUNK_PLANE_BYTES + planeBytes(D/div)){ kd = D/div; break; }
        }
        if (!kd){
            nch[LEV] = 8;
            k_corr<LEV><<<dim3(64,8,2), 256, 0, stream>>>(refsr, lrsr, ws);
            k_levfin<LEV><<<16, 256, 0, stream>>>(ws, 0);   // ninv needed pre-corr...
            return;  // (unreachable in practice; ws is large)
        }
    }
    unsigned short* pl = (unsigned short*)((char*)ws + (fused ? G_BASE_BYTES : CHUNK_PLANE_BYTES));
    float* G = ws + (G_BASE_BYTES >> 2);
    const size_t PS = (size_t)4096 * kd;
    const int nkc = D / kd;
    nch[LEV] = fused ? ((LEV==0) ? 32 : 16) : 8;

    for (int b=0; b<2; b++){
        for (int kc=0; kc<nkc; kc++){
            k_split<LEV,true ,NSP><<<2*kd, 256, 0, stream>>>(refsr, ws, pl, b, kc*kd, kd);
            k_split<LEV,false,NSP><<<2*kd, 256, 0, stream>>>(lrsr,  ws, pl + NSP*PS, b, kc*kd, kd);
            k_stats2<NSP><<<2048, 256, 0, stream>>>(pl, pl + NSP*PS, PS,
                ws + p_off(LEV), ws + csum_off(LEV), ws + ninv_off(LEV), kd, kc==0, b);
            if (!fused){
                if (LEV==0){
                    if (kc==0) k_gmfma<0,1,3><<<dim3(32,32), 256, 0, stream>>>(pl, ws, G, b, kd);
                    else       k_gmfma<0,2,3><<<dim3(32,32), 256, 0, stream>>>(pl, ws, G, b, kd);
                } else {
                    if (kc==0) k_g8<LEV,1><<<dim3(16,16), 512, 0, stream>>>(pl, ws, G, b, kd);
                    else       k_g8<LEV,2><<<dim3(16,16), 512, 0, stream>>>(pl, ws, G, b, kd);
                }
            }
        }
        k_levfin<LEV><<<16, 256, 0, stream>>>(ws, b);
        if (fused){
            if (LEV==0) k_gmfma<0,0,3><<<dim3(32,32), 256, 0, stream>>>(pl, ws, G, b, kd);
            else        k_g8<LEV,0><<<dim3(16,16), 512, 0, stream>>>(pl, ws, G, b, kd);
        } else {
            k_score<LEV><<<dim3(64,8), 256, 0, stream>>>(G, ws, b);
        }
    }
    k_scalar_late<LEV><<<1, 64, 0, stream>>>(ws);
}

extern "C" void kernel_launch(void* const* d_in, const int* in_sizes, int n_in,
                              void* d_out, int out_size, void* d_ws, size_t ws_size,
                              hipStream_t stream){
    const float* lrsr[3]  = { (const float*)d_in[2], (const float*)d_in[1], (const float*)d_in[0] };
    const float* refsr[3] = { (const float*)d_in[5], (const float*)d_in[4], (const float*)d_in[3] };
    const float* refp[3]  = { (const float*)d_in[8], (const float*)d_in[7], (const float*)d_in[6] };
    float* ws  = (float*)d_ws;
    float* out = (float*)d_out;

    hipMemsetAsync(d_ws, 0, 4096, stream);  // zero scalar slots + scalars

    int nch[3];
    run_level<0>(refsr[0], lrsr[0], ws, ws_size, stream, nch);
    run_level<1>(refsr[1], lrsr[1], ws, ws_size, stream, nch);
    run_level<2>(refsr[2], lrsr[2], ws, ws_size, stream, nch);

    k_smax<<<32, 256, 0, stream>>>(ws, out, nch[0], nch[1], nch[2]);

    k_transfer<0><<< (2*256*64*64)/256,   256, 0, stream>>>(refp[0], ws, out + 32768);
    k_transfer<1><<< (2*128*128*128)/256, 256, 0, stream>>>(refp[1], ws, out + 2129920);
    k_transfer<2><<< (2*64*256*256)/256,  256, 0, stream>>>(refp[2], ws, out + 6324224);
}

// Round 8
// 3099.207 us; speedup vs baseline: 7.9638x; 1.3925x over previous
//
#include <hip/hip_runtime.h>
#include <cfloat>

// ---------------------------------------------------------------------------
// SearchTransfer (TTSR): 3-level patch correlation + argmax + gather/fold.
// Levels: 0 = lv3 (C=256,H=64,k=3,s=1,p=1,D=2304)
//         1 = lv2 (C=128,H=128,k=6,s=2,p=2,D=4608)
//         2 = lv1 (C=64,H=256,k=12,s=4,p=4,D=9216)
//
// score(l,m) = ninv[m]*G[l,m] - mval*P[l] - mval*ninv[m]*csum[m] + D*mval^2
// lev0: bf16x3 split, 6 products (exact argmax chain -> arg, T1-T3).
// lev1/2: single bf16 (NSP=1), 1 product, 256^2 counted-vmcnt kernel.
//   (only max VALUE consumed; error ~1.5e-8 after the ~1.6e-4 global scale,
//    vs ~1.6e-7 output threshold)
// ---------------------------------------------------------------------------

typedef short short8 __attribute__((ext_vector_type(8)));
typedef float f32x4  __attribute__((ext_vector_type(4)));

template<int LEV> struct LT;
template<> struct LT<0> { static constexpr int C=256, H=64,  K=3,  S=1, P=1; };
template<> struct LT<1> { static constexpr int C=128, H=128, K=6,  S=2, P=2; };
template<> struct LT<2> { static constexpr int C=64,  H=256, K=12, S=4, P=4; };

__host__ __device__ constexpr int lev_D(int lev){ return lev==0?2304:(lev==1?4608:9216); }
// ws float-index offsets
// [0,192): scalar slots: lev*64 + q*16 + slot (q:0=sum_rs,1=ssq_rs,2=sum_lr,3=ssq_lr)
// 200+lev: mval  204+lev: scale  208: gy2_lev0  212+lev: gx2
__host__ __device__ constexpr int rho_off(int lev){ return 256 + (lev>0?2*2304:0) + (lev>1?2*4608:0); }
__host__ __device__ constexpr int p_off(int lev)   { return 32512  + lev*8192;   }
__host__ __device__ constexpr int ninv_off(int lev){ return 57088  + lev*8192;   }
__host__ __device__ constexpr int csum_off(int lev){ return 81664  + lev*8192;   }
__host__ __device__ constexpr int pmax_off(int lev){ return 106240 + lev*262144; }
__host__ __device__ constexpr int parg_off(int lev){ return 892672 + lev*262144; }
__host__ __device__ constexpr int arg_off(){ return 1679104; }
static constexpr size_t G_BASE_BYTES      = 8ull  << 20;
static constexpr size_t CHUNK_PLANE_BYTES = 72ull << 20;

__device__ inline unsigned short f2bf(float f){
    unsigned int u = __float_as_uint(f);
    return (unsigned short)((u + 0x7fffu + ((u >> 16) & 1u)) >> 16);
}
__device__ inline float bf2f(unsigned short h){ return __uint_as_float(((unsigned)h) << 16); }

#define GLOAD16(g, l) __builtin_amdgcn_global_load_lds( \
    (const __attribute__((address_space(1))) unsigned int*)(g), \
    (__attribute__((address_space(3))) unsigned int*)(l), 16, 0, 0)

__device__ __forceinline__ void barx(){
    __builtin_amdgcn_sched_barrier(0);
    __builtin_amdgcn_s_barrier();
    __builtin_amdgcn_sched_barrier(0);
}

// --- per-(b,d) row norm of refsr unfold + rs scalar slots ---
template<int LEV>
__global__ void k_rownorm(const float* __restrict__ refsr, float* __restrict__ ws){
    constexpr int C=LT<LEV>::C, H=LT<LEV>::H, K=LT<LEV>::K, S=LT<LEV>::S, PD=LT<LEV>::P;
    constexpr int D = C*K*K, KK=K*K;
    __shared__ float sh0[4], sh1[4];
    int tid = threadIdx.x, lane = tid & 63, w = tid >> 6;
    int wid = (blockIdx.x*blockDim.x + tid) >> 6;
    int b = wid / D, d = wid % D;
    int c = d/KK, rem = d%KK, ki = rem/K, kj = rem%K;
    const float* img = refsr + (size_t)(b*C + c)*H*H;
    float sum=0.f, ssq=0.f;
    for (int idx=lane; idx<4096; idx+=64){
        int ho=idx>>6, wo=idx&63;
        int row = ho*S+ki-PD, col = wo*S+kj-PD;
        if (row>=0 && row<H && col>=0 && col<H){
            float v = img[row*H+col]; sum += v; ssq += v*v;
        }
    }
    #pragma unroll
    for (int off=32; off; off>>=1){ sum += __shfl_xor(sum,off); ssq += __shfl_xor(ssq,off); }
    if (lane==0){
        float rinv = 1.0f / fmaxf(sqrtf(ssq), 1e-12f);
        ws[rho_off(LEV) + b*D + d] = rinv;
        sh0[w] = sum*rinv;
        sh1[w] = ssq*rinv*rinv;
    }
    __syncthreads();
    if (tid==0){
        int s = blockIdx.x & 15;
        atomicAdd(&ws[LEV*64 + 0*16 + s], sh0[0]+sh0[1]+sh0[2]+sh0[3]);
        atomicAdd(&ws[LEV*64 + 1*16 + s], sh1[0]+sh1[1]+sh1[2]+sh1[3]);
    }
}

template<int LEV>
__global__ void k_scalar_early(float* __restrict__ ws){
    if (threadIdx.x || blockIdx.x) return;
    float s0=0.f, s1=0.f;
    for (int s=0;s<16;s++){ s0 += ws[LEV*64+s]; s1 += ws[LEV*64+16+s]; }
    float BDL = 2.0f * (float)lev_D(LEV) * 4096.0f;
    float m = s0 / BDL;
    ws[200+LEV] = m;
    ws[212+LEV] = s1 - 2.f*m*s0 + BDL*m*m;
}

// --- bf16 split (NSP planes), 16B slots swizzled: slot ^= (row>>1)&3 ---
template<int LEV, bool ISA, int NSP>
__global__ void k_split(const float* __restrict__ img4, const float* __restrict__ ws,
                        unsigned short* __restrict__ base, int b, int kb0, int kd){
    constexpr int C=LT<LEV>::C, H=LT<LEV>::H, K=LT<LEV>::K, S=LT<LEV>::S, PD=LT<LEV>::P;
    constexpr int KK=K*K;
    const size_t PS = (size_t)4096 * kd;
    int gid = blockIdx.x*256 + threadIdx.x;
    int kslots = kd >> 3;
    if (gid >= 4096*kslots) return;
    int kb = gid % kslots, l = gid / kslots;
    int kl0 = kb*8;
    int ly = l>>6, lx = l&63;
    const float* img = img4 + (size_t)b*C*H*H;
    const float* rinv = ws + rho_off(LEV) + b*lev_D(LEV);
    unsigned short h[NSP][8];
    #pragma unroll
    for (int j=0;j<8;j++){
        int k = kb0 + kl0 + j; int c=k/KK, rem=k%KK, ki=rem/K, kj=rem%K;
        int row=ly*S+ki-PD, col=lx*S+kj-PD;
        float x = (row>=0 && row<H && col>=0 && col<H)
                  ? img[(size_t)(c*H+row)*H+col] : 0.f;
        if (ISA) x *= rinv[k];
        unsigned short a = f2bf(x); h[0][j]=a;
        if (NSP>=2){
            float r = x - bf2f(a);
            unsigned short m = f2bf(r); h[1][j]=m;
            if (NSP==3){ float r2 = r - bf2f(m); h[2][j]=f2bf(r2); }
        }
    }
    int slot = (kl0>>3)&3, sw = slot ^ ((l>>1)&3);
    size_t off = (size_t)l*kd + (size_t)(kl0 & ~31) + sw*8;
    #pragma unroll
    for (int q=0;q<NSP;q++){
        uint4 u;
        u.x=h[q][0]|((unsigned)h[q][1]<<16); u.y=h[q][2]|((unsigned)h[q][3]<<16);
        u.z=h[q][4]|((unsigned)h[q][5]<<16); u.w=h[q][6]|((unsigned)h[q][7]<<16);
        *(uint4*)(base + q*PS + off) = u;
    }
}

// --- merged row-stat kernel: side0 (rs) -> P[l]; side1 (lr) -> csum+ssq ---
template<int NSP>
__global__ void k_stats2(const unsigned short* __restrict__ rs,
                         const unsigned short* __restrict__ lr, size_t PS,
                         float* __restrict__ Pdst, float* __restrict__ csum,
                         float* __restrict__ ssqd, int kd, int first, int b){
    int tid = threadIdx.x, lane = tid & 63;
    int idx = (blockIdx.x*256 + tid) >> 6;   // 0..8191
    int side = idx >> 12, row = idx & 4095;
    const unsigned short* pl = side ? lr : rs;
    int ns = kd >> 3;
    float sum = 0.f, ssq = 0.f;
    for (int s = lane; s < ns; s += 64){
        const unsigned short* p0 = pl + (size_t)row*kd + s*8;
        short8 v0 = *(const short8*)p0;
        short8 v1{}, v2{};
        if (NSP>=2) v1 = *(const short8*)(p0 + PS);
        if (NSP==3) v2 = *(const short8*)(p0 + 2*PS);
        #pragma unroll
        for (int j=0;j<8;j++){
            float x = bf2f((unsigned short)v0[j]);
            if (NSP>=2) x += bf2f((unsigned short)v1[j]);
            if (NSP==3) x += bf2f((unsigned short)v2[j]);
            sum += x; ssq += x*x;
        }
    }
    #pragma unroll
    for (int off=32; off; off>>=1){ sum += __shfl_xor(sum,off); ssq += __shfl_xor(ssq,off); }
    if (lane==0){
        int o = b*4096 + row;
        if (!side){ if (first) Pdst[o] = sum; else Pdst[o] += sum; }
        else {
            if (first){ csum[o] = sum; ssqd[o] = ssq; }
            else      { csum[o] += sum; ssqd[o] += ssq; }
        }
    }
}

template<int LEV>
__global__ void k_levfin(float* __restrict__ ws, int b){
    __shared__ float r0[4], r1[4];
    int tid = threadIdx.x, lane = tid & 63, w = tid >> 6;
    int m = blockIdx.x*256 + tid;
    float ssq = ws[ninv_off(LEV) + b*4096 + m];
    float ninv = 1.0f / fmaxf(sqrtf(ssq), 1e-12f);
    ws[ninv_off(LEV) + b*4096 + m] = ninv;
    float y0 = ws[csum_off(LEV) + b*4096 + m] * ninv;
    float y1 = ssq * ninv * ninv;
    #pragma unroll
    for (int off=32; off; off>>=1){ y0 += __shfl_xor(y0,off); y1 += __shfl_xor(y1,off); }
    if (lane==0){ r0[w]=y0; r1[w]=y1; }
    __syncthreads();
    if (tid==0){
        int s = blockIdx.x & 15;
        atomicAdd(&ws[LEV*64 + 2*16 + s], r0[0]+r0[1]+r0[2]+r0[3]);
        atomicAdd(&ws[LEV*64 + 3*16 + s], r1[0]+r1[1]+r1[2]+r1[3]);
    }
}

template<int LEV>
__global__ void k_scalar_late(float* __restrict__ ws){
    if (threadIdx.x || blockIdx.x) return;
    float s2=0.f, s3=0.f;
    for (int s=0;s<16;s++){ s2 += ws[LEV*64+32+s]; s3 += ws[LEV*64+48+s]; }
    float BDL = 2.0f * (float)lev_D(LEV) * 4096.0f;
    float m = ws[200+LEV];
    float gy2 = s3 - 2.f*m*s2 + BDL*m*m;
    if (LEV==0) ws[208] = gy2;
    float gx2 = ws[212+LEV];
    float gyu = (LEV==1) ? ws[208] : gy2;
    ws[204+LEV] = 1.0f/(sqrtf(gx2)*sqrtf(gyu));
}

// ===========================================================================
// 256^2 counted-vmcnt phase GEMM, NSP planes/side (products pa+pb<NSP; NSP=1:
// single product). 512 thr. LDS = 2buf * 2*NSP * 16KB.
// MODE 0: fused score/max/argmax. MODE 1: G = acc. MODE 2: G += acc.
// ===========================================================================
template<int LEV, int MODE, int NSP>
__launch_bounds__(512, 2)
__global__ void k_g8(const unsigned short* __restrict__ planes,
                     float* __restrict__ ws, float* __restrict__ G,
                     int b, int kd){
    const size_t PS = (size_t)4096 * kd;
    __shared__ unsigned short lds[2*2*NSP*256*32];
    const int tid = threadIdx.x;
    const int w = tid >> 6, lane = tid & 63;
    const int mblk = blockIdx.x, lblk = blockIdx.y;
    const int wm = w >> 2, wn = w & 3;
    const int colrow = lane & 15, rgrp = lane >> 4;
    const int swz = (rgrp ^ ((lane >> 1) & 3)) * 8;
    const int abase = wm*4096 + colrow*32 + swz;
    const int bbase = NSP*8192 + wn*2048 + colrow*32 + swz;
    const int NT = kd >> 5;
    const int BUFS = 2*NSP*8192;

    f32x4 acc[8][4];
    #pragma unroll
    for (int i=0;i<8;i++)
        #pragma unroll
        for (int j=0;j<4;j++) acc[i][j] = (f32x4){0.f,0.f,0.f,0.f};

    short8 aF[NSP][4], bF[NSP][4];

#define STAGE(bufv, k0v, qi) do { \
    _Pragma("unroll") \
    for (int e=0;e<NSP;e++){ \
        int flat = w*(4*NSP) + (qi)*NSP + e; \
        int p = flat >> 4; \
        int rb = (flat & 15) << 4; \
        int rowbase = (p < NSP ? lblk : mblk) << 8; \
        const unsigned short* g = planes + (size_t)p*PS \
            + (size_t)(rowbase + rb + (lane>>2))*kd + (size_t)(k0v) + (lane&3)*8; \
        unsigned short* lp = (unsigned short*)&lds[(bufv)*BUFS + p*8192 + rb*32]; \
        GLOAD16(g, lp); \
    } \
} while(0)

#define RDA(bufv, half) do { \
    _Pragma("unroll") \
    for (int pl=0; pl<NSP; pl++) \
        _Pragma("unroll") \
        for (int i=0;i<4;i++) \
            aF[pl][i] = *(const short8*)&lds[(bufv)*BUFS + pl*8192 + abase + ((half)*4+i)*512]; \
} while(0)

#define RDB(bufv, half) do { \
    _Pragma("unroll") \
    for (int pl=0; pl<NSP; pl++) \
        _Pragma("unroll") \
        for (int j=0;j<2;j++) \
            bF[pl][(half)*2+j] = *(const short8*)&lds[(bufv)*BUFS + pl*8192 + bbase + ((half)*2+j)*512]; \
} while(0)

#define MM(ihalf, jhalf) do { \
    __builtin_amdgcn_s_setprio(1); \
    _Pragma("unroll") \
    for (int i=0;i<4;i++) \
        _Pragma("unroll") \
        for (int j=0;j<2;j++){ \
            const int ai = (ihalf)*4+i, bj = (jhalf)*2+j; \
            acc[ai][bj] = __builtin_amdgcn_mfma_f32_16x16x32_bf16(aF[0][i], bF[0][bj], acc[ai][bj],0,0,0); \
            if (NSP>=2){ \
                acc[ai][bj] = __builtin_amdgcn_mfma_f32_16x16x32_bf16(aF[0][i], bF[1][bj], acc[ai][bj],0,0,0); \
                acc[ai][bj] = __builtin_amdgcn_mfma_f32_16x16x32_bf16(aF[1][i], bF[0][bj], acc[ai][bj],0,0,0); \
            } \
        } \
    __builtin_amdgcn_s_setprio(0); \
} while(0)

    // prologue: stage tile 0 into buf0 (4*NSP loads/thread in flight)
    STAGE(0, 0, 0); STAGE(0, 0, 1); STAGE(0, 0, 2); STAGE(0, 0, 3);

    int cur = 0;
    for (int kt = 0; kt < NT-1; kt++){
        const int k0n = (kt+1) << 5;
        STAGE(cur^1, k0n, 0);
        if constexpr (NSP==1) asm volatile("s_waitcnt vmcnt(1)" ::: "memory");
        else                  asm volatile("s_waitcnt vmcnt(2)" ::: "memory");
        barx();                       // current tile resident for all waves
        RDB(cur, 0); RDA(cur, 0);
        MM(0, 0);
        STAGE(cur^1, k0n, 1);
        RDB(cur, 1);
        MM(0, 1);
        STAGE(cur^1, k0n, 2);
        RDA(cur, 1);
        MM(1, 1);
        STAGE(cur^1, k0n, 3);
        MM(1, 0);
        barx();                       // reads of buf[cur] done before reuse
        cur ^= 1;
    }
    asm volatile("s_waitcnt vmcnt(0)" ::: "memory");
    barx();
    RDB(cur, 0); RDA(cur, 0); MM(0, 0);
    RDB(cur, 1); MM(0, 1);
    RDA(cur, 1); MM(1, 1);
    MM(1, 0);

#undef STAGE
#undef RDA
#undef RDB
#undef MM

    const int lbase = (lblk<<8) + wm*128;
    const int mbase = (mblk<<8) + wn*64;

    if (MODE != 0){
        #pragma unroll
        for (int i=0;i<8;i++){
            #pragma unroll
            for (int rg=0; rg<4; rg++){
                float* gp = G + (size_t)(lbase + i*16 + rgrp*4 + rg)*4096 + mbase + colrow;
                #pragma unroll
                for (int j=0;j<4;j++){
                    float v = acc[i][j][rg];
                    if (MODE == 2) v += gp[j*16];
                    gp[j*16] = v;
                }
            }
        }
        return;
    }

    // MODE 0: score + per-m max/argmax over this block's 256 l
    constexpr int D = lev_D(LEV);
    const float mval = ws[200+LEV];
    const float Dm2 = (float)D * mval * mval;
    const float* Pv  = ws + p_off(LEV)    + b*4096;
    const float* NIv = ws + ninv_off(LEV) + b*4096;
    const float* CSv = ws + csum_off(LEV) + b*4096;
    barx();                           // safe to reuse LDS
    float* smax = (float*)lds;                 // [2][256]
    int*   sarg = (int*)((char*)lds + 2048);   // [2][256]
    #pragma unroll
    for (int j=0;j<4;j++){
        int m = mbase + j*16 + colrow;
        float nv = NIv[m];
        float cmv = -mval*nv*CSv[m] + Dm2;
        float v = -FLT_MAX; int vi = 0x7fffffff;
        #pragma unroll
        for (int i=0;i<8;i++){
            #pragma unroll
            for (int rg=0; rg<4; rg++){
                int l = lbase + i*16 + rgrp*4 + rg;
                float sc = nv*acc[i][j][rg] - mval*Pv[l] + cmv;
                if (sc > v){ v = sc; vi = l; }
            }
        }
        #pragma unroll
        for (int off=16; off<64; off<<=1){
            float ov = __shfl_xor(v, off);
            int   oi = __shfl_xor(vi, off);
            if (ov > v || (ov == v && oi < vi)){ v = ov; vi = oi; }
        }
        if (rgrp == 0){
            smax[wm*256 + wn*64 + j*16 + colrow] = v;
            sarg[wm*256 + wn*64 + j*16 + colrow] = vi;
        }
    }
    barx();
    if (tid < 256){
        float v0 = smax[tid];     int a0 = sarg[tid];
        float v1 = smax[256+tid]; int a1 = sarg[256+tid];
        if (v1 > v0 || (v1 == v0 && a1 < a0)){ v0 = v1; a0 = a1; }
        int o = (b*32 + lblk)*4096 + (mblk<<8) + tid;
        ws[pmax_off(LEV) + o] = v0;
        ((int*)ws)[parg_off(LEV) + o] = a0;
    }
}

// --- OLD 128^2 MFMA GEMM (kept for lev0 bf16x3 exact chain) ---
template<int LEV, int MODE, int NSP>
__launch_bounds__(256, 2)
__global__ void k_gmfma(const unsigned short* __restrict__ planes,
                        float* __restrict__ ws, float* __restrict__ G,
                        int b, int kd){
    const size_t PS = (size_t)4096 * kd;
    __shared__ unsigned short lds[2*NSP*128*32];
    const int tid = threadIdx.x;
    const int w = tid >> 6, lane = tid & 63;
    const int mblk = blockIdx.x, lblk = blockIdx.y;
    const int lw = w >> 1, mw = w & 1;

    f32x4 acc[4][4];
    #pragma unroll
    for (int i=0;i<4;i++)
        #pragma unroll
        for (int j=0;j<4;j++) acc[i][j] = (f32x4){0.f,0.f,0.f,0.f};

    const int srow = lane >> 2, ssl = lane & 3;
    const int colrow = lane & 15, kk = lane >> 4;
    const int swz = (kk ^ ((lane >> 1) & 3)) * 8;
    const int aRow0 = lw*64 + colrow;
    const int bRow0 = mw*64 + colrow;

    for (int k0 = 0; k0 < kd; k0 += 32){
        #pragma unroll
        for (int p = 0; p < 2*NSP; p++){
            const int rb = (p < NSP ? lblk : mblk)*128 + w*32 + srow;
            const unsigned short* gp0 = planes + (size_t)p*PS
                                        + (size_t)rb*kd + (size_t)k0 + ssl*8;
            unsigned short* lp0 = &lds[p*4096 + w*1024];
            GLOAD16(gp0, lp0);
            GLOAD16(gp0 + (size_t)16*kd, lp0 + 512);
        }
        __syncthreads();

        short8 aF[NSP][4];
        #pragma unroll
        for (int pa=0; pa<NSP; pa++)
            #pragma unroll
            for (int i=0;i<4;i++)
                aF[pa][i] = *(const short8*)&lds[pa*4096 + (aRow0 + i*16)*32 + swz];
        #pragma unroll
        for (int pb=0; pb<NSP; pb++){
            short8 bF[4];
            #pragma unroll
            for (int j=0;j<4;j++)
                bF[j] = *(const short8*)&lds[(NSP+pb)*4096 + (bRow0 + j*16)*32 + swz];
            const int npa = NSP - pb;
            for (int pa=0; pa<npa; pa++)
                #pragma unroll
                for (int i=0;i<4;i++)
                    #pragma unroll
                    for (int j=0;j<4;j++)
                        acc[i][j] = __builtin_amdgcn_mfma_f32_16x16x32_bf16(
                                        aF[pa][i], bF[j], acc[i][j], 0, 0, 0);
        }
        __syncthreads();
    }

    const int lbase = lblk*128 + lw*64;
    const int mbase = mblk*128 + mw*64;
    const int rgrp = lane >> 4;

    if (MODE != 0){
        #pragma unroll
        for (int i=0;i<4;i++){
            #pragma unroll
            for (int rg=0; rg<4; rg++){
                float* gp = G + (size_t)(lbase + i*16 + rgrp*4 + rg)*4096
                              + mbase + colrow;
                #pragma unroll
                for (int j=0;j<4;j++){
                    float v = acc[i][j][rg];
                    if (MODE == 2) v += gp[j*16];
                    gp[j*16] = v;
                }
            }
        }
        return;
    }

    constexpr int D = lev_D(LEV);
    const float mval = ws[200+LEV];
    const float Dm2 = (float)D * mval * mval;
    const float* Pv  = ws + p_off(LEV)    + b*4096;
    const float* NIv = ws + ninv_off(LEV) + b*4096;
    const float* CSv = ws + csum_off(LEV) + b*4096;
    float* smax = (float*)lds;
    int*   sarg = (int*)&lds[512];
    #pragma unroll
    for (int j=0;j<4;j++){
        int m = mbase + j*16 + colrow;
        float nv = NIv[m];
        float cmv = -mval*nv*CSv[m] + Dm2;
        float v = -FLT_MAX; int vi = 0x7fffffff;
        #pragma unroll
        for (int i=0;i<4;i++){
            #pragma unroll
            for (int rg=0; rg<4; rg++){
                int l = lbase + i*16 + rgrp*4 + rg;
                float sc = nv*acc[i][j][rg] - mval*Pv[l] + cmv;
                if (sc > v){ v = sc; vi = l; }
            }
        }
        #pragma unroll
        for (int off=16; off<64; off<<=1){
            float ov = __shfl_xor(v, off);
            int   oi = __shfl_xor(vi, off);
            if (ov > v || (ov == v && oi < vi)){ v = ov; vi = oi; }
        }
        if (rgrp == 0){
            smax[w*64 + j*16 + colrow] = v;
            sarg[w*64 + j*16 + colrow] = vi;
        }
    }
    __syncthreads();
    if (tid < 128){
        int mg = tid >> 6, idx = tid & 63;
        float v0 = smax[mg*64 + idx];     int a0 = sarg[mg*64 + idx];
        float v1 = smax[(mg+2)*64 + idx]; int a1 = sarg[(mg+2)*64 + idx];
        if (v1 > v0 || (v1 == v0 && a1 < a0)){ v0 = v1; a0 = a1; }
        int m = mblk*128 + mg*64 + idx;
        int o = (b*32 + lblk)*4096 + m;
        ws[pmax_off(LEV) + o] = v0;
        ((int*)ws)[parg_off(LEV) + o] = a0;
    }
}

// --- score + max/argmax from accumulated G; grid (64 mblk, 8 lsplit) ---
template<int LEV>
__global__ void k_score(const float* __restrict__ G, float* __restrict__ ws, int b){
    constexpr int D = lev_D(LEV);
    __shared__ float smax[4][64];
    __shared__ int   sarg[4][64];
    int tid = threadIdx.x, mloc = tid & 63, r = tid >> 6;
    int m = blockIdx.x*64 + mloc;
    int l0 = blockIdx.y*512;
    float mval = ws[200+LEV];
    float nv = ws[ninv_off(LEV) + b*4096 + m];
    float cmv = -mval*nv*ws[csum_off(LEV) + b*4096 + m] + (float)D*mval*mval;
    const float* Pv = ws + p_off(LEV) + b*4096;
    float best = -FLT_MAX; int bi = 0x7fffffff;
    for (int lt=0; lt<128; lt++){
        int l = l0 + lt*4 + r;
        float sc = nv*G[(size_t)l*4096 + m] - mval*Pv[l] + cmv;
        if (sc > best){ best = sc; bi = l; }
    }
    smax[r][mloc] = best; sarg[r][mloc] = bi;
    __syncthreads();
    if (tid < 64){
        float v = smax[0][tid]; int vi = sarg[0][tid];
        #pragma unroll
        for (int rr=1; rr<4; rr++){
            float ov = smax[rr][tid]; int oi = sarg[rr][tid];
            if (ov > v || (ov == v && oi < vi)){ v = ov; vi = oi; }
        }
        int o = (b*32 + blockIdx.y)*4096 + blockIdx.x*64 + tid;
        ws[pmax_off(LEV) + o] = v;
        ((int*)ws)[parg_off(LEV) + o] = vi;
    }
}

// --- reduce l-chunks -> S3,S2,S1,arg outputs (applies late scale) ---
__global__ void k_smax(float* __restrict__ ws, float* __restrict__ out,
                       int nch0, int nch1, int nch2){
    int gid = blockIdx.x*256 + threadIdx.x;
    if (gid >= 8192) return;
    int b = gid >> 12, m = gid & 4095;
    int nchs[3] = {nch0, nch1, nch2};
    for (int lev=0; lev<3; lev++){
        float mv = -FLT_MAX; int ma = 0x7fffffff;
        for (int ch=0; ch<nchs[lev]; ch++){
            int o = ((b*32+ch)<<12) + m;
            float v = ws[pmax_off(lev) + o];
            int   a = ((const int*)ws)[parg_off(lev) + o];
            if (v > mv || (v == mv && a < ma)){ mv=v; ma=a; }
        }
        out[lev*8192 + gid] = mv * ws[204+lev];
        if (lev==0){
            out[3*8192 + gid] = (float)ma;
            ((int*)ws)[arg_off() + gid] = ma;
        }
    }
}

// --- T = fold(gather(unfold(ref), arg)) / 9 ---
template<int LEV>
__global__ void k_transfer(const float* __restrict__ ref, const float* __restrict__ wsf,
                           float* __restrict__ outT){
    constexpr int C=LT<LEV>::C, H=LT<LEV>::H, K=LT<LEV>::K, S=LT<LEV>::S, PD=LT<LEV>::P;
    const int* arg = (const int*)wsf + arg_off();
    size_t gid = (size_t)blockIdx.x*256 + threadIdx.x;
    size_t total = (size_t)2*C*H*H;
    if (gid >= total) return;
    int x = (int)(gid % H);
    int y = (int)((gid / H) % H);
    int c = (int)((gid / ((size_t)H*H)) % C);
    int b = (int)(gid / ((size_t)C*H*H));
    const float* rimg = ref + (size_t)(b*C+c)*H*H;
    int byo = (y+PD)/S, ryo = (y+PD)%S;
    int bxo = (x+PD)/S, rxo = (x+PD)%S;
    float acc = 0.f;
    #pragma unroll
    for (int jy=0; jy<3; jy++){
        int ho = byo - jy;
        if (ho < 0 || ho >= 64) continue;
        int ki = ryo + jy*S;
        #pragma unroll
        for (int jx=0; jx<3; jx++){
            int wo = bxo - jx;
            if (wo < 0 || wo >= 64) continue;
            int kj = rxo + jx*S;
            int l = arg[b*4096 + ho*64 + wo];
            int ly = l>>6, lx = l&63;
            int srow = ly*S + ki - PD, scol = lx*S + kj - PD;
            if (srow>=0 && srow<H && scol>=0 && scol<H)
                acc += rimg[srow*H + scol];
        }
    }
    outT[gid] = acc * (1.0f/9.0f);
}

template<int LEV>
static void run_level(const float* refsr, const float* lrsr, float* ws,
                      size_t ws_size, hipStream_t stream, int* nch){
    constexpr int D = lev_D(LEV);
    constexpr int NSP = (LEV==0) ? 3 : 1;   // lev0 exact argmax; others value-only
    k_rownorm<LEV><<<D/2, 256, 0, stream>>>(refsr, ws);
    k_scalar_early<LEV><<<1, 64, 0, stream>>>(ws);

    auto planeBytes = [](int c){ return (size_t)4*NSP*4096*c; };
    bool fused = (ws_size >= G_BASE_BYTES + planeBytes(D));
    int kd = D;
    if (!fused){
        kd = 0;
        for (int div = 2; div <= 16; div <<= 1){
            if (ws_size >= CHUNK_PLANE_BYTES + planeBytes(D/div)){ kd = D/div; break; }
        }
        if (!kd) kd = D/16;  // ws is known-large; defensive only
    }
    unsigned short* pl = (unsigned short*)((char*)ws + (fused ? G_BASE_BYTES : CHUNK_PLANE_BYTES));
    float* G = ws + (G_BASE_BYTES >> 2);
    const size_t PS = (size_t)4096 * kd;
    const int nkc = D / kd;
    nch[LEV] = fused ? ((LEV==0) ? 32 : 16) : 8;

    for (int b=0; b<2; b++){
        for (int kc=0; kc<nkc; kc++){
            k_split<LEV,true ,NSP><<<2*kd, 256, 0, stream>>>(refsr, ws, pl, b, kc*kd, kd);
            k_split<LEV,false,NSP><<<2*kd, 256, 0, stream>>>(lrsr,  ws, pl + NSP*PS, b, kc*kd, kd);
            k_stats2<NSP><<<2048, 256, 0, stream>>>(pl, pl + NSP*PS, PS,
                ws + p_off(LEV), ws + csum_off(LEV), ws + ninv_off(LEV), kd, kc==0, b);
            if (!fused){
                if constexpr (LEV==0){
                    if (kc==0) k_gmfma<0,1,3><<<dim3(32,32), 256, 0, stream>>>(pl, ws, G, b, kd);
                    else       k_gmfma<0,2,3><<<dim3(32,32), 256, 0, stream>>>(pl, ws, G, b, kd);
                } else {
                    if (kc==0) k_g8<LEV,1,NSP><<<dim3(16,16), 512, 0, stream>>>(pl, ws, G, b, kd);
                    else       k_g8<LEV,2,NSP><<<dim3(16,16), 512, 0, stream>>>(pl, ws, G, b, kd);
                }
            }
        }
        k_levfin<LEV><<<16, 256, 0, stream>>>(ws, b);
        if (fused){
            if constexpr (LEV==0) k_gmfma<0,0,3><<<dim3(32,32), 256, 0, stream>>>(pl, ws, G, b, kd);
            else                  k_g8<LEV,0,NSP><<<dim3(16,16), 512, 0, stream>>>(pl, ws, G, b, kd);
        } else {
            k_score<LEV><<<dim3(64,8), 256, 0, stream>>>(G, ws, b);
        }
    }
    k_scalar_late<LEV><<<1, 64, 0, stream>>>(ws);
}

extern "C" void kernel_launch(void* const* d_in, const int* in_sizes, int n_in,
                              void* d_out, int out_size, void* d_ws, size_t ws_size,
                              hipStream_t stream){
    const float* lrsr[3]  = { (const float*)d_in[2], (const float*)d_in[1], (const float*)d_in[0] };
    const float* refsr[3] = { (const float*)d_in[5], (const float*)d_in[4], (const float*)d_in[3] };
    const float* refp[3]  = { (const float*)d_in[8], (const float*)d_in[7], (const float*)d_in[6] };
    float* ws  = (float*)d_ws;
    float* out = (float*)d_out;

    hipMemsetAsync(d_ws, 0, 4096, stream);  // zero scalar slots + scalars

    int nch[3];
    run_level<0>(refsr[0], lrsr[0], ws, ws_size, stream, nch);
    run_level<1>(refsr[1], lrsr[1], ws, ws_size, stream, nch);
    run_level<2>(refsr[2], lrsr[2], ws, ws_size, stream, nch);

    k_smax<<<32, 256, 0, stream>>>(ws, out, nch[0], nch[1], nch[2]);

    k_transfer<0><<< (2*256*64*64)/256,   256, 0, stream>>>(refp[0], ws, out + 32768);
    k_transfer<1><<< (2*128*128*128)/256, 256, 0, stream>>>(refp[1], ws, out + 2129920);
    k_transfer<2><<< (2*64*256*256)/256,  256, 0, stream>>>(refp[2], ws, out + 6324224);
}

// Round 9
// 2907.292 us; speedup vs baseline: 8.4896x; 1.0660x over previous
//
#include <hip/hip_runtime.h>
#include <cfloat>

// ---------------------------------------------------------------------------
// SearchTransfer (TTSR): 3-level patch correlation + argmax + gather/fold.
// Levels: 0 = lv3 (C=256,H=64,k=3,s=1,p=1,D=2304)
//         1 = lv2 (C=128,H=128,k=6,s=2,p=2,D=4608)
//         2 = lv1 (C=64,H=256,k=12,s=4,p=4,D=9216)
//
// score(l,m) = ninv[m]*G[l,m] - mval*P[l] - mval*ninv[m]*csum[m] + D*mval^2
// lev0: bf16x3 split, 6 products (exact argmax chain -> arg, T1-T3),
//       NEW k_g0: 256x128 tile counted-vmcnt schedule, both batches 1 dispatch.
// lev1/2: single bf16 (NSP=1), 1 product, 256^2 counted-vmcnt k_g8.
// ---------------------------------------------------------------------------

typedef short short8 __attribute__((ext_vector_type(8)));
typedef float f32x4  __attribute__((ext_vector_type(4)));

template<int LEV> struct LT;
template<> struct LT<0> { static constexpr int C=256, H=64,  K=3,  S=1, P=1; };
template<> struct LT<1> { static constexpr int C=128, H=128, K=6,  S=2, P=2; };
template<> struct LT<2> { static constexpr int C=64,  H=256, K=12, S=4, P=4; };

__host__ __device__ constexpr int lev_D(int lev){ return lev==0?2304:(lev==1?4608:9216); }
// ws float-index offsets
// [0,192): scalar slots: lev*64 + q*16 + slot (q:0=sum_rs,1=ssq_rs,2=sum_lr,3=ssq_lr)
// 200+lev: mval  204+lev: scale  208: gy2_lev0  212+lev: gx2
__host__ __device__ constexpr int rho_off(int lev){ return 256 + (lev>0?2*2304:0) + (lev>1?2*4608:0); }
__host__ __device__ constexpr int p_off(int lev)   { return 32512  + lev*8192;   }
__host__ __device__ constexpr int ninv_off(int lev){ return 57088  + lev*8192;   }
__host__ __device__ constexpr int csum_off(int lev){ return 81664  + lev*8192;   }
__host__ __device__ constexpr int pmax_off(int lev){ return 106240 + lev*262144; }
__host__ __device__ constexpr int parg_off(int lev){ return 892672 + lev*262144; }
__host__ __device__ constexpr int arg_off(){ return 1679104; }
static constexpr size_t G_BASE_BYTES      = 8ull  << 20;
static constexpr size_t CHUNK_PLANE_BYTES = 72ull << 20;

__device__ inline unsigned short f2bf(float f){
    unsigned int u = __float_as_uint(f);
    return (unsigned short)((u + 0x7fffu + ((u >> 16) & 1u)) >> 16);
}
__device__ inline float bf2f(unsigned short h){ return __uint_as_float(((unsigned)h) << 16); }

#define GLOAD16(g, l) __builtin_amdgcn_global_load_lds( \
    (const __attribute__((address_space(1))) unsigned int*)(g), \
    (__attribute__((address_space(3))) unsigned int*)(l), 16, 0, 0)

__device__ __forceinline__ void barx(){
    __builtin_amdgcn_sched_barrier(0);
    __builtin_amdgcn_s_barrier();
    __builtin_amdgcn_sched_barrier(0);
}

// --- per-(b,d) row norm of refsr unfold + rs scalar slots ---
template<int LEV>
__global__ void k_rownorm(const float* __restrict__ refsr, float* __restrict__ ws){
    constexpr int C=LT<LEV>::C, H=LT<LEV>::H, K=LT<LEV>::K, S=LT<LEV>::S, PD=LT<LEV>::P;
    constexpr int D = C*K*K, KK=K*K;
    __shared__ float sh0[4], sh1[4];
    int tid = threadIdx.x, lane = tid & 63, w = tid >> 6;
    int wid = (blockIdx.x*blockDim.x + tid) >> 6;
    int b = wid / D, d = wid % D;
    int c = d/KK, rem = d%KK, ki = rem/K, kj = rem%K;
    const float* img = refsr + (size_t)(b*C + c)*H*H;
    float sum=0.f, ssq=0.f;
    for (int idx=lane; idx<4096; idx+=64){
        int ho=idx>>6, wo=idx&63;
        int row = ho*S+ki-PD, col = wo*S+kj-PD;
        if (row>=0 && row<H && col>=0 && col<H){
            float v = img[row*H+col]; sum += v; ssq += v*v;
        }
    }
    #pragma unroll
    for (int off=32; off; off>>=1){ sum += __shfl_xor(sum,off); ssq += __shfl_xor(ssq,off); }
    if (lane==0){
        float rinv = 1.0f / fmaxf(sqrtf(ssq), 1e-12f);
        ws[rho_off(LEV) + b*D + d] = rinv;
        sh0[w] = sum*rinv;
        sh1[w] = ssq*rinv*rinv;
    }
    __syncthreads();
    if (tid==0){
        int s = blockIdx.x & 15;
        atomicAdd(&ws[LEV*64 + 0*16 + s], sh0[0]+sh0[1]+sh0[2]+sh0[3]);
        atomicAdd(&ws[LEV*64 + 1*16 + s], sh1[0]+sh1[1]+sh1[2]+sh1[3]);
    }
}

template<int LEV>
__global__ void k_scalar_early(float* __restrict__ ws){
    if (threadIdx.x || blockIdx.x) return;
    float s0=0.f, s1=0.f;
    for (int s=0;s<16;s++){ s0 += ws[LEV*64+s]; s1 += ws[LEV*64+16+s]; }
    float BDL = 2.0f * (float)lev_D(LEV) * 4096.0f;
    float m = s0 / BDL;
    ws[200+LEV] = m;
    ws[212+LEV] = s1 - 2.f*m*s0 + BDL*m*m;
}

// --- bf16 split (NSP planes), 16B slots swizzled: slot ^= (row>>1)&3 ---
template<int LEV, bool ISA, int NSP>
__global__ void k_split(const float* __restrict__ img4, const float* __restrict__ ws,
                        unsigned short* __restrict__ base, int b, int kb0, int kd){
    constexpr int C=LT<LEV>::C, H=LT<LEV>::H, K=LT<LEV>::K, S=LT<LEV>::S, PD=LT<LEV>::P;
    constexpr int KK=K*K;
    const size_t PS = (size_t)4096 * kd;
    int gid = blockIdx.x*256 + threadIdx.x;
    int kslots = kd >> 3;
    if (gid >= 4096*kslots) return;
    int kb = gid % kslots, l = gid / kslots;
    int kl0 = kb*8;
    int ly = l>>6, lx = l&63;
    const float* img = img4 + (size_t)b*C*H*H;
    const float* rinv = ws + rho_off(LEV) + b*lev_D(LEV);
    unsigned short h[NSP][8];
    #pragma unroll
    for (int j=0;j<8;j++){
        int k = kb0 + kl0 + j; int c=k/KK, rem=k%KK, ki=rem/K, kj=rem%K;
        int row=ly*S+ki-PD, col=lx*S+kj-PD;
        float x = (row>=0 && row<H && col>=0 && col<H)
                  ? img[(size_t)(c*H+row)*H+col] : 0.f;
        if (ISA) x *= rinv[k];
        unsigned short a = f2bf(x); h[0][j]=a;
        if (NSP>=2){
            float r = x - bf2f(a);
            unsigned short m = f2bf(r); h[1][j]=m;
            if (NSP==3){ float r2 = r - bf2f(m); h[2][j]=f2bf(r2); }
        }
    }
    int slot = (kl0>>3)&3, sw = slot ^ ((l>>1)&3);
    size_t off = (size_t)l*kd + (size_t)(kl0 & ~31) + sw*8;
    #pragma unroll
    for (int q=0;q<NSP;q++){
        uint4 u;
        u.x=h[q][0]|((unsigned)h[q][1]<<16); u.y=h[q][2]|((unsigned)h[q][3]<<16);
        u.z=h[q][4]|((unsigned)h[q][5]<<16); u.w=h[q][6]|((unsigned)h[q][7]<<16);
        *(uint4*)(base + q*PS + off) = u;
    }
}

// --- merged row-stat kernel: side0 (rs) -> P[l]; side1 (lr) -> csum+ssq ---
template<int NSP>
__global__ void k_stats2(const unsigned short* __restrict__ rs,
                         const unsigned short* __restrict__ lr, size_t PS,
                         float* __restrict__ Pdst, float* __restrict__ csum,
                         float* __restrict__ ssqd, int kd, int first, int b){
    int tid = threadIdx.x, lane = tid & 63;
    int idx = (blockIdx.x*256 + tid) >> 6;   // 0..8191
    int side = idx >> 12, row = idx & 4095;
    const unsigned short* pl = side ? lr : rs;
    int ns = kd >> 3;
    float sum = 0.f, ssq = 0.f;
    for (int s = lane; s < ns; s += 64){
        const unsigned short* p0 = pl + (size_t)row*kd + s*8;
        short8 v0 = *(const short8*)p0;
        short8 v1{}, v2{};
        if (NSP>=2) v1 = *(const short8*)(p0 + PS);
        if (NSP==3) v2 = *(const short8*)(p0 + 2*PS);
        #pragma unroll
        for (int j=0;j<8;j++){
            float x = bf2f((unsigned short)v0[j]);
            if (NSP>=2) x += bf2f((unsigned short)v1[j]);
            if (NSP==3) x += bf2f((unsigned short)v2[j]);
            sum += x; ssq += x*x;
        }
    }
    #pragma unroll
    for (int off=32; off; off>>=1){ sum += __shfl_xor(sum,off); ssq += __shfl_xor(ssq,off); }
    if (lane==0){
        int o = b*4096 + row;
        if (!side){ if (first) Pdst[o] = sum; else Pdst[o] += sum; }
        else {
            if (first){ csum[o] = sum; ssqd[o] = ssq; }
            else      { csum[o] += sum; ssqd[o] += ssq; }
        }
    }
}

template<int LEV>
__global__ void k_levfin(float* __restrict__ ws, int b){
    __shared__ float r0[4], r1[4];
    int tid = threadIdx.x, lane = tid & 63, w = tid >> 6;
    int m = blockIdx.x*256 + tid;
    float ssq = ws[ninv_off(LEV) + b*4096 + m];
    float ninv = 1.0f / fmaxf(sqrtf(ssq), 1e-12f);
    ws[ninv_off(LEV) + b*4096 + m] = ninv;
    float y0 = ws[csum_off(LEV) + b*4096 + m] * ninv;
    float y1 = ssq * ninv * ninv;
    #pragma unroll
    for (int off=32; off; off>>=1){ y0 += __shfl_xor(y0,off); y1 += __shfl_xor(y1,off); }
    if (lane==0){ r0[w]=y0; r1[w]=y1; }
    __syncthreads();
    if (tid==0){
        int s = blockIdx.x & 15;
        atomicAdd(&ws[LEV*64 + 2*16 + s], r0[0]+r0[1]+r0[2]+r0[3]);
        atomicAdd(&ws[LEV*64 + 3*16 + s], r1[0]+r1[1]+r1[2]+r1[3]);
    }
}

template<int LEV>
__global__ void k_scalar_late(float* __restrict__ ws){
    if (threadIdx.x || blockIdx.x) return;
    float s2=0.f, s3=0.f;
    for (int s=0;s<16;s++){ s2 += ws[LEV*64+32+s]; s3 += ws[LEV*64+48+s]; }
    float BDL = 2.0f * (float)lev_D(LEV) * 4096.0f;
    float m = ws[200+LEV];
    float gy2 = s3 - 2.f*m*s2 + BDL*m*m;
    if (LEV==0) ws[208] = gy2;
    float gx2 = ws[212+LEV];
    float gyu = (LEV==1) ? ws[208] : gy2;
    ws[204+LEV] = 1.0f/(sqrtf(gx2)*sqrtf(gyu));
}

// ===========================================================================
// NEW: lev0 256(l)x128(m) counted-vmcnt GEMM, NSP=3 both sides (6 products),
// fused score/max/argmax. 512 thr, 144KB LDS, both batches via blockIdx.z.
// ===========================================================================
__launch_bounds__(512, 1)
__global__ void k_g0(const unsigned short* __restrict__ planes0,
                     float* __restrict__ ws, int kd){
    const size_t PS = (size_t)4096 * kd;
    const int b = blockIdx.z;
    const unsigned short* planes = planes0 + (size_t)b*6*PS;
    __shared__ unsigned short lds[2*36864];   // 144 KB
    const int tid = threadIdx.x;
    const int w = tid >> 6, lane = tid & 63;
    const int mblk = blockIdx.x, lblk = blockIdx.y;
    const int wm = w >> 2, wn = w & 3;
    const int colrow = lane & 15, rgrp = lane >> 4;
    const int swz = (rgrp ^ ((lane >> 1) & 3)) * 8;
    // LDS: buf*36864 + [A: p*8192 + row*32] ; [B: 24576 + p*4096 + row*32]
    const int abase = wm*4096 + colrow*32 + swz;          // + p*8192 + i*512
    const int bbase = 24576 + wn*1024 + colrow*32 + swz;  // + p*4096 + j*512
    const int NT = kd >> 5;

    f32x4 acc[8][2];
    #pragma unroll
    for (int i=0;i<8;i++){ acc[i][0]=(f32x4){0,0,0,0}; acc[i][1]=(f32x4){0,0,0,0}; }

    short8 bF[3][2];

#define STAGE0(bufv, k0v, qv) do { \
    int f = w*9 + (qv); \
    int isA = f < 48; \
    int p  = isA ? (f>>4) : ((f-48)>>3); \
    int rb = isA ? ((f&15)<<4) : (((f-48)&7)<<4); \
    const unsigned short* g = planes + (size_t)(isA ? p : 3+p)*PS \
        + (size_t)((isA ? (lblk<<8) : (mblk<<7)) + rb + (lane>>2))*kd \
        + (size_t)(k0v) + (lane&3)*8; \
    unsigned short* lp = (unsigned short*)&lds[(bufv)*36864 \
        + (isA ? p*8192 : 24576 + p*4096) + rb*32]; \
    GLOAD16(g, lp); \
} while(0)

#define RDB0(bufv) do { \
    _Pragma("unroll") \
    for (int p=0;p<3;p++) \
        _Pragma("unroll") \
        for (int j=0;j<2;j++) \
            bF[p][j] = *(const short8*)&lds[(bufv)*36864 + bbase + p*4096 + j*512]; \
} while(0)

#define MMI(bufv, i) do { \
    short8 a0 = *(const short8*)&lds[(bufv)*36864 + 0*8192 + abase + (i)*512]; \
    short8 a1 = *(const short8*)&lds[(bufv)*36864 + 1*8192 + abase + (i)*512]; \
    short8 a2 = *(const short8*)&lds[(bufv)*36864 + 2*8192 + abase + (i)*512]; \
    __builtin_amdgcn_s_setprio(1); \
    _Pragma("unroll") \
    for (int j=0;j<2;j++){ \
        acc[i][j] = __builtin_amdgcn_mfma_f32_16x16x32_bf16(a0, bF[0][j], acc[i][j],0,0,0); \
        acc[i][j] = __builtin_amdgcn_mfma_f32_16x16x32_bf16(a0, bF[1][j], acc[i][j],0,0,0); \
        acc[i][j] = __builtin_amdgcn_mfma_f32_16x16x32_bf16(a1, bF[0][j], acc[i][j],0,0,0); \
        acc[i][j] = __builtin_amdgcn_mfma_f32_16x16x32_bf16(a0, bF[2][j], acc[i][j],0,0,0); \
        acc[i][j] = __builtin_amdgcn_mfma_f32_16x16x32_bf16(a1, bF[1][j], acc[i][j],0,0,0); \
        acc[i][j] = __builtin_amdgcn_mfma_f32_16x16x32_bf16(a2, bF[0][j], acc[i][j],0,0,0); \
    } \
    __builtin_amdgcn_s_setprio(0); \
} while(0)

    // prologue: stage tile 0 (9 loads per thread-group in flight)
    STAGE0(0,0,0); STAGE0(0,0,1); STAGE0(0,0,2); STAGE0(0,0,3); STAGE0(0,0,4);
    STAGE0(0,0,5); STAGE0(0,0,6); STAGE0(0,0,7); STAGE0(0,0,8);

    int cur = 0;
    for (int kt = 0; kt < NT-1; kt++){
        const int k0n = (kt+1) << 5;
        STAGE0(cur^1, k0n, 0); STAGE0(cur^1, k0n, 1); STAGE0(cur^1, k0n, 2);
        asm volatile("s_waitcnt vmcnt(3)" ::: "memory");
        barx();                       // current tile resident for all waves
        RDB0(cur);
        MMI(cur,0); MMI(cur,1);
        STAGE0(cur^1, k0n, 3); STAGE0(cur^1, k0n, 4); STAGE0(cur^1, k0n, 5);
        MMI(cur,2); MMI(cur,3); MMI(cur,4);
        STAGE0(cur^1, k0n, 6); STAGE0(cur^1, k0n, 7); STAGE0(cur^1, k0n, 8);
        MMI(cur,5); MMI(cur,6); MMI(cur,7);
        barx();                       // reads of buf[cur] done before reuse
        cur ^= 1;
    }
    asm volatile("s_waitcnt vmcnt(0)" ::: "memory");
    barx();
    RDB0(cur);
    MMI(cur,0); MMI(cur,1); MMI(cur,2); MMI(cur,3);
    MMI(cur,4); MMI(cur,5); MMI(cur,6); MMI(cur,7);

#undef STAGE0
#undef RDB0
#undef MMI

    // ---- fused score + per-m max/argmax over this block's 256 l ----
    const int lbase = (lblk<<8) + wm*128;
    const int mbase = (mblk<<7) + wn*32;
    const int D = kd;
    const float mval = ws[200];
    const float Dm2 = (float)D * mval * mval;
    const float* Pv  = ws + p_off(0)    + b*4096;
    const float* NIv = ws + ninv_off(0) + b*4096;
    const float* CSv = ws + csum_off(0) + b*4096;
    barx();                           // safe to reuse LDS
    float* smax = (float*)lds;                 // [2][128]
    int*   sarg = (int*)((char*)lds + 1024);   // [2][128]
    #pragma unroll
    for (int j=0;j<2;j++){
        int m = mbase + j*16 + colrow;
        float nv = NIv[m];
        float cmv = -mval*nv*CSv[m] + Dm2;
        float v = -FLT_MAX; int vi = 0x7fffffff;
        #pragma unroll
        for (int i=0;i<8;i++){
            #pragma unroll
            for (int rg=0; rg<4; rg++){
                int l = lbase + i*16 + rgrp*4 + rg;
                float sc = nv*acc[i][j][rg] - mval*Pv[l] + cmv;
                if (sc > v){ v = sc; vi = l; }
            }
        }
        #pragma unroll
        for (int off=16; off<64; off<<=1){
            float ov = __shfl_xor(v, off);
            int   oi = __shfl_xor(vi, off);
            if (ov > v || (ov == v && oi < vi)){ v = ov; vi = oi; }
        }
        if (rgrp == 0){
            smax[wm*128 + wn*32 + j*16 + colrow] = v;
            sarg[wm*128 + wn*32 + j*16 + colrow] = vi;
        }
    }
    barx();
    if (tid < 128){
        float v0 = smax[tid];     int a0 = sarg[tid];
        float v1 = smax[128+tid]; int a1 = sarg[128+tid];
        if (v1 > v0 || (v1 == v0 && a1 < a0)){ v0 = v1; a0 = a1; }
        int o = (b*32 + lblk)*4096 + (mblk<<7) + tid;
        ws[pmax_off(0) + o] = v0;
        ((int*)ws)[parg_off(0) + o] = a0;
    }
}

// ===========================================================================
// 256^2 counted-vmcnt phase GEMM, NSP planes/side. 512 thr.
// b = b0 + blockIdx.z; per-batch plane stride bstride (shorts).
// MODE 0: fused score/max/argmax. MODE 1: G = acc. MODE 2: G += acc.
// ===========================================================================
template<int LEV, int MODE, int NSP>
__launch_bounds__(512, 2)
__global__ void k_g8(const unsigned short* __restrict__ planes0,
                     float* __restrict__ ws, float* __restrict__ G,
                     int b0, int kd, size_t bstride){
    const size_t PS = (size_t)4096 * kd;
    const int b = b0 + blockIdx.z;
    const unsigned short* planes = planes0 + (size_t)blockIdx.z * bstride;
    __shared__ unsigned short lds[2*2*NSP*256*32];
    const int tid = threadIdx.x;
    const int w = tid >> 6, lane = tid & 63;
    const int mblk = blockIdx.x, lblk = blockIdx.y;
    const int wm = w >> 2, wn = w & 3;
    const int colrow = lane & 15, rgrp = lane >> 4;
    const int swz = (rgrp ^ ((lane >> 1) & 3)) * 8;
    const int abase = wm*4096 + colrow*32 + swz;
    const int bbase = NSP*8192 + wn*2048 + colrow*32 + swz;
    const int NT = kd >> 5;
    const int BUFS = 2*NSP*8192;

    f32x4 acc[8][4];
    #pragma unroll
    for (int i=0;i<8;i++)
        #pragma unroll
        for (int j=0;j<4;j++) acc[i][j] = (f32x4){0.f,0.f,0.f,0.f};

    short8 aF[NSP][4], bF[NSP][4];

#define STAGE(bufv, k0v, qi) do { \
    _Pragma("unroll") \
    for (int e=0;e<NSP;e++){ \
        int flat = w*(4*NSP) + (qi)*NSP + e; \
        int p = flat >> 4; \
        int rb = (flat & 15) << 4; \
        int rowbase = (p < NSP ? lblk : mblk) << 8; \
        const unsigned short* g = planes + (size_t)p*PS \
            + (size_t)(rowbase + rb + (lane>>2))*kd + (size_t)(k0v) + (lane&3)*8; \
        unsigned short* lp = (unsigned short*)&lds[(bufv)*BUFS + p*8192 + rb*32]; \
        GLOAD16(g, lp); \
    } \
} while(0)

#define RDA(bufv, half) do { \
    _Pragma("unroll") \
    for (int pl=0; pl<NSP; pl++) \
        _Pragma("unroll") \
        for (int i=0;i<4;i++) \
            aF[pl][i] = *(const short8*)&lds[(bufv)*BUFS + pl*8192 + abase + ((half)*4+i)*512]; \
} while(0)

#define RDB(bufv, half) do { \
    _Pragma("unroll") \
    for (int pl=0; pl<NSP; pl++) \
        _Pragma("unroll") \
        for (int j=0;j<2;j++) \
            bF[pl][(half)*2+j] = *(const short8*)&lds[(bufv)*BUFS + pl*8192 + bbase + ((half)*2+j)*512]; \
} while(0)

#define MM(ihalf, jhalf) do { \
    __builtin_amdgcn_s_setprio(1); \
    _Pragma("unroll") \
    for (int i=0;i<4;i++) \
        _Pragma("unroll") \
        for (int j=0;j<2;j++){ \
            const int ai = (ihalf)*4+i, bj = (jhalf)*2+j; \
            acc[ai][bj] = __builtin_amdgcn_mfma_f32_16x16x32_bf16(aF[0][i], bF[0][bj], acc[ai][bj],0,0,0); \
            if (NSP>=2){ \
                acc[ai][bj] = __builtin_amdgcn_mfma_f32_16x16x32_bf16(aF[0][i], bF[1][bj], acc[ai][bj],0,0,0); \
                acc[ai][bj] = __builtin_amdgcn_mfma_f32_16x16x32_bf16(aF[1][i], bF[0][bj], acc[ai][bj],0,0,0); \
            } \
        } \
    __builtin_amdgcn_s_setprio(0); \
} while(0)

    STAGE(0, 0, 0); STAGE(0, 0, 1); STAGE(0, 0, 2); STAGE(0, 0, 3);

    int cur = 0;
    for (int kt = 0; kt < NT-1; kt++){
        const int k0n = (kt+1) << 5;
        STAGE(cur^1, k0n, 0);
        if constexpr (NSP==1) asm volatile("s_waitcnt vmcnt(1)" ::: "memory");
        else                  asm volatile("s_waitcnt vmcnt(2)" ::: "memory");
        barx();
        RDB(cur, 0); RDA(cur, 0);
        MM(0, 0);
        STAGE(cur^1, k0n, 1);
        RDB(cur, 1);
        MM(0, 1);
        STAGE(cur^1, k0n, 2);
        RDA(cur, 1);
        MM(1, 1);
        STAGE(cur^1, k0n, 3);
        MM(1, 0);
        barx();
        cur ^= 1;
    }
    asm volatile("s_waitcnt vmcnt(0)" ::: "memory");
    barx();
    RDB(cur, 0); RDA(cur, 0); MM(0, 0);
    RDB(cur, 1); MM(0, 1);
    RDA(cur, 1); MM(1, 1);
    MM(1, 0);

#undef STAGE
#undef RDA
#undef RDB
#undef MM

    const int lbase = (lblk<<8) + wm*128;
    const int mbase = (mblk<<8) + wn*64;

    if (MODE != 0){
        #pragma unroll
        for (int i=0;i<8;i++){
            #pragma unroll
            for (int rg=0; rg<4; rg++){
                float* gp = G + (size_t)(lbase + i*16 + rgrp*4 + rg)*4096 + mbase + colrow;
                #pragma unroll
                for (int j=0;j<4;j++){
                    float v = acc[i][j][rg];
                    if (MODE == 2) v += gp[j*16];
                    gp[j*16] = v;
                }
            }
        }
        return;
    }

    constexpr int D = lev_D(LEV);
    const float mval = ws[200+LEV];
    const float Dm2 = (float)D * mval * mval;
    const float* Pv  = ws + p_off(LEV)    + b*4096;
    const float* NIv = ws + ninv_off(LEV) + b*4096;
    const float* CSv = ws + csum_off(LEV) + b*4096;
    barx();
    float* smax = (float*)lds;                 // [2][256]
    int*   sarg = (int*)((char*)lds + 2048);   // [2][256]
    #pragma unroll
    for (int j=0;j<4;j++){
        int m = mbase + j*16 + colrow;
        float nv = NIv[m];
        float cmv = -mval*nv*CSv[m] + Dm2;
        float v = -FLT_MAX; int vi = 0x7fffffff;
        #pragma unroll
        for (int i=0;i<8;i++){
            #pragma unroll
            for (int rg=0; rg<4; rg++){
                int l = lbase + i*16 + rgrp*4 + rg;
                float sc = nv*acc[i][j][rg] - mval*Pv[l] + cmv;
                if (sc > v){ v = sc; vi = l; }
            }
        }
        #pragma unroll
        for (int off=16; off<64; off<<=1){
            float ov = __shfl_xor(v, off);
            int   oi = __shfl_xor(vi, off);
            if (ov > v || (ov == v && oi < vi)){ v = ov; vi = oi; }
        }
        if (rgrp == 0){
            smax[wm*256 + wn*64 + j*16 + colrow] = v;
            sarg[wm*256 + wn*64 + j*16 + colrow] = vi;
        }
    }
    barx();
    if (tid < 256){
        float v0 = smax[tid];     int a0 = sarg[tid];
        float v1 = smax[256+tid]; int a1 = sarg[256+tid];
        if (v1 > v0 || (v1 == v0 && a1 < a0)){ v0 = v1; a0 = a1; }
        int o = (b*32 + lblk)*4096 + (mblk<<8) + tid;
        ws[pmax_off(LEV) + o] = v0;
        ((int*)ws)[parg_off(LEV) + o] = a0;
    }
}

// --- OLD 128^2 MFMA GEMM (fallback for lev0 if ws too small) ---
template<int LEV, int MODE, int NSP>
__launch_bounds__(256, 2)
__global__ void k_gmfma(const unsigned short* __restrict__ planes,
                        float* __restrict__ ws, float* __restrict__ G,
                        int b, int kd){
    const size_t PS = (size_t)4096 * kd;
    __shared__ unsigned short lds[2*NSP*128*32];
    const int tid = threadIdx.x;
    const int w = tid >> 6, lane = tid & 63;
    const int mblk = blockIdx.x, lblk = blockIdx.y;
    const int lw = w >> 1, mw = w & 1;

    f32x4 acc[4][4];
    #pragma unroll
    for (int i=0;i<4;i++)
        #pragma unroll
        for (int j=0;j<4;j++) acc[i][j] = (f32x4){0.f,0.f,0.f,0.f};

    const int srow = lane >> 2, ssl = lane & 3;
    const int colrow = lane & 15, kk = lane >> 4;
    const int swz = (kk ^ ((lane >> 1) & 3)) * 8;
    const int aRow0 = lw*64 + colrow;
    const int bRow0 = mw*64 + colrow;

    for (int k0 = 0; k0 < kd; k0 += 32){
        #pragma unroll
        for (int p = 0; p < 2*NSP; p++){
            const int rb = (p < NSP ? lblk : mblk)*128 + w*32 + srow;
            const unsigned short* gp0 = planes + (size_t)p*PS
                                        + (size_t)rb*kd + (size_t)k0 + ssl*8;
            unsigned short* lp0 = &lds[p*4096 + w*1024];
            GLOAD16(gp0, lp0);
            GLOAD16(gp0 + (size_t)16*kd, lp0 + 512);
        }
        __syncthreads();

        short8 aF[NSP][4];
        #pragma unroll
        for (int pa=0; pa<NSP; pa++)
            #pragma unroll
            for (int i=0;i<4;i++)
                aF[pa][i] = *(const short8*)&lds[pa*4096 + (aRow0 + i*16)*32 + swz];
        #pragma unroll
        for (int pb=0; pb<NSP; pb++){
            short8 bF[4];
            #pragma unroll
            for (int j=0;j<4;j++)
                bF[j] = *(const short8*)&lds[(NSP+pb)*4096 + (bRow0 + j*16)*32 + swz];
            const int npa = NSP - pb;
            for (int pa=0; pa<npa; pa++)
                #pragma unroll
                for (int i=0;i<4;i++)
                    #pragma unroll
                    for (int j=0;j<4;j++)
                        acc[i][j] = __builtin_amdgcn_mfma_f32_16x16x32_bf16(
                                        aF[pa][i], bF[j], acc[i][j], 0, 0, 0);
        }
        __syncthreads();
    }

    const int lbase = lblk*128 + lw*64;
    const int mbase = mblk*128 + mw*64;
    const int rgrp = lane >> 4;

    if (MODE != 0){
        #pragma unroll
        for (int i=0;i<4;i++){
            #pragma unroll
            for (int rg=0; rg<4; rg++){
                float* gp = G + (size_t)(lbase + i*16 + rgrp*4 + rg)*4096
                              + mbase + colrow;
                #pragma unroll
                for (int j=0;j<4;j++){
                    float v = acc[i][j][rg];
                    if (MODE == 2) v += gp[j*16];
                    gp[j*16] = v;
                }
            }
        }
        return;
    }

    constexpr int D = lev_D(LEV);
    const float mval = ws[200+LEV];
    const float Dm2 = (float)D * mval * mval;
    const float* Pv  = ws + p_off(LEV)    + b*4096;
    const float* NIv = ws + ninv_off(LEV) + b*4096;
    const float* CSv = ws + csum_off(LEV) + b*4096;
    float* smax = (float*)lds;
    int*   sarg = (int*)&lds[512];
    #pragma unroll
    for (int j=0;j<4;j++){
        int m = mbase + j*16 + colrow;
        float nv = NIv[m];
        float cmv = -mval*nv*CSv[m] + Dm2;
        float v = -FLT_MAX; int vi = 0x7fffffff;
        #pragma unroll
        for (int i=0;i<4;i++){
            #pragma unroll
            for (int rg=0; rg<4; rg++){
                int l = lbase + i*16 + rgrp*4 + rg;
                float sc = nv*acc[i][j][rg] - mval*Pv[l] + cmv;
                if (sc > v){ v = sc; vi = l; }
            }
        }
        #pragma unroll
        for (int off=16; off<64; off<<=1){
            float ov = __shfl_xor(v, off);
            int   oi = __shfl_xor(vi, off);
            if (ov > v || (ov == v && oi < vi)){ v = ov; vi = oi; }
        }
        if (rgrp == 0){
            smax[w*64 + j*16 + colrow] = v;
            sarg[w*64 + j*16 + colrow] = vi;
        }
    }
    __syncthreads();
    if (tid < 128){
        int mg = tid >> 6, idx = tid & 63;
        float v0 = smax[mg*64 + idx];     int a0 = sarg[mg*64 + idx];
        float v1 = smax[(mg+2)*64 + idx]; int a1 = sarg[(mg+2)*64 + idx];
        if (v1 > v0 || (v1 == v0 && a1 < a0)){ v0 = v1; a0 = a1; }
        int m = mblk*128 + mg*64 + idx;
        int o = (b*32 + lblk)*4096 + m;
        ws[pmax_off(LEV) + o] = v0;
        ((int*)ws)[parg_off(LEV) + o] = a0;
    }
}

// --- score + max/argmax from accumulated G; grid (64 mblk, 8 lsplit) ---
template<int LEV>
__global__ void k_score(const float* __restrict__ G, float* __restrict__ ws, int b){
    constexpr int D = lev_D(LEV);
    __shared__ float smax[4][64];
    __shared__ int   sarg[4][64];
    int tid = threadIdx.x, mloc = tid & 63, r = tid >> 6;
    int m = blockIdx.x*64 + mloc;
    int l0 = blockIdx.y*512;
    float mval = ws[200+LEV];
    float nv = ws[ninv_off(LEV) + b*4096 + m];
    float cmv = -mval*nv*ws[csum_off(LEV) + b*4096 + m] + (float)D*mval*mval;
    const float* Pv = ws + p_off(LEV) + b*4096;
    float best = -FLT_MAX; int bi = 0x7fffffff;
    for (int lt=0; lt<128; lt++){
        int l = l0 + lt*4 + r;
        float sc = nv*G[(size_t)l*4096 + m] - mval*Pv[l] + cmv;
        if (sc > best){ best = sc; bi = l; }
    }
    smax[r][mloc] = best; sarg[r][mloc] = bi;
    __syncthreads();
    if (tid < 64){
        float v = smax[0][tid]; int vi = sarg[0][tid];
        #pragma unroll
        for (int rr=1; rr<4; rr++){
            float ov = smax[rr][tid]; int oi = sarg[rr][tid];
            if (ov > v || (ov == v && oi < vi)){ v = ov; vi = oi; }
        }
        int o = (b*32 + blockIdx.y)*4096 + blockIdx.x*64 + tid;
        ws[pmax_off(LEV) + o] = v;
        ((int*)ws)[parg_off(LEV) + o] = vi;
    }
}

// --- reduce l-chunks -> S3,S2,S1,arg outputs (applies late scale) ---
__global__ void k_smax(float* __restrict__ ws, float* __restrict__ out,
                       int nch0, int nch1, int nch2){
    int gid = blockIdx.x*256 + threadIdx.x;
    if (gid >= 8192) return;
    int b = gid >> 12, m = gid & 4095;
    int nchs[3] = {nch0, nch1, nch2};
    for (int lev=0; lev<3; lev++){
        float mv = -FLT_MAX; int ma = 0x7fffffff;
        for (int ch=0; ch<nchs[lev]; ch++){
            int o = ((b*32+ch)<<12) + m;
            float v = ws[pmax_off(lev) + o];
            int   a = ((const int*)ws)[parg_off(lev) + o];
            if (v > mv || (v == mv && a < ma)){ mv=v; ma=a; }
        }
        out[lev*8192 + gid] = mv * ws[204+lev];
        if (lev==0){
            out[3*8192 + gid] = (float)ma;
            ((int*)ws)[arg_off() + gid] = ma;
        }
    }
}

// --- T = fold(gather(unfold(ref), arg)) / 9 ---
template<int LEV>
__global__ void k_transfer(const float* __restrict__ ref, const float* __restrict__ wsf,
                           float* __restrict__ outT){
    constexpr int C=LT<LEV>::C, H=LT<LEV>::H, K=LT<LEV>::K, S=LT<LEV>::S, PD=LT<LEV>::P;
    const int* arg = (const int*)wsf + arg_off();
    size_t gid = (size_t)blockIdx.x*256 + threadIdx.x;
    size_t total = (size_t)2*C*H*H;
    if (gid >= total) return;
    int x = (int)(gid % H);
    int y = (int)((gid / H) % H);
    int c = (int)((gid / ((size_t)H*H)) % C);
    int b = (int)(gid / ((size_t)C*H*H));
    const float* rimg = ref + (size_t)(b*C+c)*H*H;
    int byo = (y+PD)/S, ryo = (y+PD)%S;
    int bxo = (x+PD)/S, rxo = (x+PD)%S;
    float acc = 0.f;
    #pragma unroll
    for (int jy=0; jy<3; jy++){
        int ho = byo - jy;
        if (ho < 0 || ho >= 64) continue;
        int ki = ryo + jy*S;
        #pragma unroll
        for (int jx=0; jx<3; jx++){
            int wo = bxo - jx;
            if (wo < 0 || wo >= 64) continue;
            int kj = rxo + jx*S;
            int l = arg[b*4096 + ho*64 + wo];
            int ly = l>>6, lx = l&63;
            int srow = ly*S + ki - PD, scol = lx*S + kj - PD;
            if (srow>=0 && srow<H && scol>=0 && scol<H)
                acc += rimg[srow*H + scol];
        }
    }
    outT[gid] = acc * (1.0f/9.0f);
}

// --- lev0: bf16x3, k_g0 both-batch path (fallback: R8 per-batch k_gmfma) ---
static void run_level0(const float* refsr, const float* lrsr, float* ws,
                       size_t ws_size, hipStream_t stream, int* nch){
    constexpr int D = 2304;
    const size_t PS = (size_t)4096 * D;
    k_rownorm<0><<<D/2, 256, 0, stream>>>(refsr, ws);
    k_scalar_early<0><<<1, 64, 0, stream>>>(ws);

    unsigned short* pl = (unsigned short*)((char*)ws + G_BASE_BYTES);
    if (ws_size >= G_BASE_BYTES + (size_t)2*6*PS*2){          // 234.5 MB
        nch[0] = 16;
        for (int b=0; b<2; b++){
            unsigned short* plb = pl + (size_t)b*6*PS;
            k_split<0,true ,3><<<2*D, 256, 0, stream>>>(refsr, ws, plb, b, 0, D);
            k_split<0,false,3><<<2*D, 256, 0, stream>>>(lrsr,  ws, plb + 3*PS, b, 0, D);
            k_stats2<3><<<2048, 256, 0, stream>>>(plb, plb + 3*PS, PS,
                ws + p_off(0), ws + csum_off(0), ws + ninv_off(0), D, 1, b);
            k_levfin<0><<<16, 256, 0, stream>>>(ws, b);
        }
        k_g0<<<dim3(32,16,2), 512, 0, stream>>>(pl, ws, D);
    } else {                                                   // R8 fallback
        nch[0] = 32;
        for (int b=0; b<2; b++){
            k_split<0,true ,3><<<2*D, 256, 0, stream>>>(refsr, ws, pl, b, 0, D);
            k_split<0,false,3><<<2*D, 256, 0, stream>>>(lrsr,  ws, pl + 3*PS, b, 0, D);
            k_stats2<3><<<2048, 256, 0, stream>>>(pl, pl + 3*PS, PS,
                ws + p_off(0), ws + csum_off(0), ws + ninv_off(0), D, 1, b);
            k_levfin<0><<<16, 256, 0, stream>>>(ws, b);
            k_gmfma<0,0,3><<<dim3(32,32), 256, 0, stream>>>(pl, ws, nullptr, b, D);
        }
    }
    k_scalar_late<0><<<1, 64, 0, stream>>>(ws);
}

// --- lev1/lev2: NSP=1 k_g8 (lev1 both-batch; lev2 per-batch) ---
template<int LEV>
static void run_level(const float* refsr, const float* lrsr, float* ws,
                      size_t ws_size, hipStream_t stream, int* nch){
    constexpr int D = lev_D(LEV);
    constexpr int NSP = 1;
    k_rownorm<LEV><<<D/2, 256, 0, stream>>>(refsr, ws);
    k_scalar_early<LEV><<<1, 64, 0, stream>>>(ws);

    const size_t PS = (size_t)4096 * D;
    const size_t perBatchBytes = (size_t)2*NSP*PS*2;   // both sides, one batch
    unsigned short* pl = (unsigned short*)((char*)ws + G_BASE_BYTES);
    float* G = ws + (G_BASE_BYTES >> 2);

    if (LEV==1 && ws_size >= G_BASE_BYTES + 2*perBatchBytes){
        nch[LEV] = 16;
        for (int b=0; b<2; b++){
            unsigned short* plb = pl + (size_t)b*2*NSP*PS;
            k_split<LEV,true ,NSP><<<2*D, 256, 0, stream>>>(refsr, ws, plb, b, 0, D);
            k_split<LEV,false,NSP><<<2*D, 256, 0, stream>>>(lrsr,  ws, plb + NSP*PS, b, 0, D);
            k_stats2<NSP><<<2048, 256, 0, stream>>>(plb, plb + NSP*PS, PS,
                ws + p_off(LEV), ws + csum_off(LEV), ws + ninv_off(LEV), D, 1, b);
            k_levfin<LEV><<<16, 256, 0, stream>>>(ws, b);
        }
        k_g8<LEV,0,NSP><<<dim3(16,16,2), 512, 0, stream>>>(pl, ws, nullptr, 0, D, 2*NSP*PS);
        k_scalar_late<LEV><<<1, 64, 0, stream>>>(ws);
        return;
    }

    bool fused = (ws_size >= G_BASE_BYTES + perBatchBytes);
    int kd = D;
    if (!fused){
        kd = 0;
        for (int div = 2; div <= 16; div <<= 1){
            if (ws_size >= CHUNK_PLANE_BYTES + (size_t)2*NSP*4096*(D/div)*2){ kd = D/div; break; }
        }
        if (!kd) kd = D/16;
        pl = (unsigned short*)((char*)ws + CHUNK_PLANE_BYTES);
    }
    const size_t PSc = (size_t)4096 * kd;
    const int nkc = D / kd;
    nch[LEV] = fused ? 16 : 8;

    for (int b=0; b<2; b++){
        for (int kc=0; kc<nkc; kc++){
            k_split<LEV,true ,NSP><<<2*kd, 256, 0, stream>>>(refsr, ws, pl, b, kc*kd, kd);
            k_split<LEV,false,NSP><<<2*kd, 256, 0, stream>>>(lrsr,  ws, pl + NSP*PSc, b, kc*kd, kd);
            k_stats2<NSP><<<2048, 256, 0, stream>>>(pl, pl + NSP*PSc, PSc,
                ws + p_off(LEV), ws + csum_off(LEV), ws + ninv_off(LEV), kd, kc==0, b);
            if (!fused){
                if (kc==0) k_g8<LEV,1,NSP><<<dim3(16,16,1), 512, 0, stream>>>(pl, ws, G, b, kd, 0);
                else       k_g8<LEV,2,NSP><<<dim3(16,16,1), 512, 0, stream>>>(pl, ws, G, b, kd, 0);
            }
        }
        k_levfin<LEV><<<16, 256, 0, stream>>>(ws, b);
        if (fused) k_g8<LEV,0,NSP><<<dim3(16,16,1), 512, 0, stream>>>(pl, ws, nullptr, b, kd, 0);
        else       k_score<LEV><<<dim3(64,8), 256, 0, stream>>>(G, ws, b);
    }
    k_scalar_late<LEV><<<1, 64, 0, stream>>>(ws);
}

extern "C" void kernel_launch(void* const* d_in, const int* in_sizes, int n_in,
                              void* d_out, int out_size, void* d_ws, size_t ws_size,
                              hipStream_t stream){
    const float* lrsr[3]  = { (const float*)d_in[2], (const float*)d_in[1], (const float*)d_in[0] };
    const float* refsr[3] = { (const float*)d_in[5], (const float*)d_in[4], (const float*)d_in[3] };
    const float* refp[3]  = { (const float*)d_in[8], (const float*)d_in[7], (const float*)d_in[6] };
    float* ws  = (float*)d_ws;
    float* out = (float*)d_out;

    hipMemsetAsync(d_ws, 0, 4096, stream);  // zero scalar slots + scalars

    int nch[3];
    run_level0  (refsr[0], lrsr[0], ws, ws_size, stream, nch);
    run_level<1>(refsr[1], lrsr[1], ws, ws_size, stream, nch);
    run_level<2>(refsr[2], lrsr[2], ws, ws_size, stream, nch);

    k_smax<<<32, 256, 0, stream>>>(ws, out, nch[0], nch[1], nch[2]);

    k_transfer<0><<< (2*256*64*64)/256,   256, 0, stream>>>(refp[0], ws, out + 32768);
    k_transfer<1><<< (2*128*128*128)/256, 256, 0, stream>>>(refp[1], ws, out + 2129920);
    k_transfer<2><<< (2*64*256*256)/256,  256, 0, stream>>>(refp[2], ws, out + 6324224);
}